// Round 4
// baseline (680.940 us; speedup 1.0000x reference)
//
#include <hip/hip_runtime.h>

// SGConv (K=2, two layers) on MI355X.
// R2: single-atomic CSR build (rank trick), deg via post-CSR row reduction,
//     hop uses float4 gathers (4 rows / wave-instr) + quarter-wave reduction.
// R3: linears rewritten as LDS-tiled register-blocked fp32 GEMM (BM=128,
//     4x8 / 4x5 register tiles, XOR-swizzled LDS for conflict-free b128).
//     Old wave-per-node shfl linear was a serial-FMA-chain latency disaster
//     (103us each; VALUBusy 16%).

#define SCAN_TPB 256
#define SCAN_ITEMS 8
#define SCAN_CHUNK (SCAN_TPB * SCAN_ITEMS)   // 2048 elements per block

__global__ __launch_bounds__(256) void zero_cnt_kernel(int* cnt, int N_) {
    int n = blockIdx.x * blockDim.x + threadIdx.x;
    if (n < N_) cnt[n] = 0;
}

// rank[e] = arrival index of edge e within its dst bucket. ONLY atomic pass.
__global__ __launch_bounds__(256) void count_rank_kernel(const int* __restrict__ ei,
                                                         int* cnt, int* __restrict__ rank, int E_) {
    int e = blockIdx.x * blockDim.x + threadIdx.x;
    if (e < E_) rank[e] = atomicAdd(&cnt[ei[E_ + e]], 1);
}

// --- 3-phase hierarchical exclusive scan of cnt -> row_ptr ---

__global__ __launch_bounds__(SCAN_TPB) void scan_partial_kernel(const int* __restrict__ cnt,
                                                                int* __restrict__ bsums, int N_) {
    int t = threadIdx.x;
    int base = blockIdx.x * SCAN_CHUNK + t * SCAN_ITEMS;
    int s = 0;
    #pragma unroll
    for (int j = 0; j < SCAN_ITEMS; ++j) { int i = base + j; if (i < N_) s += cnt[i]; }
    __shared__ int sm[SCAN_TPB];
    sm[t] = s; __syncthreads();
    for (int o = SCAN_TPB / 2; o > 0; o >>= 1) {
        if (t < o) sm[t] += sm[t + o];
        __syncthreads();
    }
    if (t == 0) bsums[blockIdx.x] = sm[0];
}

__global__ __launch_bounds__(1024) void scan_bsums_kernel(int* bsums, int nb,
                                                          int* row_ptr, int N_) {
    __shared__ int sm[1024];
    int t = threadIdx.x;
    int v = (t < nb) ? bsums[t] : 0;
    sm[t] = v; __syncthreads();
    for (int o = 1; o < 1024; o <<= 1) {
        int u = (t >= o) ? sm[t - o] : 0;
        __syncthreads();
        sm[t] += u;
        __syncthreads();
    }
    if (t < nb) bsums[t] = sm[t] - v;          // exclusive block offset
    if (t == 1023) row_ptr[N_] = sm[1023];     // grand total
}

__global__ __launch_bounds__(SCAN_TPB) void scan_final_kernel(const int* __restrict__ cnt,
                                                              const int* __restrict__ bsums,
                                                              int* __restrict__ row_ptr, int N_) {
    int t = threadIdx.x;
    int base = blockIdx.x * SCAN_CHUNK + t * SCAN_ITEMS;
    int loc[SCAN_ITEMS];
    int s = 0;
    #pragma unroll
    for (int j = 0; j < SCAN_ITEMS; ++j) {
        int i = base + j;
        int c = (i < N_) ? cnt[i] : 0;
        loc[j] = s; s += c;
    }
    __shared__ int sm[SCAN_TPB];
    sm[t] = s; __syncthreads();
    for (int o = 1; o < SCAN_TPB; o <<= 1) {
        int u = (t >= o) ? sm[t - o] : 0;
        __syncthreads();
        sm[t] += u;
        __syncthreads();
    }
    int excl = bsums[blockIdx.x] + sm[t] - s;
    #pragma unroll
    for (int j = 0; j < SCAN_ITEMS; ++j) {
        int i = base + j;
        if (i < N_) row_ptr[i] = excl + loc[j];
    }
}

// Atomic-free CSR fill using precomputed ranks.
__global__ __launch_bounds__(256) void fill_kernel(const int* __restrict__ ei,
                                                   const float* __restrict__ w,
                                                   const int* __restrict__ row_ptr,
                                                   const int* __restrict__ rank,
                                                   int* __restrict__ col,
                                                   float* __restrict__ wv, int E_) {
    int e = blockIdx.x * blockDim.x + threadIdx.x;
    if (e < E_) {
        int d = ei[E_ + e];
        int pos = row_ptr[d] + rank[e];
        col[pos] = ei[e];
        wv[pos] = w[e];
    }
}

// deg[d] = 1 (self-loop) + sum of row d's weights; dinv = 1/sqrt(deg).
__global__ __launch_bounds__(256) void deg_dinv_kernel(const float* __restrict__ wv,
                                                       const int* __restrict__ row_ptr,
                                                       float* __restrict__ dinv, int N_) {
    int n = blockIdx.x * blockDim.x + threadIdx.x;
    if (n < N_) {
        float s = 1.0f;
        int p0 = row_ptr[n], p1 = row_ptr[n + 1];
        for (int p = p0; p < p1; ++p) s += wv[p];
        dinv[n] = 1.0f / sqrtf(s);
    }
}

// val[pos] = dinv[src] * w * dinv[dst], written in place over wv.
__global__ __launch_bounds__(256) void scale_kernel(const int* __restrict__ ei,
                                                    const float* __restrict__ w,
                                                    const int* __restrict__ row_ptr,
                                                    const int* __restrict__ rank,
                                                    const float* __restrict__ dinv,
                                                    float* __restrict__ val, int E_) {
    int e = blockIdx.x * blockDim.x + threadIdx.x;
    if (e < E_) {
        int s = ei[e];
        int d = ei[E_ + e];
        int pos = row_ptr[d] + rank[e];
        val[pos] = dinv[s] * w[e] * dinv[d];
    }
}

// One wave per dst node. float4 gathers: quarter q of the wave fetches source row
// s_q (16 lanes x float4 = 256B row), so one wave-instruction covers 4 edges (1KB).
__global__ __launch_bounds__(256) void hop_kernel(const float* __restrict__ xin,
                                                  float* __restrict__ xout,
                                                  const float* __restrict__ dinv,
                                                  const int* __restrict__ row_ptr,
                                                  const int* __restrict__ col,
                                                  const float* __restrict__ val, int N_) {
    int wave = (blockIdx.x * blockDim.x + threadIdx.x) >> 6;
    int lane = threadIdx.x & 63;
    if (wave >= N_) return;
    const int d  = wave;
    const int q  = lane >> 4;      // quarter 0..3
    const int fl = lane & 15;      // float4 slot within row

    int e0 = row_ptr[d], e1 = row_ptr[d + 1];
    int nE = e1 - e0;
    float di = dinv[d];
    float4 selfv = ((const float4*)(xin + (size_t)d * 64))[fl];   // prefetch self row
    float4 acc = make_float4(0.f, 0.f, 0.f, 0.f);

    for (int eb = 0; eb < nE; eb += 64) {
        int m = min(64, nE - eb);
        bool ok = lane < m;
        int   cs = ok ? col[e0 + eb + lane] : d;    // pad: self row, weight 0
        float vs = ok ? val[e0 + eb + lane] : 0.f;
        for (int g = 0; g < m; g += 8) {
            int   s0 = __shfl(cs, g + q);
            int   s1 = __shfl(cs, g + 4 + q);
            float v0 = __shfl(vs, g + q);
            float v1 = __shfl(vs, g + 4 + q);
            float4 x0 = ((const float4*)(xin + (size_t)s0 * 64))[fl];
            float4 x1 = ((const float4*)(xin + (size_t)s1 * 64))[fl];
            acc.x = fmaf(v0, x0.x, acc.x); acc.y = fmaf(v0, x0.y, acc.y);
            acc.z = fmaf(v0, x0.z, acc.z); acc.w = fmaf(v0, x0.w, acc.w);
            acc.x = fmaf(v1, x1.x, acc.x); acc.y = fmaf(v1, x1.y, acc.y);
            acc.z = fmaf(v1, x1.z, acc.z); acc.w = fmaf(v1, x1.w, acc.w);
        }
    }
    acc.x += __shfl_xor(acc.x, 16); acc.y += __shfl_xor(acc.y, 16);
    acc.z += __shfl_xor(acc.z, 16); acc.w += __shfl_xor(acc.w, 16);
    acc.x += __shfl_xor(acc.x, 32); acc.y += __shfl_xor(acc.y, 32);
    acc.z += __shfl_xor(acc.z, 32); acc.w += __shfl_xor(acc.w, 32);
    float dii = di * di;
    acc.x = fmaf(dii, selfv.x, acc.x); acc.y = fmaf(dii, selfv.y, acc.y);
    acc.z = fmaf(dii, selfv.z, acc.z); acc.w = fmaf(dii, selfv.w, acc.w);
    if (lane < 16)
        ((float4*)(xout + (size_t)d * 64))[fl] = acc;
}

// LDS-tiled GEMM: out[n][f] = (relu?)(sum_k h[n][k]*W[f][k] + b[f]).
// BM=128 nodes/block, 256 threads, thread tile = 4 nodes x (F/8) outs.
// Both h and W tiles XOR-swizzled (write AND read side) so the b128
// column-slice reads are bank-conflict-free with broadcast.
template<int F, bool RELU>
__global__ __launch_bounds__(256) void linear_tiled_kernel(const float* __restrict__ hin,
                                                           float* __restrict__ outp,
                                                           const float* __restrict__ W,
                                                           const float* __restrict__ b,
                                                           int N_) {
    constexpr int BM = 128;
    constexpr int NJ = F / 8;            // outs per thread (8 for F=64, 5 for F=40)
    __shared__ float hs[BM * 64];
    __shared__ float ws[F * 64];
    __shared__ float bl[F];
    const int tid  = threadIdx.x;
    const int base = blockIdx.x * BM;

    // stage W (swizzled) + bias
    for (int u = tid; u < F * 16; u += 256) {
        int f = u >> 4, kc = u & 15;
        float4 v = ((const float4*)W)[u];
        *(float4*)&ws[f * 64 + ((kc ^ (f & 7)) << 2)] = v;
    }
    for (int u = tid; u < F; u += 256) bl[u] = b[u];
    // stage h tile (coalesced global read, swizzled LDS write)
    const int lim = min(BM, N_ - base);
    for (int u = tid; u < BM * 16; u += 256) {
        int n = u >> 4, kc = u & 15;
        float4 v = (n < lim) ? ((const float4*)(hin + (size_t)(base + n) * 64))[kc]
                             : make_float4(0.f, 0.f, 0.f, 0.f);
        *(float4*)&hs[n * 64 + ((kc ^ ((n >> 2) & 7)) << 2)] = v;
    }
    __syncthreads();

    const int fb  = tid & 7;     // f = fb + 8j
    const int nbb = tid >> 3;    // n = nbb*4 + i  (nbb = lane>>3 within wave -> conflict-free)
    float acc[4][NJ];
    #pragma unroll
    for (int i = 0; i < 4; ++i)
        #pragma unroll
        for (int j = 0; j < NJ; ++j) acc[i][j] = 0.f;

    #pragma unroll
    for (int kc = 0; kc < 16; ++kc) {
        float4 hv[4], wv[NJ];
        #pragma unroll
        for (int i = 0; i < 4; ++i) {
            int n = nbb * 4 + i;
            hv[i] = *(const float4*)&hs[n * 64 + ((kc ^ ((n >> 2) & 7)) << 2)];
        }
        #pragma unroll
        for (int j = 0; j < NJ; ++j) {
            int f = fb + 8 * j;
            wv[j] = *(const float4*)&ws[f * 64 + ((kc ^ (f & 7)) << 2)];
        }
        #pragma unroll
        for (int i = 0; i < 4; ++i)
            #pragma unroll
            for (int j = 0; j < NJ; ++j) {
                acc[i][j] = fmaf(hv[i].x, wv[j].x, acc[i][j]);
                acc[i][j] = fmaf(hv[i].y, wv[j].y, acc[i][j]);
                acc[i][j] = fmaf(hv[i].z, wv[j].z, acc[i][j]);
                acc[i][j] = fmaf(hv[i].w, wv[j].w, acc[i][j]);
            }
    }

    #pragma unroll
    for (int i = 0; i < 4; ++i) {
        int n = nbb * 4 + i;
        if (base + n < N_) {
            #pragma unroll
            for (int j = 0; j < NJ; ++j) {
                int f = fb + 8 * j;
                float r = acc[i][j] + bl[f];
                if (RELU) r = fmaxf(r, 0.f);
                outp[(size_t)(base + n) * F + f] = r;
            }
        }
    }
}

extern "C" void kernel_launch(void* const* d_in, const int* in_sizes, int n_in,
                              void* d_out, int out_size, void* d_ws, size_t ws_size,
                              hipStream_t stream) {
    const float* x   = (const float*)d_in[0];
    const int*   ei  = (const int*)d_in[1];
    const float* w   = (const float*)d_in[2];
    const float* W1  = (const float*)d_in[3];
    const float* b1  = (const float*)d_in[4];
    const float* W2  = (const float*)d_in[5];
    const float* b2  = (const float*)d_in[6];
    float* out = (float*)d_out;

    const int N_ = in_sizes[0] / 64;        // 100000
    const int E_ = in_sizes[2];             // 1200000

    char* ws = (char*)d_ws;
    size_t off = 0;
    auto alloc = [&](size_t bytes) { size_t o = off; off += (bytes + 255) & ~(size_t)255; return o; };
    float* dinv    = (float*)(ws + alloc((size_t)N_ * 4));
    int*   cnt     = (int*)  (ws + alloc((size_t)N_ * 4));
    int*   row_ptr = (int*)  (ws + alloc(((size_t)N_ + 1) * 4));
    int*   bsums   = (int*)  (ws + alloc(1024 * 4));
    int*   rank    = (int*)  (ws + alloc((size_t)E_ * 4));
    int*   col     = (int*)  (ws + alloc((size_t)E_ * 4));
    float* val     = (float*)(ws + alloc((size_t)E_ * 4));
    float* bufA    = (float*)(ws + alloc((size_t)N_ * 64 * 4));
    float* bufB    = (float*)(ws + alloc((size_t)N_ * 64 * 4));
    (void)ws_size; (void)n_in; (void)out_size;

    const int bn = (N_ + 255) / 256;
    const int be = (E_ + 255) / 256;
    const int bh = (N_ + 3) / 4;                       // hop: 4 waves (nodes) per block
    const int nb = (N_ + SCAN_CHUNK - 1) / SCAN_CHUNK; // 49 blocks (<=1024)
    const int bl_ = (N_ + 127) / 128;                  // linear: BM=128 tiles

    zero_cnt_kernel<<<bn, 256, 0, stream>>>(cnt, N_);
    count_rank_kernel<<<be, 256, 0, stream>>>(ei, cnt, rank, E_);
    scan_partial_kernel<<<nb, SCAN_TPB, 0, stream>>>(cnt, bsums, N_);
    scan_bsums_kernel<<<1, 1024, 0, stream>>>(bsums, nb, row_ptr, N_);
    scan_final_kernel<<<nb, SCAN_TPB, 0, stream>>>(cnt, bsums, row_ptr, N_);
    fill_kernel<<<be, 256, 0, stream>>>(ei, w, row_ptr, rank, col, val, E_);
    deg_dinv_kernel<<<bn, 256, 0, stream>>>(val, row_ptr, dinv, N_);
    scale_kernel<<<be, 256, 0, stream>>>(ei, w, row_ptr, rank, dinv, val, E_);

    hop_kernel<<<bh, 256, 0, stream>>>(x,    bufA, dinv, row_ptr, col, val, N_);
    hop_kernel<<<bh, 256, 0, stream>>>(bufA, bufB, dinv, row_ptr, col, val, N_);
    linear_tiled_kernel<64, true><<<bl_, 256, 0, stream>>>(bufB, bufA, W1, b1, N_);
    hop_kernel<<<bh, 256, 0, stream>>>(bufA, bufB, dinv, row_ptr, col, val, N_);
    hop_kernel<<<bh, 256, 0, stream>>>(bufB, bufA, dinv, row_ptr, col, val, N_);
    linear_tiled_kernel<40, false><<<bl_, 256, 0, stream>>>(bufA, out, W2, b2, N_);
}

// Round 5
// 362.727 us; speedup vs baseline: 1.8773x; 1.8773x over previous
//
#include <hip/hip_runtime.h>

// SGConv (K=2, two layers) on MI355X.
// R2: single-atomic CSR build (rank trick), deg via post-CSR row reduction,
//     hop uses float4 gathers (4 rows / wave-instr) + quarter-wave reduction.
// R3: LDS-tiled GEMM linears -- REGRESSED: 4x8 float4 tile + full unroll ->
//     256 VGPR + 580MB scratch spill traffic -> 305us/dispatch.
// R4: GEMM tile resized 4x4, unroll 2, __launch_bounds__(256,4) caps 128 VGPR,
//     BM=64, zero-padded W rows for uniform mapping. No spill.

#define SCAN_TPB 256
#define SCAN_ITEMS 8
#define SCAN_CHUNK (SCAN_TPB * SCAN_ITEMS)   // 2048 elements per block

__global__ __launch_bounds__(256) void zero_cnt_kernel(int* cnt, int N_) {
    int n = blockIdx.x * blockDim.x + threadIdx.x;
    if (n < N_) cnt[n] = 0;
}

// rank[e] = arrival index of edge e within its dst bucket. ONLY atomic pass.
__global__ __launch_bounds__(256) void count_rank_kernel(const int* __restrict__ ei,
                                                         int* cnt, int* __restrict__ rank, int E_) {
    int e = blockIdx.x * blockDim.x + threadIdx.x;
    if (e < E_) rank[e] = atomicAdd(&cnt[ei[E_ + e]], 1);
}

// --- 3-phase hierarchical exclusive scan of cnt -> row_ptr ---

__global__ __launch_bounds__(SCAN_TPB) void scan_partial_kernel(const int* __restrict__ cnt,
                                                                int* __restrict__ bsums, int N_) {
    int t = threadIdx.x;
    int base = blockIdx.x * SCAN_CHUNK + t * SCAN_ITEMS;
    int s = 0;
    #pragma unroll
    for (int j = 0; j < SCAN_ITEMS; ++j) { int i = base + j; if (i < N_) s += cnt[i]; }
    __shared__ int sm[SCAN_TPB];
    sm[t] = s; __syncthreads();
    for (int o = SCAN_TPB / 2; o > 0; o >>= 1) {
        if (t < o) sm[t] += sm[t + o];
        __syncthreads();
    }
    if (t == 0) bsums[blockIdx.x] = sm[0];
}

__global__ __launch_bounds__(1024) void scan_bsums_kernel(int* bsums, int nb,
                                                          int* row_ptr, int N_) {
    __shared__ int sm[1024];
    int t = threadIdx.x;
    int v = (t < nb) ? bsums[t] : 0;
    sm[t] = v; __syncthreads();
    for (int o = 1; o < 1024; o <<= 1) {
        int u = (t >= o) ? sm[t - o] : 0;
        __syncthreads();
        sm[t] += u;
        __syncthreads();
    }
    if (t < nb) bsums[t] = sm[t] - v;          // exclusive block offset
    if (t == 1023) row_ptr[N_] = sm[1023];     // grand total
}

__global__ __launch_bounds__(SCAN_TPB) void scan_final_kernel(const int* __restrict__ cnt,
                                                              const int* __restrict__ bsums,
                                                              int* __restrict__ row_ptr, int N_) {
    int t = threadIdx.x;
    int base = blockIdx.x * SCAN_CHUNK + t * SCAN_ITEMS;
    int loc[SCAN_ITEMS];
    int s = 0;
    #pragma unroll
    for (int j = 0; j < SCAN_ITEMS; ++j) {
        int i = base + j;
        int c = (i < N_) ? cnt[i] : 0;
        loc[j] = s; s += c;
    }
    __shared__ int sm[SCAN_TPB];
    sm[t] = s; __syncthreads();
    for (int o = 1; o < SCAN_TPB; o <<= 1) {
        int u = (t >= o) ? sm[t - o] : 0;
        __syncthreads();
        sm[t] += u;
        __syncthreads();
    }
    int excl = bsums[blockIdx.x] + sm[t] - s;
    #pragma unroll
    for (int j = 0; j < SCAN_ITEMS; ++j) {
        int i = base + j;
        if (i < N_) row_ptr[i] = excl + loc[j];
    }
}

// Atomic-free CSR fill using precomputed ranks.
__global__ __launch_bounds__(256) void fill_kernel(const int* __restrict__ ei,
                                                   const float* __restrict__ w,
                                                   const int* __restrict__ row_ptr,
                                                   const int* __restrict__ rank,
                                                   int* __restrict__ col,
                                                   float* __restrict__ wv, int E_) {
    int e = blockIdx.x * blockDim.x + threadIdx.x;
    if (e < E_) {
        int d = ei[E_ + e];
        int pos = row_ptr[d] + rank[e];
        col[pos] = ei[e];
        wv[pos] = w[e];
    }
}

// deg[d] = 1 (self-loop) + sum of row d's weights; dinv = 1/sqrt(deg).
__global__ __launch_bounds__(256) void deg_dinv_kernel(const float* __restrict__ wv,
                                                       const int* __restrict__ row_ptr,
                                                       float* __restrict__ dinv, int N_) {
    int n = blockIdx.x * blockDim.x + threadIdx.x;
    if (n < N_) {
        float s = 1.0f;
        int p0 = row_ptr[n], p1 = row_ptr[n + 1];
        for (int p = p0; p < p1; ++p) s += wv[p];
        dinv[n] = 1.0f / sqrtf(s);
    }
}

// val[pos] = dinv[src] * w * dinv[dst], written in place over wv.
__global__ __launch_bounds__(256) void scale_kernel(const int* __restrict__ ei,
                                                    const float* __restrict__ w,
                                                    const int* __restrict__ row_ptr,
                                                    const int* __restrict__ rank,
                                                    const float* __restrict__ dinv,
                                                    float* __restrict__ val, int E_) {
    int e = blockIdx.x * blockDim.x + threadIdx.x;
    if (e < E_) {
        int s = ei[e];
        int d = ei[E_ + e];
        int pos = row_ptr[d] + rank[e];
        val[pos] = dinv[s] * w[e] * dinv[d];
    }
}

// One wave per dst node. float4 gathers: quarter q of the wave fetches source row
// s_q (16 lanes x float4 = 256B row), so one wave-instruction covers 4 edges (1KB).
__global__ __launch_bounds__(256) void hop_kernel(const float* __restrict__ xin,
                                                  float* __restrict__ xout,
                                                  const float* __restrict__ dinv,
                                                  const int* __restrict__ row_ptr,
                                                  const int* __restrict__ col,
                                                  const float* __restrict__ val, int N_) {
    int wave = (blockIdx.x * blockDim.x + threadIdx.x) >> 6;
    int lane = threadIdx.x & 63;
    if (wave >= N_) return;
    const int d  = wave;
    const int q  = lane >> 4;      // quarter 0..3
    const int fl = lane & 15;      // float4 slot within row

    int e0 = row_ptr[d], e1 = row_ptr[d + 1];
    int nE = e1 - e0;
    float di = dinv[d];
    float4 selfv = ((const float4*)(xin + (size_t)d * 64))[fl];   // prefetch self row
    float4 acc = make_float4(0.f, 0.f, 0.f, 0.f);

    for (int eb = 0; eb < nE; eb += 64) {
        int m = min(64, nE - eb);
        bool ok = lane < m;
        int   cs = ok ? col[e0 + eb + lane] : d;    // pad: self row, weight 0
        float vs = ok ? val[e0 + eb + lane] : 0.f;
        for (int g = 0; g < m; g += 8) {
            int   s0 = __shfl(cs, g + q);
            int   s1 = __shfl(cs, g + 4 + q);
            float v0 = __shfl(vs, g + q);
            float v1 = __shfl(vs, g + 4 + q);
            float4 x0 = ((const float4*)(xin + (size_t)s0 * 64))[fl];
            float4 x1 = ((const float4*)(xin + (size_t)s1 * 64))[fl];
            acc.x = fmaf(v0, x0.x, acc.x); acc.y = fmaf(v0, x0.y, acc.y);
            acc.z = fmaf(v0, x0.z, acc.z); acc.w = fmaf(v0, x0.w, acc.w);
            acc.x = fmaf(v1, x1.x, acc.x); acc.y = fmaf(v1, x1.y, acc.y);
            acc.z = fmaf(v1, x1.z, acc.z); acc.w = fmaf(v1, x1.w, acc.w);
        }
    }
    acc.x += __shfl_xor(acc.x, 16); acc.y += __shfl_xor(acc.y, 16);
    acc.z += __shfl_xor(acc.z, 16); acc.w += __shfl_xor(acc.w, 16);
    acc.x += __shfl_xor(acc.x, 32); acc.y += __shfl_xor(acc.y, 32);
    acc.z += __shfl_xor(acc.z, 32); acc.w += __shfl_xor(acc.w, 32);
    float dii = di * di;
    acc.x = fmaf(dii, selfv.x, acc.x); acc.y = fmaf(dii, selfv.y, acc.y);
    acc.z = fmaf(dii, selfv.z, acc.z); acc.w = fmaf(dii, selfv.w, acc.w);
    if (lane < 16)
        ((float4*)(xout + (size_t)d * 64))[fl] = acc;
}

// LDS-tiled GEMM: out[n][f] = (relu?)(sum_k h[n][k]*W[f][k] + b[f]).
// BM=64 nodes/block, 256 threads as 16 node-groups x 16 f-groups,
// thread tile = 4 nodes x 4 outs. acc16+hv16+wv16 live floats, unroll 2,
// launch_bounds(256,4) caps VGPR at 128 -> no scratch spill (R3 lesson).
// Swizzles: hs slot = kc ^ ((n>>2)&7)  (4 node-addrs -> 4 distinct slots, CF)
//           ws slot = kc ^ ((f>>2)&7)  (16 f-lanes -> 8 slots, 2-way = free)
// Same involution on write and read; logical kc pairing preserved.
template<int F, bool RELU>
__global__ __launch_bounds__(256, 4) void linear_tiled_kernel(const float* __restrict__ hin,
                                                              float* __restrict__ outp,
                                                              const float* __restrict__ W,
                                                              const float* __restrict__ b,
                                                              int N_) {
    constexpr int BM = 64;
    __shared__ float hs[BM * 64];    // 16 KB
    __shared__ float ws[64 * 64];    // 16 KB (rows >= F zeroed)
    __shared__ float bl[64];
    const int tid  = threadIdx.x;
    const int base = blockIdx.x * BM;

    // stage W swizzled, zero-pad rows >= F
    for (int u = tid; u < 64 * 16; u += 256) {
        int f = u >> 4, kc = u & 15;
        float4 v = (f < F) ? ((const float4*)W)[f * 16 + kc]
                           : make_float4(0.f, 0.f, 0.f, 0.f);
        *(float4*)&ws[f * 64 + ((kc ^ ((f >> 2) & 7)) << 2)] = v;
    }
    if (tid < 64) bl[tid] = (tid < F) ? b[tid] : 0.f;
    // stage h tile (coalesced global read, swizzled LDS write)
    const int lim = min(BM, N_ - base);
    for (int u = tid; u < BM * 16; u += 256) {
        int n = u >> 4, kc = u & 15;
        float4 v = (n < lim) ? ((const float4*)(hin + (size_t)(base + n) * 64))[kc]
                             : make_float4(0.f, 0.f, 0.f, 0.f);
        *(float4*)&hs[n * 64 + ((kc ^ ((n >> 2) & 7)) << 2)] = v;
    }
    __syncthreads();

    const int f0 = (tid & 15) << 2;    // 4-out group
    const int n0 = (tid >> 4) << 2;    // 4-node group
    float4 acc[4];
    #pragma unroll
    for (int i = 0; i < 4; ++i) acc[i] = make_float4(0.f, 0.f, 0.f, 0.f);

    #pragma unroll 2
    for (int kc = 0; kc < 16; ++kc) {
        float4 hv[4], wv[4];
        #pragma unroll
        for (int i = 0; i < 4; ++i) {
            int n = n0 + i;
            hv[i] = *(const float4*)&hs[n * 64 + ((kc ^ ((n >> 2) & 7)) << 2)];
        }
        #pragma unroll
        for (int j = 0; j < 4; ++j) {
            int f = f0 + j;
            wv[j] = *(const float4*)&ws[f * 64 + ((kc ^ ((f >> 2) & 7)) << 2)];
        }
        #pragma unroll
        for (int i = 0; i < 4; ++i) {
            // acc[i].{x,y,z,w} accumulate outs f0..f0+3 for node n0+i
            acc[i].x = fmaf(hv[i].x, wv[0].x, acc[i].x);
            acc[i].x = fmaf(hv[i].y, wv[0].y, acc[i].x);
            acc[i].x = fmaf(hv[i].z, wv[0].z, acc[i].x);
            acc[i].x = fmaf(hv[i].w, wv[0].w, acc[i].x);
            acc[i].y = fmaf(hv[i].x, wv[1].x, acc[i].y);
            acc[i].y = fmaf(hv[i].y, wv[1].y, acc[i].y);
            acc[i].y = fmaf(hv[i].z, wv[1].z, acc[i].y);
            acc[i].y = fmaf(hv[i].w, wv[1].w, acc[i].y);
            acc[i].z = fmaf(hv[i].x, wv[2].x, acc[i].z);
            acc[i].z = fmaf(hv[i].y, wv[2].y, acc[i].z);
            acc[i].z = fmaf(hv[i].z, wv[2].z, acc[i].z);
            acc[i].z = fmaf(hv[i].w, wv[2].w, acc[i].z);
            acc[i].w = fmaf(hv[i].x, wv[3].x, acc[i].w);
            acc[i].w = fmaf(hv[i].y, wv[3].y, acc[i].w);
            acc[i].w = fmaf(hv[i].z, wv[3].z, acc[i].w);
            acc[i].w = fmaf(hv[i].w, wv[3].w, acc[i].w);
        }
    }

    if (f0 < F) {
        float4 bv = *(const float4*)&bl[f0];
        #pragma unroll
        for (int i = 0; i < 4; ++i) {
            int n = base + n0 + i;
            if (n < N_) {
                float4 r;
                r.x = acc[i].x + bv.x; r.y = acc[i].y + bv.y;
                r.z = acc[i].z + bv.z; r.w = acc[i].w + bv.w;
                if (RELU) {
                    r.x = fmaxf(r.x, 0.f); r.y = fmaxf(r.y, 0.f);
                    r.z = fmaxf(r.z, 0.f); r.w = fmaxf(r.w, 0.f);
                }
                *(float4*)&outp[(size_t)n * F + f0] = r;
            }
        }
    }
}

extern "C" void kernel_launch(void* const* d_in, const int* in_sizes, int n_in,
                              void* d_out, int out_size, void* d_ws, size_t ws_size,
                              hipStream_t stream) {
    const float* x   = (const float*)d_in[0];
    const int*   ei  = (const int*)d_in[1];
    const float* w   = (const float*)d_in[2];
    const float* W1  = (const float*)d_in[3];
    const float* b1  = (const float*)d_in[4];
    const float* W2  = (const float*)d_in[5];
    const float* b2  = (const float*)d_in[6];
    float* out = (float*)d_out;

    const int N_ = in_sizes[0] / 64;        // 100000
    const int E_ = in_sizes[2];             // 1200000

    char* ws = (char*)d_ws;
    size_t off = 0;
    auto alloc = [&](size_t bytes) { size_t o = off; off += (bytes + 255) & ~(size_t)255; return o; };
    float* dinv    = (float*)(ws + alloc((size_t)N_ * 4));
    int*   cnt     = (int*)  (ws + alloc((size_t)N_ * 4));
    int*   row_ptr = (int*)  (ws + alloc(((size_t)N_ + 1) * 4));
    int*   bsums   = (int*)  (ws + alloc(1024 * 4));
    int*   rank    = (int*)  (ws + alloc((size_t)E_ * 4));
    int*   col     = (int*)  (ws + alloc((size_t)E_ * 4));
    float* val     = (float*)(ws + alloc((size_t)E_ * 4));
    float* bufA    = (float*)(ws + alloc((size_t)N_ * 64 * 4));
    float* bufB    = (float*)(ws + alloc((size_t)N_ * 64 * 4));
    (void)ws_size; (void)n_in; (void)out_size;

    const int bn = (N_ + 255) / 256;
    const int be = (E_ + 255) / 256;
    const int bh = (N_ + 3) / 4;                       // hop: 4 waves (nodes) per block
    const int nb = (N_ + SCAN_CHUNK - 1) / SCAN_CHUNK; // 49 blocks (<=1024)
    const int bl_ = (N_ + 63) / 64;                    // linear: BM=64 tiles

    zero_cnt_kernel<<<bn, 256, 0, stream>>>(cnt, N_);
    count_rank_kernel<<<be, 256, 0, stream>>>(ei, cnt, rank, E_);
    scan_partial_kernel<<<nb, SCAN_TPB, 0, stream>>>(cnt, bsums, N_);
    scan_bsums_kernel<<<1, 1024, 0, stream>>>(bsums, nb, row_ptr, N_);
    scan_final_kernel<<<nb, SCAN_TPB, 0, stream>>>(cnt, bsums, row_ptr, N_);
    fill_kernel<<<be, 256, 0, stream>>>(ei, w, row_ptr, rank, col, val, E_);
    deg_dinv_kernel<<<bn, 256, 0, stream>>>(val, row_ptr, dinv, N_);
    scale_kernel<<<be, 256, 0, stream>>>(ei, w, row_ptr, rank, dinv, val, E_);

    hop_kernel<<<bh, 256, 0, stream>>>(x,    bufA, dinv, row_ptr, col, val, N_);
    hop_kernel<<<bh, 256, 0, stream>>>(bufA, bufB, dinv, row_ptr, col, val, N_);
    linear_tiled_kernel<64, true><<<bl_, 256, 0, stream>>>(bufB, bufA, W1, b1, N_);
    hop_kernel<<<bh, 256, 0, stream>>>(bufA, bufB, dinv, row_ptr, col, val, N_);
    hop_kernel<<<bh, 256, 0, stream>>>(bufB, bufA, dinv, row_ptr, col, val, N_);
    linear_tiled_kernel<40, false><<<bl_, 256, 0, stream>>>(bufA, out, W2, b2, N_);
}

// Round 6
// 336.243 us; speedup vs baseline: 2.0251x; 1.0788x over previous
//
#include <hip/hip_runtime.h>

// SGConv (K=2, two layers) on MI355X.
// R2: single-atomic CSR build (rank trick), float4 gather hop.
// R3: GEMM linears regressed (VGPR spill, 580MB scratch). R4: fixed (4x4 tile).
// R5: packed int2 CSR payload (1 scattered 8B store/edge instead of 2x4B ->
//     halves write amplification), scale pass now CSR-ordered (coalesced,
//     replaces scattered-write pass), hop pipelines 4 gathers in flight.

#define SCAN_TPB 256
#define SCAN_ITEMS 8
#define SCAN_CHUNK (SCAN_TPB * SCAN_ITEMS)   // 2048 elements per block

__global__ __launch_bounds__(256) void zero_cnt_kernel(int* cnt, int N_) {
    int n = blockIdx.x * blockDim.x + threadIdx.x;
    if (n < N_) cnt[n] = 0;
}

// rank[e] = arrival index of edge e within its dst bucket. ONLY atomic pass.
__global__ __launch_bounds__(256) void count_rank_kernel(const int* __restrict__ ei,
                                                         int* cnt, int* __restrict__ rank, int E_) {
    int e = blockIdx.x * blockDim.x + threadIdx.x;
    if (e < E_) rank[e] = atomicAdd(&cnt[ei[E_ + e]], 1);
}

// --- 3-phase hierarchical exclusive scan of cnt -> row_ptr ---

__global__ __launch_bounds__(SCAN_TPB) void scan_partial_kernel(const int* __restrict__ cnt,
                                                                int* __restrict__ bsums, int N_) {
    int t = threadIdx.x;
    int base = blockIdx.x * SCAN_CHUNK + t * SCAN_ITEMS;
    int s = 0;
    #pragma unroll
    for (int j = 0; j < SCAN_ITEMS; ++j) { int i = base + j; if (i < N_) s += cnt[i]; }
    __shared__ int sm[SCAN_TPB];
    sm[t] = s; __syncthreads();
    for (int o = SCAN_TPB / 2; o > 0; o >>= 1) {
        if (t < o) sm[t] += sm[t + o];
        __syncthreads();
    }
    if (t == 0) bsums[blockIdx.x] = sm[0];
}

__global__ __launch_bounds__(1024) void scan_bsums_kernel(int* bsums, int nb,
                                                          int* row_ptr, int N_) {
    __shared__ int sm[1024];
    int t = threadIdx.x;
    int v = (t < nb) ? bsums[t] : 0;
    sm[t] = v; __syncthreads();
    for (int o = 1; o < 1024; o <<= 1) {
        int u = (t >= o) ? sm[t - o] : 0;
        __syncthreads();
        sm[t] += u;
        __syncthreads();
    }
    if (t < nb) bsums[t] = sm[t] - v;          // exclusive block offset
    if (t == 1023) row_ptr[N_] = sm[1023];     // grand total
}

__global__ __launch_bounds__(SCAN_TPB) void scan_final_kernel(const int* __restrict__ cnt,
                                                              const int* __restrict__ bsums,
                                                              int* __restrict__ row_ptr, int N_) {
    int t = threadIdx.x;
    int base = blockIdx.x * SCAN_CHUNK + t * SCAN_ITEMS;
    int loc[SCAN_ITEMS];
    int s = 0;
    #pragma unroll
    for (int j = 0; j < SCAN_ITEMS; ++j) {
        int i = base + j;
        int c = (i < N_) ? cnt[i] : 0;
        loc[j] = s; s += c;
    }
    __shared__ int sm[SCAN_TPB];
    sm[t] = s; __syncthreads();
    for (int o = 1; o < SCAN_TPB; o <<= 1) {
        int u = (t >= o) ? sm[t - o] : 0;
        __syncthreads();
        sm[t] += u;
        __syncthreads();
    }
    int excl = bsums[blockIdx.x] + sm[t] - s;
    #pragma unroll
    for (int j = 0; j < SCAN_ITEMS; ++j) {
        int i = base + j;
        if (i < N_) row_ptr[i] = excl + loc[j];
    }
}

// Atomic-free CSR fill: ONE scattered 8B store per edge {src, w_bits}.
__global__ __launch_bounds__(256) void fill_kernel(const int* __restrict__ ei,
                                                   const float* __restrict__ w,
                                                   const int* __restrict__ row_ptr,
                                                   const int* __restrict__ rank,
                                                   int2* __restrict__ edge, int E_) {
    int e = blockIdx.x * blockDim.x + threadIdx.x;
    if (e < E_) {
        int d = ei[E_ + e];
        int pos = row_ptr[d] + rank[e];
        edge[pos] = make_int2(ei[e], __float_as_int(w[e]));
    }
}

// deg[d] = 1 (self-loop) + sum of row d's weights; dinv = 1/sqrt(deg).
__global__ __launch_bounds__(256) void deg_dinv_kernel(const int2* __restrict__ edge,
                                                       const int* __restrict__ row_ptr,
                                                       float* __restrict__ dinv, int N_) {
    int n = blockIdx.x * blockDim.x + threadIdx.x;
    if (n < N_) {
        float s = 1.0f;
        int p0 = row_ptr[n], p1 = row_ptr[n + 1];
        for (int p = p0; p < p1; ++p) s += __int_as_float(edge[p].y);
        dinv[n] = (s > 0.f) ? (1.0f / sqrtf(s)) : 0.f;
    }
}

// In CSR order (coalesced in aggregate): edge[p].y = w * dinv[src] * dinv[dst].
__global__ __launch_bounds__(256) void scale_csr_kernel(int2* __restrict__ edge,
                                                        const int* __restrict__ row_ptr,
                                                        const float* __restrict__ dinv, int N_) {
    int n = blockIdx.x * blockDim.x + threadIdx.x;
    if (n < N_) {
        float dd = dinv[n];
        int p0 = row_ptr[n], p1 = row_ptr[n + 1];
        for (int p = p0; p < p1; ++p) {
            int2 e = edge[p];
            edge[p].y = __float_as_int(__int_as_float(e.y) * dinv[e.x] * dd);
        }
    }
}

// One wave per dst node. Quarter q of the wave fetches source row s_q
// (16 lanes x float4 = 256B), 4 edge-gathers in flight per group of 16.
// Padded lanes point at the self row with weight 0 (L1-hot, harmless).
__global__ __launch_bounds__(256) void hop_kernel(const float* __restrict__ xin,
                                                  float* __restrict__ xout,
                                                  const float* __restrict__ dinv,
                                                  const int* __restrict__ row_ptr,
                                                  const int2* __restrict__ edge, int N_) {
    int wave = (blockIdx.x * blockDim.x + threadIdx.x) >> 6;
    int lane = threadIdx.x & 63;
    if (wave >= N_) return;
    const int d  = wave;
    const int q  = lane >> 4;      // quarter 0..3
    const int fl = lane & 15;      // float4 slot within row

    int e0 = row_ptr[d], e1 = row_ptr[d + 1];
    int nE = e1 - e0;
    float di = dinv[d];
    float4 selfv = ((const float4*)(xin + (size_t)d * 64))[fl];   // prefetch self row
    float4 acc = make_float4(0.f, 0.f, 0.f, 0.f);

    for (int eb = 0; eb < nE; eb += 64) {
        bool ok = (eb + lane) < nE;
        int2 ev = ok ? edge[e0 + eb + lane] : make_int2(d, 0);
        int m = min(64, nE - eb);
        for (int g = 0; g < m; g += 16) {
            int   s0 = __shfl(ev.x, g + q);
            int   s1 = __shfl(ev.x, g + 4 + q);
            int   s2 = __shfl(ev.x, g + 8 + q);
            int   s3 = __shfl(ev.x, g + 12 + q);
            float v0 = __shfl(__int_as_float(ev.y), g + q);
            float v1 = __shfl(__int_as_float(ev.y), g + 4 + q);
            float v2 = __shfl(__int_as_float(ev.y), g + 8 + q);
            float v3 = __shfl(__int_as_float(ev.y), g + 12 + q);
            float4 x0 = ((const float4*)(xin + (size_t)s0 * 64))[fl];
            float4 x1 = ((const float4*)(xin + (size_t)s1 * 64))[fl];
            float4 x2 = ((const float4*)(xin + (size_t)s2 * 64))[fl];
            float4 x3 = ((const float4*)(xin + (size_t)s3 * 64))[fl];
            acc.x = fmaf(v0, x0.x, acc.x); acc.y = fmaf(v0, x0.y, acc.y);
            acc.z = fmaf(v0, x0.z, acc.z); acc.w = fmaf(v0, x0.w, acc.w);
            acc.x = fmaf(v1, x1.x, acc.x); acc.y = fmaf(v1, x1.y, acc.y);
            acc.z = fmaf(v1, x1.z, acc.z); acc.w = fmaf(v1, x1.w, acc.w);
            acc.x = fmaf(v2, x2.x, acc.x); acc.y = fmaf(v2, x2.y, acc.y);
            acc.z = fmaf(v2, x2.z, acc.z); acc.w = fmaf(v2, x2.w, acc.w);
            acc.x = fmaf(v3, x3.x, acc.x); acc.y = fmaf(v3, x3.y, acc.y);
            acc.z = fmaf(v3, x3.z, acc.z); acc.w = fmaf(v3, x3.w, acc.w);
        }
    }
    acc.x += __shfl_xor(acc.x, 16); acc.y += __shfl_xor(acc.y, 16);
    acc.z += __shfl_xor(acc.z, 16); acc.w += __shfl_xor(acc.w, 16);
    acc.x += __shfl_xor(acc.x, 32); acc.y += __shfl_xor(acc.y, 32);
    acc.z += __shfl_xor(acc.z, 32); acc.w += __shfl_xor(acc.w, 32);
    float dii = di * di;
    acc.x = fmaf(dii, selfv.x, acc.x); acc.y = fmaf(dii, selfv.y, acc.y);
    acc.z = fmaf(dii, selfv.z, acc.z); acc.w = fmaf(dii, selfv.w, acc.w);
    if (lane < 16)
        ((float4*)(xout + (size_t)d * 64))[fl] = acc;
}

// LDS-tiled GEMM: out[n][f] = (relu?)(sum_k h[n][k]*W[f][k] + b[f]).
// BM=64, 256 threads as 16x16 groups, 4 nodes x 4 outs per thread, unroll 2,
// launch_bounds(256,4) caps VGPR at 128 -> no scratch spill (R3 lesson).
template<int F, bool RELU>
__global__ __launch_bounds__(256, 4) void linear_tiled_kernel(const float* __restrict__ hin,
                                                              float* __restrict__ outp,
                                                              const float* __restrict__ W,
                                                              const float* __restrict__ b,
                                                              int N_) {
    constexpr int BM = 64;
    __shared__ float hs[BM * 64];    // 16 KB
    __shared__ float ws[64 * 64];    // 16 KB (rows >= F zeroed)
    __shared__ float bl[64];
    const int tid  = threadIdx.x;
    const int base = blockIdx.x * BM;

    for (int u = tid; u < 64 * 16; u += 256) {
        int f = u >> 4, kc = u & 15;
        float4 v = (f < F) ? ((const float4*)W)[f * 16 + kc]
                           : make_float4(0.f, 0.f, 0.f, 0.f);
        *(float4*)&ws[f * 64 + ((kc ^ ((f >> 2) & 7)) << 2)] = v;
    }
    if (tid < 64) bl[tid] = (tid < F) ? b[tid] : 0.f;
    const int lim = min(BM, N_ - base);
    for (int u = tid; u < BM * 16; u += 256) {
        int n = u >> 4, kc = u & 15;
        float4 v = (n < lim) ? ((const float4*)(hin + (size_t)(base + n) * 64))[kc]
                             : make_float4(0.f, 0.f, 0.f, 0.f);
        *(float4*)&hs[n * 64 + ((kc ^ ((n >> 2) & 7)) << 2)] = v;
    }
    __syncthreads();

    const int f0 = (tid & 15) << 2;
    const int n0 = (tid >> 4) << 2;
    float4 acc[4];
    #pragma unroll
    for (int i = 0; i < 4; ++i) acc[i] = make_float4(0.f, 0.f, 0.f, 0.f);

    #pragma unroll 2
    for (int kc = 0; kc < 16; ++kc) {
        float4 hv[4], wv[4];
        #pragma unroll
        for (int i = 0; i < 4; ++i) {
            int n = n0 + i;
            hv[i] = *(const float4*)&hs[n * 64 + ((kc ^ ((n >> 2) & 7)) << 2)];
        }
        #pragma unroll
        for (int j = 0; j < 4; ++j) {
            int f = f0 + j;
            wv[j] = *(const float4*)&ws[f * 64 + ((kc ^ ((f >> 2) & 7)) << 2)];
        }
        #pragma unroll
        for (int i = 0; i < 4; ++i) {
            acc[i].x = fmaf(hv[i].x, wv[0].x, acc[i].x);
            acc[i].x = fmaf(hv[i].y, wv[0].y, acc[i].x);
            acc[i].x = fmaf(hv[i].z, wv[0].z, acc[i].x);
            acc[i].x = fmaf(hv[i].w, wv[0].w, acc[i].x);
            acc[i].y = fmaf(hv[i].x, wv[1].x, acc[i].y);
            acc[i].y = fmaf(hv[i].y, wv[1].y, acc[i].y);
            acc[i].y = fmaf(hv[i].z, wv[1].z, acc[i].y);
            acc[i].y = fmaf(hv[i].w, wv[1].w, acc[i].y);
            acc[i].z = fmaf(hv[i].x, wv[2].x, acc[i].z);
            acc[i].z = fmaf(hv[i].y, wv[2].y, acc[i].z);
            acc[i].z = fmaf(hv[i].z, wv[2].z, acc[i].z);
            acc[i].z = fmaf(hv[i].w, wv[2].w, acc[i].z);
            acc[i].w = fmaf(hv[i].x, wv[3].x, acc[i].w);
            acc[i].w = fmaf(hv[i].y, wv[3].y, acc[i].w);
            acc[i].w = fmaf(hv[i].z, wv[3].z, acc[i].w);
            acc[i].w = fmaf(hv[i].w, wv[3].w, acc[i].w);
        }
    }

    if (f0 < F) {
        float4 bv = *(const float4*)&bl[f0];
        #pragma unroll
        for (int i = 0; i < 4; ++i) {
            int n = base + n0 + i;
            if (n < N_) {
                float4 r;
                r.x = acc[i].x + bv.x; r.y = acc[i].y + bv.y;
                r.z = acc[i].z + bv.z; r.w = acc[i].w + bv.w;
                if (RELU) {
                    r.x = fmaxf(r.x, 0.f); r.y = fmaxf(r.y, 0.f);
                    r.z = fmaxf(r.z, 0.f); r.w = fmaxf(r.w, 0.f);
                }
                *(float4*)&outp[(size_t)n * F + f0] = r;
            }
        }
    }
}

extern "C" void kernel_launch(void* const* d_in, const int* in_sizes, int n_in,
                              void* d_out, int out_size, void* d_ws, size_t ws_size,
                              hipStream_t stream) {
    const float* x   = (const float*)d_in[0];
    const int*   ei  = (const int*)d_in[1];
    const float* w   = (const float*)d_in[2];
    const float* W1  = (const float*)d_in[3];
    const float* b1  = (const float*)d_in[4];
    const float* W2  = (const float*)d_in[5];
    const float* b2  = (const float*)d_in[6];
    float* out = (float*)d_out;

    const int N_ = in_sizes[0] / 64;        // 100000
    const int E_ = in_sizes[2];             // 1200000

    char* ws = (char*)d_ws;
    size_t off = 0;
    auto alloc = [&](size_t bytes) { size_t o = off; off += (bytes + 255) & ~(size_t)255; return o; };
    float* dinv    = (float*)(ws + alloc((size_t)N_ * 4));
    int*   cnt     = (int*)  (ws + alloc((size_t)N_ * 4));
    int*   row_ptr = (int*)  (ws + alloc(((size_t)N_ + 1) * 4));
    int*   bsums   = (int*)  (ws + alloc(1024 * 4));
    int*   rank    = (int*)  (ws + alloc((size_t)E_ * 4));
    int2*  edge    = (int2*) (ws + alloc((size_t)E_ * 8));
    float* bufA    = (float*)(ws + alloc((size_t)N_ * 64 * 4));
    float* bufB    = (float*)(ws + alloc((size_t)N_ * 64 * 4));
    (void)ws_size; (void)n_in; (void)out_size;

    const int bn = (N_ + 255) / 256;
    const int be = (E_ + 255) / 256;
    const int bh = (N_ + 3) / 4;                       // hop: 4 waves (nodes) per block
    const int nb = (N_ + SCAN_CHUNK - 1) / SCAN_CHUNK; // 49 blocks (<=1024)
    const int bl_ = (N_ + 63) / 64;                    // linear: BM=64 tiles

    zero_cnt_kernel<<<bn, 256, 0, stream>>>(cnt, N_);
    count_rank_kernel<<<be, 256, 0, stream>>>(ei, cnt, rank, E_);
    scan_partial_kernel<<<nb, SCAN_TPB, 0, stream>>>(cnt, bsums, N_);
    scan_bsums_kernel<<<1, 1024, 0, stream>>>(bsums, nb, row_ptr, N_);
    scan_final_kernel<<<nb, SCAN_TPB, 0, stream>>>(cnt, bsums, row_ptr, N_);
    fill_kernel<<<be, 256, 0, stream>>>(ei, w, row_ptr, rank, edge, E_);
    deg_dinv_kernel<<<bn, 256, 0, stream>>>(edge, row_ptr, dinv, N_);
    scale_csr_kernel<<<bn, 256, 0, stream>>>(edge, row_ptr, dinv, N_);

    hop_kernel<<<bh, 256, 0, stream>>>(x,    bufA, dinv, row_ptr, edge, N_);
    hop_kernel<<<bh, 256, 0, stream>>>(bufA, bufB, dinv, row_ptr, edge, N_);
    linear_tiled_kernel<64, true><<<bl_, 256, 0, stream>>>(bufB, bufA, W1, b1, N_);
    hop_kernel<<<bh, 256, 0, stream>>>(bufA, bufB, dinv, row_ptr, edge, N_);
    hop_kernel<<<bh, 256, 0, stream>>>(bufB, bufA, dinv, row_ptr, edge, N_);
    linear_tiled_kernel<40, false><<<bl_, 256, 0, stream>>>(bufA, out, W2, b2, N_);
}

// Round 7
// 300.188 us; speedup vs baseline: 2.2684x; 1.1201x over previous
//
#include <hip/hip_runtime.h>

// SGConv (K=2, two layers) on MI355X.
// R2: rank-trick CSR build. R4: 4x4-tile GEMM linears (no spill).
// R5: packed int2 CSR payload, CSR-ordered scale, 4-deep hop gathers.
// R6: atomic-free CSR build via 2-phase counting sort. The old count_rank
//     (1.2M device-scope atomics = memory-side RMW, 52us) and fill (scattered
//     stores, ~35us) are replaced by LDS-histogram passes: coarse bucket
//     (dst>>7, 782 bins) count -> hierarchical scan -> bucket scatter ->
//     per-bucket fine (128 bins) count+scan+place. All atomics LDS-scope.

#define SCAN_TPB 256
#define SCAN_ITEMS 8
#define SCAN_CHUNK (SCAN_TPB * SCAN_ITEMS)   // 2048 elements per block
#define P1_EDGES 4096                        // edges per phase-1 block
#define MAX_NB 784                           // coarse buckets (ceil(100000/128)=782)

// --- 3-phase hierarchical exclusive scan (generic: cnt[] -> out[], out[M]=total) ---

__global__ __launch_bounds__(SCAN_TPB) void scan_partial_kernel(const int* __restrict__ cnt,
                                                                int* __restrict__ bsums, int N_) {
    int t = threadIdx.x;
    int base = blockIdx.x * SCAN_CHUNK + t * SCAN_ITEMS;
    int s = 0;
    #pragma unroll
    for (int j = 0; j < SCAN_ITEMS; ++j) { int i = base + j; if (i < N_) s += cnt[i]; }
    __shared__ int sm[SCAN_TPB];
    sm[t] = s; __syncthreads();
    for (int o = SCAN_TPB / 2; o > 0; o >>= 1) {
        if (t < o) sm[t] += sm[t + o];
        __syncthreads();
    }
    if (t == 0) bsums[blockIdx.x] = sm[0];
}

__global__ __launch_bounds__(1024) void scan_bsums_kernel(int* bsums, int nb,
                                                          int* out, int N_) {
    __shared__ int sm[1024];
    int t = threadIdx.x;
    int v = (t < nb) ? bsums[t] : 0;
    sm[t] = v; __syncthreads();
    for (int o = 1; o < 1024; o <<= 1) {
        int u = (t >= o) ? sm[t - o] : 0;
        __syncthreads();
        sm[t] += u;
        __syncthreads();
    }
    if (t < nb) bsums[t] = sm[t] - v;          // exclusive block offset
    if (t == 1023) out[N_] = sm[1023];         // grand total
}

__global__ __launch_bounds__(SCAN_TPB) void scan_final_kernel(const int* __restrict__ cnt,
                                                              const int* __restrict__ bsums,
                                                              int* __restrict__ out, int N_) {
    int t = threadIdx.x;
    int base = blockIdx.x * SCAN_CHUNK + t * SCAN_ITEMS;
    int loc[SCAN_ITEMS];
    int s = 0;
    #pragma unroll
    for (int j = 0; j < SCAN_ITEMS; ++j) {
        int i = base + j;
        int c = (i < N_) ? cnt[i] : 0;
        loc[j] = s; s += c;
    }
    __shared__ int sm[SCAN_TPB];
    sm[t] = s; __syncthreads();
    for (int o = 1; o < SCAN_TPB; o <<= 1) {
        int u = (t >= o) ? sm[t - o] : 0;
        __syncthreads();
        sm[t] += u;
        __syncthreads();
    }
    int excl = bsums[blockIdx.x] + sm[t] - s;
    #pragma unroll
    for (int j = 0; j < SCAN_ITEMS; ++j) {
        int i = base + j;
        if (i < N_) out[i] = excl + loc[j];
    }
}

// --- Phase 1: coarse bucket (dst>>7) LDS histogram per 4096-edge block ---
__global__ __launch_bounds__(256) void p1_count_kernel(const int* __restrict__ ei,
                                                       int* __restrict__ coarseCnt,
                                                       int E_, int PB, int NB) {
    __shared__ int hist[MAX_NB];
    int tid = threadIdx.x;
    for (int u = tid; u < NB; u += 256) hist[u] = 0;
    __syncthreads();
    int base = blockIdx.x * P1_EDGES;
    #pragma unroll 4
    for (int j = 0; j < P1_EDGES / 256; ++j) {
        int e = base + j * 256 + tid;
        if (e < E_) atomicAdd(&hist[ei[E_ + e] >> 7], 1);
    }
    __syncthreads();
    for (int u = tid; u < NB; u += 256) coarseCnt[u * PB + blockIdx.x] = hist[u];
}

// Scatter edges into coarse-bucket-sorted order. LDS cursor = coarseOff column.
// Payload packs fine node id (dst&127) into src's upper bits: src<2^17, fine<2^7.
__global__ __launch_bounds__(256) void p1_scatter_kernel(const int* __restrict__ ei,
                                                         const float* __restrict__ w,
                                                         const int* __restrict__ coarseOff,
                                                         int2* __restrict__ sorted,
                                                         int E_, int PB, int NB) {
    __shared__ int lcur[MAX_NB];
    int tid = threadIdx.x;
    for (int u = tid; u < NB; u += 256) lcur[u] = coarseOff[u * PB + blockIdx.x];
    __syncthreads();
    int base = blockIdx.x * P1_EDGES;
    #pragma unroll 4
    for (int j = 0; j < P1_EDGES / 256; ++j) {
        int e = base + j * 256 + tid;
        if (e < E_) {
            int dst = ei[E_ + e];
            int b = dst >> 7;
            int pos = atomicAdd(&lcur[b], 1);
            sorted[pos] = make_int2(ei[e] | ((dst & 127) << 17), __float_as_int(w[e]));
        }
    }
}

// --- Phase 2: one block per coarse bucket. 128-bin fine histogram + scan in LDS,
// emit row_ptr for the bucket's nodes and the final CSR edge array. ---
__global__ __launch_bounds__(256) void p2_fine_kernel(const int2* __restrict__ sorted,
                                                      const int* __restrict__ coarseOff,
                                                      int2* __restrict__ edge,
                                                      int* __restrict__ row_ptr,
                                                      int N_, int E_, int PB, int NB) {
    __shared__ int fcnt[128], fexc[128], fcur[128];
    const int b = blockIdx.x;
    const int tid = threadIdx.x;
    const int start = coarseOff[b * PB];
    const int end = (b + 1 < NB) ? coarseOff[(b + 1) * PB] : E_;
    if (tid < 128) fcnt[tid] = 0;
    __syncthreads();
    for (int p = start + tid; p < end; p += 256)
        atomicAdd(&fcnt[sorted[p].x >> 17], 1);
    __syncthreads();
    if (tid < 128) fexc[tid] = fcnt[tid];
    __syncthreads();
    for (int o = 1; o < 128; o <<= 1) {
        int v = (tid < 128 && tid >= o) ? fexc[tid - o] : 0;
        __syncthreads();
        if (tid < 128) fexc[tid] += v;
        __syncthreads();
    }
    const int node0 = b << 7;
    if (tid < 128) {
        fexc[tid] -= fcnt[tid];          // inclusive -> exclusive
        fcur[tid] = 0;
        int node = node0 + tid;
        if (node < N_) row_ptr[node] = start + fexc[tid];
    }
    __syncthreads();
    for (int p = start + tid; p < end; p += 256) {
        int2 pk = sorted[p];
        int fine = pk.x >> 17;
        int src  = pk.x & 0x1FFFF;
        int r = atomicAdd(&fcur[fine], 1);
        edge[start + fexc[fine] + r] = make_int2(src, pk.y);
    }
    if (b == 0 && tid == 0) row_ptr[N_] = E_;
}

// deg[d] = 1 (self-loop) + sum of row d's weights; dinv = 1/sqrt(deg).
__global__ __launch_bounds__(256) void deg_dinv_kernel(const int2* __restrict__ edge,
                                                       const int* __restrict__ row_ptr,
                                                       float* __restrict__ dinv, int N_) {
    int n = blockIdx.x * blockDim.x + threadIdx.x;
    if (n < N_) {
        float s = 1.0f;
        int p0 = row_ptr[n], p1 = row_ptr[n + 1];
        for (int p = p0; p < p1; ++p) s += __int_as_float(edge[p].y);
        dinv[n] = (s > 0.f) ? (1.0f / sqrtf(s)) : 0.f;
    }
}

// In CSR order (coalesced in aggregate): edge[p].y = w * dinv[src] * dinv[dst].
__global__ __launch_bounds__(256) void scale_csr_kernel(int2* __restrict__ edge,
                                                        const int* __restrict__ row_ptr,
                                                        const float* __restrict__ dinv, int N_) {
    int n = blockIdx.x * blockDim.x + threadIdx.x;
    if (n < N_) {
        float dd = dinv[n];
        int p0 = row_ptr[n], p1 = row_ptr[n + 1];
        for (int p = p0; p < p1; ++p) {
            int2 e = edge[p];
            edge[p].y = __float_as_int(__int_as_float(e.y) * dinv[e.x] * dd);
        }
    }
}

// One wave per dst node. Quarter q of the wave fetches source row s_q
// (16 lanes x float4 = 256B), 4 edge-gathers in flight per group of 16.
__global__ __launch_bounds__(256) void hop_kernel(const float* __restrict__ xin,
                                                  float* __restrict__ xout,
                                                  const float* __restrict__ dinv,
                                                  const int* __restrict__ row_ptr,
                                                  const int2* __restrict__ edge, int N_) {
    int wave = (blockIdx.x * blockDim.x + threadIdx.x) >> 6;
    int lane = threadIdx.x & 63;
    if (wave >= N_) return;
    const int d  = wave;
    const int q  = lane >> 4;      // quarter 0..3
    const int fl = lane & 15;      // float4 slot within row

    int e0 = row_ptr[d], e1 = row_ptr[d + 1];
    int nE = e1 - e0;
    float di = dinv[d];
    float4 selfv = ((const float4*)(xin + (size_t)d * 64))[fl];   // prefetch self row
    float4 acc = make_float4(0.f, 0.f, 0.f, 0.f);

    for (int eb = 0; eb < nE; eb += 64) {
        bool ok = (eb + lane) < nE;
        int2 ev = ok ? edge[e0 + eb + lane] : make_int2(d, 0);
        int m = min(64, nE - eb);
        for (int g = 0; g < m; g += 16) {
            int   s0 = __shfl(ev.x, g + q);
            int   s1 = __shfl(ev.x, g + 4 + q);
            int   s2 = __shfl(ev.x, g + 8 + q);
            int   s3 = __shfl(ev.x, g + 12 + q);
            float v0 = __shfl(__int_as_float(ev.y), g + q);
            float v1 = __shfl(__int_as_float(ev.y), g + 4 + q);
            float v2 = __shfl(__int_as_float(ev.y), g + 8 + q);
            float v3 = __shfl(__int_as_float(ev.y), g + 12 + q);
            float4 x0 = ((const float4*)(xin + (size_t)s0 * 64))[fl];
            float4 x1 = ((const float4*)(xin + (size_t)s1 * 64))[fl];
            float4 x2 = ((const float4*)(xin + (size_t)s2 * 64))[fl];
            float4 x3 = ((const float4*)(xin + (size_t)s3 * 64))[fl];
            acc.x = fmaf(v0, x0.x, acc.x); acc.y = fmaf(v0, x0.y, acc.y);
            acc.z = fmaf(v0, x0.z, acc.z); acc.w = fmaf(v0, x0.w, acc.w);
            acc.x = fmaf(v1, x1.x, acc.x); acc.y = fmaf(v1, x1.y, acc.y);
            acc.z = fmaf(v1, x1.z, acc.z); acc.w = fmaf(v1, x1.w, acc.w);
            acc.x = fmaf(v2, x2.x, acc.x); acc.y = fmaf(v2, x2.y, acc.y);
            acc.z = fmaf(v2, x2.z, acc.z); acc.w = fmaf(v2, x2.w, acc.w);
            acc.x = fmaf(v3, x3.x, acc.x); acc.y = fmaf(v3, x3.y, acc.y);
            acc.z = fmaf(v3, x3.z, acc.z); acc.w = fmaf(v3, x3.w, acc.w);
        }
    }
    acc.x += __shfl_xor(acc.x, 16); acc.y += __shfl_xor(acc.y, 16);
    acc.z += __shfl_xor(acc.z, 16); acc.w += __shfl_xor(acc.w, 16);
    acc.x += __shfl_xor(acc.x, 32); acc.y += __shfl_xor(acc.y, 32);
    acc.z += __shfl_xor(acc.z, 32); acc.w += __shfl_xor(acc.w, 32);
    float dii = di * di;
    acc.x = fmaf(dii, selfv.x, acc.x); acc.y = fmaf(dii, selfv.y, acc.y);
    acc.z = fmaf(dii, selfv.z, acc.z); acc.w = fmaf(dii, selfv.w, acc.w);
    if (lane < 16)
        ((float4*)(xout + (size_t)d * 64))[fl] = acc;
}

// LDS-tiled GEMM: out[n][f] = (relu?)(sum_k h[n][k]*W[f][k] + b[f]).
// BM=64, 256 threads as 16x16 groups, 4 nodes x 4 outs per thread, unroll 2,
// launch_bounds(256,4) caps VGPR at 128 -> no scratch spill (R3 lesson).
template<int F, bool RELU>
__global__ __launch_bounds__(256, 4) void linear_tiled_kernel(const float* __restrict__ hin,
                                                              float* __restrict__ outp,
                                                              const float* __restrict__ W,
                                                              const float* __restrict__ b,
                                                              int N_) {
    constexpr int BM = 64;
    __shared__ float hs[BM * 64];    // 16 KB
    __shared__ float ws[64 * 64];    // 16 KB (rows >= F zeroed)
    __shared__ float bl[64];
    const int tid  = threadIdx.x;
    const int base = blockIdx.x * BM;

    for (int u = tid; u < 64 * 16; u += 256) {
        int f = u >> 4, kc = u & 15;
        float4 v = (f < F) ? ((const float4*)W)[f * 16 + kc]
                           : make_float4(0.f, 0.f, 0.f, 0.f);
        *(float4*)&ws[f * 64 + ((kc ^ ((f >> 2) & 7)) << 2)] = v;
    }
    if (tid < 64) bl[tid] = (tid < F) ? b[tid] : 0.f;
    const int lim = min(BM, N_ - base);
    for (int u = tid; u < BM * 16; u += 256) {
        int n = u >> 4, kc = u & 15;
        float4 v = (n < lim) ? ((const float4*)(hin + (size_t)(base + n) * 64))[kc]
                             : make_float4(0.f, 0.f, 0.f, 0.f);
        *(float4*)&hs[n * 64 + ((kc ^ ((n >> 2) & 7)) << 2)] = v;
    }
    __syncthreads();

    const int f0 = (tid & 15) << 2;
    const int n0 = (tid >> 4) << 2;
    float4 acc[4];
    #pragma unroll
    for (int i = 0; i < 4; ++i) acc[i] = make_float4(0.f, 0.f, 0.f, 0.f);

    #pragma unroll 2
    for (int kc = 0; kc < 16; ++kc) {
        float4 hv[4], wv[4];
        #pragma unroll
        for (int i = 0; i < 4; ++i) {
            int n = n0 + i;
            hv[i] = *(const float4*)&hs[n * 64 + ((kc ^ ((n >> 2) & 7)) << 2)];
        }
        #pragma unroll
        for (int j = 0; j < 4; ++j) {
            int f = f0 + j;
            wv[j] = *(const float4*)&ws[f * 64 + ((kc ^ ((f >> 2) & 7)) << 2)];
        }
        #pragma unroll
        for (int i = 0; i < 4; ++i) {
            acc[i].x = fmaf(hv[i].x, wv[0].x, acc[i].x);
            acc[i].x = fmaf(hv[i].y, wv[0].y, acc[i].x);
            acc[i].x = fmaf(hv[i].z, wv[0].z, acc[i].x);
            acc[i].x = fmaf(hv[i].w, wv[0].w, acc[i].x);
            acc[i].y = fmaf(hv[i].x, wv[1].x, acc[i].y);
            acc[i].y = fmaf(hv[i].y, wv[1].y, acc[i].y);
            acc[i].y = fmaf(hv[i].z, wv[1].z, acc[i].y);
            acc[i].y = fmaf(hv[i].w, wv[1].w, acc[i].y);
            acc[i].z = fmaf(hv[i].x, wv[2].x, acc[i].z);
            acc[i].z = fmaf(hv[i].y, wv[2].y, acc[i].z);
            acc[i].z = fmaf(hv[i].z, wv[2].z, acc[i].z);
            acc[i].z = fmaf(hv[i].w, wv[2].w, acc[i].z);
            acc[i].w = fmaf(hv[i].x, wv[3].x, acc[i].w);
            acc[i].w = fmaf(hv[i].y, wv[3].y, acc[i].w);
            acc[i].w = fmaf(hv[i].z, wv[3].z, acc[i].w);
            acc[i].w = fmaf(hv[i].w, wv[3].w, acc[i].w);
        }
    }

    if (f0 < F) {
        float4 bv = *(const float4*)&bl[f0];
        #pragma unroll
        for (int i = 0; i < 4; ++i) {
            int n = base + n0 + i;
            if (n < N_) {
                float4 r;
                r.x = acc[i].x + bv.x; r.y = acc[i].y + bv.y;
                r.z = acc[i].z + bv.z; r.w = acc[i].w + bv.w;
                if (RELU) {
                    r.x = fmaxf(r.x, 0.f); r.y = fmaxf(r.y, 0.f);
                    r.z = fmaxf(r.z, 0.f); r.w = fmaxf(r.w, 0.f);
                }
                *(float4*)&outp[(size_t)n * F + f0] = r;
            }
        }
    }
}

extern "C" void kernel_launch(void* const* d_in, const int* in_sizes, int n_in,
                              void* d_out, int out_size, void* d_ws, size_t ws_size,
                              hipStream_t stream) {
    const float* x   = (const float*)d_in[0];
    const int*   ei  = (const int*)d_in[1];
    const float* w   = (const float*)d_in[2];
    const float* W1  = (const float*)d_in[3];
    const float* b1  = (const float*)d_in[4];
    const float* W2  = (const float*)d_in[5];
    const float* b2  = (const float*)d_in[6];
    float* out = (float*)d_out;

    const int N_ = in_sizes[0] / 64;        // 100000
    const int E_ = in_sizes[2];             // 1200000
    const int PB = (E_ + P1_EDGES - 1) / P1_EDGES;   // 293 phase-1 blocks
    const int NB = (N_ + 127) >> 7;                  // 782 coarse buckets (<= MAX_NB)
    const int M  = NB * PB;                          // 229,126 coarse counters

    char* ws = (char*)d_ws;
    size_t off = 0;
    auto alloc = [&](size_t bytes) { size_t o = off; off += (bytes + 255) & ~(size_t)255; return o; };
    float* dinv      = (float*)(ws + alloc((size_t)N_ * 4));
    int*   row_ptr   = (int*)  (ws + alloc(((size_t)N_ + 1) * 4));
    int*   bsums     = (int*)  (ws + alloc(1024 * 4));
    int*   coarseCnt = (int*)  (ws + alloc((size_t)M * 4));
    int*   coarseOff = (int*)  (ws + alloc(((size_t)M + 1) * 4));
    int2*  edge      = (int2*) (ws + alloc((size_t)E_ * 8));
    float* bufA      = (float*)(ws + alloc((size_t)N_ * 64 * 4));
    float* bufB      = (float*)(ws + alloc((size_t)N_ * 64 * 4));
    int2*  sorted    = (int2*)bufA;    // alias: dead before hop1 writes bufA
    (void)ws_size; (void)n_in; (void)out_size;

    const int bn = (N_ + 255) / 256;
    const int bh = (N_ + 3) / 4;                       // hop: 4 waves (nodes) per block
    const int nbs = (M + SCAN_CHUNK - 1) / SCAN_CHUNK; // 112 scan blocks (<=1024)
    const int bl_ = (N_ + 63) / 64;                    // linear: BM=64 tiles

    p1_count_kernel<<<PB, 256, 0, stream>>>(ei, coarseCnt, E_, PB, NB);
    scan_partial_kernel<<<nbs, SCAN_TPB, 0, stream>>>(coarseCnt, bsums, M);
    scan_bsums_kernel<<<1, 1024, 0, stream>>>(bsums, nbs, coarseOff, M);
    scan_final_kernel<<<nbs, SCAN_TPB, 0, stream>>>(coarseCnt, bsums, coarseOff, M);
    p1_scatter_kernel<<<PB, 256, 0, stream>>>(ei, w, coarseOff, sorted, E_, PB, NB);
    p2_fine_kernel<<<NB, 256, 0, stream>>>(sorted, coarseOff, edge, row_ptr, N_, E_, PB, NB);
    deg_dinv_kernel<<<bn, 256, 0, stream>>>(edge, row_ptr, dinv, N_);
    scale_csr_kernel<<<bn, 256, 0, stream>>>(edge, row_ptr, dinv, N_);

    hop_kernel<<<bh, 256, 0, stream>>>(x,    bufA, dinv, row_ptr, edge, N_);
    hop_kernel<<<bh, 256, 0, stream>>>(bufA, bufB, dinv, row_ptr, edge, N_);
    linear_tiled_kernel<64, true><<<bl_, 256, 0, stream>>>(bufB, bufA, W1, b1, N_);
    hop_kernel<<<bh, 256, 0, stream>>>(bufA, bufB, dinv, row_ptr, edge, N_);
    hop_kernel<<<bh, 256, 0, stream>>>(bufB, bufA, dinv, row_ptr, edge, N_);
    linear_tiled_kernel<40, false><<<bl_, 256, 0, stream>>>(bufA, out, W2, b2, N_);
}

// Round 8
// 297.833 us; speedup vs baseline: 2.2863x; 1.0079x over previous
//
#include <hip/hip_runtime.h>

// SGConv (K=2, two layers) on MI355X.
// R6: atomic-free CSR build via 2-phase LDS counting sort.
// R7: associativity rewrite: A^2(X W1) and A^2(h W2) instead of (A^2 X)W1 --
//     layer-2 hops run on 40 features (160B rows) instead of 64 (256B),
//     cutting their compulsory per-XCD L2-miss traffic ~0.65x (hops measured
//     AT the compulsory-fetch floor: 150MB/dispatch = 8 XCDs x ~20MB unique).
//     Bias/relu fused into hop epilogues (hop2: +b1,relu; hop4: +b2 -> d_out).
//     deg/dinv folded into p2_fine (LDS float atomics). P1_EDGES 4096->8192.

#define SCAN_TPB 256
#define SCAN_ITEMS 8
#define SCAN_CHUNK (SCAN_TPB * SCAN_ITEMS)   // 2048 elements per block
#define P1_EDGES 8192                        // edges per phase-1 block
#define MAX_NB 784                           // coarse buckets (ceil(100000/128)=782)

// --- 3-phase hierarchical exclusive scan (generic: cnt[] -> out[], out[M]=total) ---

__global__ __launch_bounds__(SCAN_TPB) void scan_partial_kernel(const int* __restrict__ cnt,
                                                                int* __restrict__ bsums, int N_) {
    int t = threadIdx.x;
    int base = blockIdx.x * SCAN_CHUNK + t * SCAN_ITEMS;
    int s = 0;
    #pragma unroll
    for (int j = 0; j < SCAN_ITEMS; ++j) { int i = base + j; if (i < N_) s += cnt[i]; }
    __shared__ int sm[SCAN_TPB];
    sm[t] = s; __syncthreads();
    for (int o = SCAN_TPB / 2; o > 0; o >>= 1) {
        if (t < o) sm[t] += sm[t + o];
        __syncthreads();
    }
    if (t == 0) bsums[blockIdx.x] = sm[0];
}

__global__ __launch_bounds__(1024) void scan_bsums_kernel(int* bsums, int nb,
                                                          int* out, int N_) {
    __shared__ int sm[1024];
    int t = threadIdx.x;
    int v = (t < nb) ? bsums[t] : 0;
    sm[t] = v; __syncthreads();
    for (int o = 1; o < 1024; o <<= 1) {
        int u = (t >= o) ? sm[t - o] : 0;
        __syncthreads();
        sm[t] += u;
        __syncthreads();
    }
    if (t < nb) bsums[t] = sm[t] - v;          // exclusive block offset
    if (t == 1023) out[N_] = sm[1023];         // grand total
}

__global__ __launch_bounds__(SCAN_TPB) void scan_final_kernel(const int* __restrict__ cnt,
                                                              const int* __restrict__ bsums,
                                                              int* __restrict__ out, int N_) {
    int t = threadIdx.x;
    int base = blockIdx.x * SCAN_CHUNK + t * SCAN_ITEMS;
    int loc[SCAN_ITEMS];
    int s = 0;
    #pragma unroll
    for (int j = 0; j < SCAN_ITEMS; ++j) {
        int i = base + j;
        int c = (i < N_) ? cnt[i] : 0;
        loc[j] = s; s += c;
    }
    __shared__ int sm[SCAN_TPB];
    sm[t] = s; __syncthreads();
    for (int o = 1; o < SCAN_TPB; o <<= 1) {
        int u = (t >= o) ? sm[t - o] : 0;
        __syncthreads();
        sm[t] += u;
        __syncthreads();
    }
    int excl = bsums[blockIdx.x] + sm[t] - s;
    #pragma unroll
    for (int j = 0; j < SCAN_ITEMS; ++j) {
        int i = base + j;
        if (i < N_) out[i] = excl + loc[j];
    }
}

// --- Phase 1: coarse bucket (dst>>7) LDS histogram per 8192-edge block ---
__global__ __launch_bounds__(256) void p1_count_kernel(const int* __restrict__ ei,
                                                       int* __restrict__ coarseCnt,
                                                       int E_, int PB, int NB) {
    __shared__ int hist[MAX_NB];
    int tid = threadIdx.x;
    for (int u = tid; u < NB; u += 256) hist[u] = 0;
    __syncthreads();
    int base = blockIdx.x * P1_EDGES;
    #pragma unroll 4
    for (int j = 0; j < P1_EDGES / 256; ++j) {
        int e = base + j * 256 + tid;
        if (e < E_) atomicAdd(&hist[ei[E_ + e] >> 7], 1);
    }
    __syncthreads();
    for (int u = tid; u < NB; u += 256) coarseCnt[u * PB + blockIdx.x] = hist[u];
}

// Scatter edges into coarse-bucket-sorted order. LDS cursor = coarseOff column.
// Payload packs fine node id (dst&127) into src's upper bits: src<2^17, fine<2^7.
__global__ __launch_bounds__(256) void p1_scatter_kernel(const int* __restrict__ ei,
                                                         const float* __restrict__ w,
                                                         const int* __restrict__ coarseOff,
                                                         int2* __restrict__ sorted,
                                                         int E_, int PB, int NB) {
    __shared__ int lcur[MAX_NB];
    int tid = threadIdx.x;
    for (int u = tid; u < NB; u += 256) lcur[u] = coarseOff[u * PB + blockIdx.x];
    __syncthreads();
    int base = blockIdx.x * P1_EDGES;
    #pragma unroll 4
    for (int j = 0; j < P1_EDGES / 256; ++j) {
        int e = base + j * 256 + tid;
        if (e < E_) {
            int dst = ei[E_ + e];
            int b = dst >> 7;
            int pos = atomicAdd(&lcur[b], 1);
            sorted[pos] = make_int2(ei[e] | ((dst & 127) << 17), __float_as_int(w[e]));
        }
    }
}

// --- Phase 2: one block per coarse bucket. 128-bin fine histogram + scan in LDS,
// emit row_ptr + final CSR edge array + dinv (deg folded in via LDS float atomics). ---
__global__ __launch_bounds__(256) void p2_fine_kernel(const int2* __restrict__ sorted,
                                                      const int* __restrict__ coarseOff,
                                                      int2* __restrict__ edge,
                                                      int* __restrict__ row_ptr,
                                                      float* __restrict__ dinv,
                                                      int N_, int E_, int PB, int NB) {
    __shared__ int fcnt[128], fexc[128], fcur[128];
    __shared__ float fdeg[128];
    const int b = blockIdx.x;
    const int tid = threadIdx.x;
    const int start = coarseOff[b * PB];
    const int end = (b + 1 < NB) ? coarseOff[(b + 1) * PB] : E_;
    if (tid < 128) { fcnt[tid] = 0; fdeg[tid] = 1.0f; }   // self-loop weight pre-added
    __syncthreads();
    for (int p = start + tid; p < end; p += 256)
        atomicAdd(&fcnt[sorted[p].x >> 17], 1);
    __syncthreads();
    if (tid < 128) fexc[tid] = fcnt[tid];
    __syncthreads();
    for (int o = 1; o < 128; o <<= 1) {
        int v = (tid < 128 && tid >= o) ? fexc[tid - o] : 0;
        __syncthreads();
        if (tid < 128) fexc[tid] += v;
        __syncthreads();
    }
    const int node0 = b << 7;
    if (tid < 128) {
        fexc[tid] -= fcnt[tid];          // inclusive -> exclusive
        fcur[tid] = 0;
        int node = node0 + tid;
        if (node < N_) row_ptr[node] = start + fexc[tid];
    }
    __syncthreads();
    for (int p = start + tid; p < end; p += 256) {
        int2 pk = sorted[p];
        int fine = pk.x >> 17;
        int src  = pk.x & 0x1FFFF;
        int r = atomicAdd(&fcur[fine], 1);
        atomicAdd(&fdeg[fine], __int_as_float(pk.y));
        edge[start + fexc[fine] + r] = make_int2(src, pk.y);
    }
    __syncthreads();
    if (tid < 128) {
        int node = node0 + tid;
        if (node < N_) {
            float s = fdeg[tid];
            dinv[node] = (s > 0.f) ? (1.0f / sqrtf(s)) : 0.f;
        }
    }
    if (b == 0 && tid == 0) row_ptr[N_] = E_;
}

// In CSR order (coalesced in aggregate): edge[p].y = w * dinv[src] * dinv[dst].
__global__ __launch_bounds__(256) void scale_csr_kernel(int2* __restrict__ edge,
                                                        const int* __restrict__ row_ptr,
                                                        const float* __restrict__ dinv, int N_) {
    int n = blockIdx.x * blockDim.x + threadIdx.x;
    if (n < N_) {
        float dd = dinv[n];
        int p0 = row_ptr[n], p1 = row_ptr[n + 1];
        for (int p = p0; p < p1; ++p) {
            int2 e = edge[p];
            edge[p].y = __float_as_int(__int_as_float(e.y) * dinv[e.x] * dd);
        }
    }
}

// One wave per dst node, NSLOT float4 slots per row (16 -> 64f, 10 -> 40f).
// Quarter q of the wave fetches source row s_q; 4 edge-gathers in flight.
// EPI: 0 = none, 1 = +bias then relu, 2 = +bias. Lanes fl>=NSLOT clamp their
// slot (reads land in already-fetched lines; their acc is never stored).
template<int NSLOT, int EPI>
__global__ __launch_bounds__(256) void hop_kernel(const float* __restrict__ xin,
                                                  float* __restrict__ xout,
                                                  const float* __restrict__ dinv,
                                                  const int* __restrict__ row_ptr,
                                                  const int2* __restrict__ edge,
                                                  const float* __restrict__ bias, int N_) {
    constexpr int PITCH = NSLOT * 4;
    int wave = (blockIdx.x * blockDim.x + threadIdx.x) >> 6;
    int lane = threadIdx.x & 63;
    if (wave >= N_) return;
    const int d    = wave;
    const int q    = lane >> 4;               // quarter 0..3
    const int fl   = lane & 15;
    const int slot = (NSLOT == 16) ? fl : min(fl, NSLOT - 1);

    int e0 = row_ptr[d], e1 = row_ptr[d + 1];
    int nE = e1 - e0;
    float di = dinv[d];
    float4 selfv = ((const float4*)(xin + (size_t)d * PITCH))[slot];
    float4 acc = make_float4(0.f, 0.f, 0.f, 0.f);

    for (int eb = 0; eb < nE; eb += 64) {
        bool ok = (eb + lane) < nE;
        int2 ev = ok ? edge[e0 + eb + lane] : make_int2(d, 0);
        int m = min(64, nE - eb);
        for (int g = 0; g < m; g += 16) {
            int   s0 = __shfl(ev.x, g + q);
            int   s1 = __shfl(ev.x, g + 4 + q);
            int   s2 = __shfl(ev.x, g + 8 + q);
            int   s3 = __shfl(ev.x, g + 12 + q);
            float v0 = __shfl(__int_as_float(ev.y), g + q);
            float v1 = __shfl(__int_as_float(ev.y), g + 4 + q);
            float v2 = __shfl(__int_as_float(ev.y), g + 8 + q);
            float v3 = __shfl(__int_as_float(ev.y), g + 12 + q);
            float4 x0 = ((const float4*)(xin + (size_t)s0 * PITCH))[slot];
            float4 x1 = ((const float4*)(xin + (size_t)s1 * PITCH))[slot];
            float4 x2 = ((const float4*)(xin + (size_t)s2 * PITCH))[slot];
            float4 x3 = ((const float4*)(xin + (size_t)s3 * PITCH))[slot];
            acc.x = fmaf(v0, x0.x, acc.x); acc.y = fmaf(v0, x0.y, acc.y);
            acc.z = fmaf(v0, x0.z, acc.z); acc.w = fmaf(v0, x0.w, acc.w);
            acc.x = fmaf(v1, x1.x, acc.x); acc.y = fmaf(v1, x1.y, acc.y);
            acc.z = fmaf(v1, x1.z, acc.z); acc.w = fmaf(v1, x1.w, acc.w);
            acc.x = fmaf(v2, x2.x, acc.x); acc.y = fmaf(v2, x2.y, acc.y);
            acc.z = fmaf(v2, x2.z, acc.z); acc.w = fmaf(v2, x2.w, acc.w);
            acc.x = fmaf(v3, x3.x, acc.x); acc.y = fmaf(v3, x3.y, acc.y);
            acc.z = fmaf(v3, x3.z, acc.z); acc.w = fmaf(v3, x3.w, acc.w);
        }
    }
    acc.x += __shfl_xor(acc.x, 16); acc.y += __shfl_xor(acc.y, 16);
    acc.z += __shfl_xor(acc.z, 16); acc.w += __shfl_xor(acc.w, 16);
    acc.x += __shfl_xor(acc.x, 32); acc.y += __shfl_xor(acc.y, 32);
    acc.z += __shfl_xor(acc.z, 32); acc.w += __shfl_xor(acc.w, 32);
    float dii = di * di;
    acc.x = fmaf(dii, selfv.x, acc.x); acc.y = fmaf(dii, selfv.y, acc.y);
    acc.z = fmaf(dii, selfv.z, acc.z); acc.w = fmaf(dii, selfv.w, acc.w);
    if (lane < NSLOT) {
        if constexpr (EPI != 0) {
            float4 bv = ((const float4*)bias)[fl];
            acc.x += bv.x; acc.y += bv.y; acc.z += bv.z; acc.w += bv.w;
            if constexpr (EPI == 1) {
                acc.x = fmaxf(acc.x, 0.f); acc.y = fmaxf(acc.y, 0.f);
                acc.z = fmaxf(acc.z, 0.f); acc.w = fmaxf(acc.w, 0.f);
            }
        }
        ((float4*)(xout + (size_t)d * PITCH))[fl] = acc;
    }
}

// LDS-tiled GEMM (no bias, no activation): out[n][f] = sum_k h[n][k]*W[f][k].
// BM=64, 256 threads as 16x16 groups, 4 nodes x 4 outs per thread, unroll 2,
// launch_bounds(256,4) caps VGPR at 128 -> no scratch spill (R3 lesson).
template<int F>
__global__ __launch_bounds__(256, 4) void linear_tiled_kernel(const float* __restrict__ hin,
                                                              float* __restrict__ outp,
                                                              const float* __restrict__ W,
                                                              int N_) {
    constexpr int BM = 64;
    __shared__ float hs[BM * 64];    // 16 KB
    __shared__ float ws[64 * 64];    // 16 KB (rows >= F zeroed)
    const int tid  = threadIdx.x;
    const int base = blockIdx.x * BM;

    for (int u = tid; u < 64 * 16; u += 256) {
        int f = u >> 4, kc = u & 15;
        float4 v = (f < F) ? ((const float4*)W)[f * 16 + kc]
                           : make_float4(0.f, 0.f, 0.f, 0.f);
        *(float4*)&ws[f * 64 + ((kc ^ ((f >> 2) & 7)) << 2)] = v;
    }
    const int lim = min(BM, N_ - base);
    for (int u = tid; u < BM * 16; u += 256) {
        int n = u >> 4, kc = u & 15;
        float4 v = (n < lim) ? ((const float4*)(hin + (size_t)(base + n) * 64))[kc]
                             : make_float4(0.f, 0.f, 0.f, 0.f);
        *(float4*)&hs[n * 64 + ((kc ^ ((n >> 2) & 7)) << 2)] = v;
    }
    __syncthreads();

    const int f0 = (tid & 15) << 2;
    const int n0 = (tid >> 4) << 2;
    float4 acc[4];
    #pragma unroll
    for (int i = 0; i < 4; ++i) acc[i] = make_float4(0.f, 0.f, 0.f, 0.f);

    #pragma unroll 2
    for (int kc = 0; kc < 16; ++kc) {
        float4 hv[4], wv[4];
        #pragma unroll
        for (int i = 0; i < 4; ++i) {
            int n = n0 + i;
            hv[i] = *(const float4*)&hs[n * 64 + ((kc ^ ((n >> 2) & 7)) << 2)];
        }
        #pragma unroll
        for (int j = 0; j < 4; ++j) {
            int f = f0 + j;
            wv[j] = *(const float4*)&ws[f * 64 + ((kc ^ ((f >> 2) & 7)) << 2)];
        }
        #pragma unroll
        for (int i = 0; i < 4; ++i) {
            acc[i].x = fmaf(hv[i].x, wv[0].x, acc[i].x);
            acc[i].x = fmaf(hv[i].y, wv[0].y, acc[i].x);
            acc[i].x = fmaf(hv[i].z, wv[0].z, acc[i].x);
            acc[i].x = fmaf(hv[i].w, wv[0].w, acc[i].x);
            acc[i].y = fmaf(hv[i].x, wv[1].x, acc[i].y);
            acc[i].y = fmaf(hv[i].y, wv[1].y, acc[i].y);
            acc[i].y = fmaf(hv[i].z, wv[1].z, acc[i].y);
            acc[i].y = fmaf(hv[i].w, wv[1].w, acc[i].y);
            acc[i].z = fmaf(hv[i].x, wv[2].x, acc[i].z);
            acc[i].z = fmaf(hv[i].y, wv[2].y, acc[i].z);
            acc[i].z = fmaf(hv[i].z, wv[2].z, acc[i].z);
            acc[i].z = fmaf(hv[i].w, wv[2].w, acc[i].z);
            acc[i].w = fmaf(hv[i].x, wv[3].x, acc[i].w);
            acc[i].w = fmaf(hv[i].y, wv[3].y, acc[i].w);
            acc[i].w = fmaf(hv[i].z, wv[3].z, acc[i].w);
            acc[i].w = fmaf(hv[i].w, wv[3].w, acc[i].w);
        }
    }

    if (f0 < F) {
        #pragma unroll
        for (int i = 0; i < 4; ++i) {
            int n = base + n0 + i;
            if (n < N_) *(float4*)&outp[(size_t)n * F + f0] = acc[i];
        }
    }
}

extern "C" void kernel_launch(void* const* d_in, const int* in_sizes, int n_in,
                              void* d_out, int out_size, void* d_ws, size_t ws_size,
                              hipStream_t stream) {
    const float* x   = (const float*)d_in[0];
    const int*   ei  = (const int*)d_in[1];
    const float* w   = (const float*)d_in[2];
    const float* W1  = (const float*)d_in[3];
    const float* b1  = (const float*)d_in[4];
    const float* W2  = (const float*)d_in[5];
    const float* b2  = (const float*)d_in[6];
    float* out = (float*)d_out;

    const int N_ = in_sizes[0] / 64;        // 100000
    const int E_ = in_sizes[2];             // 1200000
    const int PB = (E_ + P1_EDGES - 1) / P1_EDGES;   // 147 phase-1 blocks
    const int NB = (N_ + 127) >> 7;                  // 782 coarse buckets (<= MAX_NB)
    const int M  = NB * PB;                          // coarse counters

    char* ws = (char*)d_ws;
    size_t off = 0;
    auto alloc = [&](size_t bytes) { size_t o = off; off += (bytes + 255) & ~(size_t)255; return o; };
    float* dinv      = (float*)(ws + alloc((size_t)N_ * 4));
    int*   row_ptr   = (int*)  (ws + alloc(((size_t)N_ + 1) * 4));
    int*   bsums     = (int*)  (ws + alloc(1024 * 4));
    int*   coarseCnt = (int*)  (ws + alloc((size_t)M * 4));
    int*   coarseOff = (int*)  (ws + alloc(((size_t)M + 1) * 4));
    int2*  edge      = (int2*) (ws + alloc((size_t)E_ * 8));
    float* bufA      = (float*)(ws + alloc((size_t)N_ * 64 * 4));
    float* bufB      = (float*)(ws + alloc((size_t)N_ * 64 * 4));
    int2*  sorted    = (int2*)bufA;    // alias: dead before lin1 writes bufA
    (void)ws_size; (void)n_in; (void)out_size;

    const int bn = (N_ + 255) / 256;
    const int bh = (N_ + 3) / 4;                       // hop: 4 waves (nodes) per block
    const int nbs = (M + SCAN_CHUNK - 1) / SCAN_CHUNK; // scan blocks (<=1024)
    const int bl_ = (N_ + 63) / 64;                    // linear: BM=64 tiles

    // CSR build (atomic-free, LDS counting sort) + dinv
    p1_count_kernel<<<PB, 256, 0, stream>>>(ei, coarseCnt, E_, PB, NB);
    scan_partial_kernel<<<nbs, SCAN_TPB, 0, stream>>>(coarseCnt, bsums, M);
    scan_bsums_kernel<<<1, 1024, 0, stream>>>(bsums, nbs, coarseOff, M);
    scan_final_kernel<<<nbs, SCAN_TPB, 0, stream>>>(coarseCnt, bsums, coarseOff, M);
    p1_scatter_kernel<<<PB, 256, 0, stream>>>(ei, w, coarseOff, sorted, E_, PB, NB);
    p2_fine_kernel<<<NB, 256, 0, stream>>>(sorted, coarseOff, edge, row_ptr, dinv, N_, E_, PB, NB);
    scale_csr_kernel<<<bn, 256, 0, stream>>>(edge, row_ptr, dinv, N_);

    // Layer 1: y = X W1^T (64f), h = relu(A^2 y + b1)
    linear_tiled_kernel<64><<<bl_, 256, 0, stream>>>(x, bufA, W1, N_);
    hop_kernel<16, 0><<<bh, 256, 0, stream>>>(bufA, bufB, dinv, row_ptr, edge, nullptr, N_);
    hop_kernel<16, 1><<<bh, 256, 0, stream>>>(bufB, bufA, dinv, row_ptr, edge, b1, N_);
    // Layer 2: z = h W2^T (40f), out = A^2 z + b2
    linear_tiled_kernel<40><<<bl_, 256, 0, stream>>>(bufA, bufB, W2, N_);
    hop_kernel<10, 0><<<bh, 256, 0, stream>>>(bufB, bufA, dinv, row_ptr, edge, nullptr, N_);
    hop_kernel<10, 2><<<bh, 256, 0, stream>>>(bufA, out, dinv, row_ptr, edge, b2, N_);
}

// Round 9
// 292.037 us; speedup vs baseline: 2.3317x; 1.0198x over previous
//
#include <hip/hip_runtime.h>
#include <hip/hip_fp16.h>

// SGConv (K=2, two layers) on MI355X.
// R6: atomic-free CSR build via 2-phase LDS counting sort.
// R7: associativity rewrite (hop AFTER weight): layer-2 hops on 40f. FAILED to
//     cut fetch: 160B fp32 rows straddle 2x128B lines at every alignment ->
//     still 256B/gather. Fetch floor = XCD-replication x touched-rows x lines.
// R8: fp16 layer-2 intermediates: z stored fp16 at 64-half pitch -> 40f = 80B,
//     ALWAYS one 128B line per gather (halves hop3/4 fetch). Octet (8-lane)
//     row groups: 8 rows in flight per gather instruction. Layer 1 stays fp32.

#define SCAN_TPB 256
#define SCAN_ITEMS 8
#define SCAN_CHUNK (SCAN_TPB * SCAN_ITEMS)   // 2048 elements per block
#define P1_EDGES 8192                        // edges per phase-1 block
#define MAX_NB 784                           // coarse buckets (ceil(100000/128)=782)

// --- 3-phase hierarchical exclusive scan (generic: cnt[] -> out[], out[M]=total) ---

__global__ __launch_bounds__(SCAN_TPB) void scan_partial_kernel(const int* __restrict__ cnt,
                                                                int* __restrict__ bsums, int N_) {
    int t = threadIdx.x;
    int base = blockIdx.x * SCAN_CHUNK + t * SCAN_ITEMS;
    int s = 0;
    #pragma unroll
    for (int j = 0; j < SCAN_ITEMS; ++j) { int i = base + j; if (i < N_) s += cnt[i]; }
    __shared__ int sm[SCAN_TPB];
    sm[t] = s; __syncthreads();
    for (int o = SCAN_TPB / 2; o > 0; o >>= 1) {
        if (t < o) sm[t] += sm[t + o];
        __syncthreads();
    }
    if (t == 0) bsums[blockIdx.x] = sm[0];
}

__global__ __launch_bounds__(1024) void scan_bsums_kernel(int* bsums, int nb,
                                                          int* out, int N_) {
    __shared__ int sm[1024];
    int t = threadIdx.x;
    int v = (t < nb) ? bsums[t] : 0;
    sm[t] = v; __syncthreads();
    for (int o = 1; o < 1024; o <<= 1) {
        int u = (t >= o) ? sm[t - o] : 0;
        __syncthreads();
        sm[t] += u;
        __syncthreads();
    }
    if (t < nb) bsums[t] = sm[t] - v;          // exclusive block offset
    if (t == 1023) out[N_] = sm[1023];         // grand total
}

__global__ __launch_bounds__(SCAN_TPB) void scan_final_kernel(const int* __restrict__ cnt,
                                                              const int* __restrict__ bsums,
                                                              int* __restrict__ out, int N_) {
    int t = threadIdx.x;
    int base = blockIdx.x * SCAN_CHUNK + t * SCAN_ITEMS;
    int loc[SCAN_ITEMS];
    int s = 0;
    #pragma unroll
    for (int j = 0; j < SCAN_ITEMS; ++j) {
        int i = base + j;
        int c = (i < N_) ? cnt[i] : 0;
        loc[j] = s; s += c;
    }
    __shared__ int sm[SCAN_TPB];
    sm[t] = s; __syncthreads();
    for (int o = 1; o < SCAN_TPB; o <<= 1) {
        int u = (t >= o) ? sm[t - o] : 0;
        __syncthreads();
        sm[t] += u;
        __syncthreads();
    }
    int excl = bsums[blockIdx.x] + sm[t] - s;
    #pragma unroll
    for (int j = 0; j < SCAN_ITEMS; ++j) {
        int i = base + j;
        if (i < N_) out[i] = excl + loc[j];
    }
}

// --- Phase 1: coarse bucket (dst>>7) LDS histogram per 8192-edge block ---
__global__ __launch_bounds__(256) void p1_count_kernel(const int* __restrict__ ei,
                                                       int* __restrict__ coarseCnt,
                                                       int E_, int PB, int NB) {
    __shared__ int hist[MAX_NB];
    int tid = threadIdx.x;
    for (int u = tid; u < NB; u += 256) hist[u] = 0;
    __syncthreads();
    int base = blockIdx.x * P1_EDGES;
    #pragma unroll 4
    for (int j = 0; j < P1_EDGES / 256; ++j) {
        int e = base + j * 256 + tid;
        if (e < E_) atomicAdd(&hist[ei[E_ + e] >> 7], 1);
    }
    __syncthreads();
    for (int u = tid; u < NB; u += 256) coarseCnt[u * PB + blockIdx.x] = hist[u];
}

// Scatter edges into coarse-bucket-sorted order. LDS cursor = coarseOff column.
__global__ __launch_bounds__(256) void p1_scatter_kernel(const int* __restrict__ ei,
                                                         const float* __restrict__ w,
                                                         const int* __restrict__ coarseOff,
                                                         int2* __restrict__ sorted,
                                                         int E_, int PB, int NB) {
    __shared__ int lcur[MAX_NB];
    int tid = threadIdx.x;
    for (int u = tid; u < NB; u += 256) lcur[u] = coarseOff[u * PB + blockIdx.x];
    __syncthreads();
    int base = blockIdx.x * P1_EDGES;
    #pragma unroll 4
    for (int j = 0; j < P1_EDGES / 256; ++j) {
        int e = base + j * 256 + tid;
        if (e < E_) {
            int dst = ei[E_ + e];
            int b = dst >> 7;
            int pos = atomicAdd(&lcur[b], 1);
            sorted[pos] = make_int2(ei[e] | ((dst & 127) << 17), __float_as_int(w[e]));
        }
    }
}

// --- Phase 2: per coarse bucket: fine histogram + scan, CSR emit + dinv. ---
__global__ __launch_bounds__(256) void p2_fine_kernel(const int2* __restrict__ sorted,
                                                      const int* __restrict__ coarseOff,
                                                      int2* __restrict__ edge,
                                                      int* __restrict__ row_ptr,
                                                      float* __restrict__ dinv,
                                                      int N_, int E_, int PB, int NB) {
    __shared__ int fcnt[128], fexc[128], fcur[128];
    __shared__ float fdeg[128];
    const int b = blockIdx.x;
    const int tid = threadIdx.x;
    const int start = coarseOff[b * PB];
    const int end = (b + 1 < NB) ? coarseOff[(b + 1) * PB] : E_;
    if (tid < 128) { fcnt[tid] = 0; fdeg[tid] = 1.0f; }   // self-loop weight pre-added
    __syncthreads();
    for (int p = start + tid; p < end; p += 256)
        atomicAdd(&fcnt[sorted[p].x >> 17], 1);
    __syncthreads();
    if (tid < 128) fexc[tid] = fcnt[tid];
    __syncthreads();
    for (int o = 1; o < 128; o <<= 1) {
        int v = (tid < 128 && tid >= o) ? fexc[tid - o] : 0;
        __syncthreads();
        if (tid < 128) fexc[tid] += v;
        __syncthreads();
    }
    const int node0 = b << 7;
    if (tid < 128) {
        fexc[tid] -= fcnt[tid];          // inclusive -> exclusive
        fcur[tid] = 0;
        int node = node0 + tid;
        if (node < N_) row_ptr[node] = start + fexc[tid];
    }
    __syncthreads();
    for (int p = start + tid; p < end; p += 256) {
        int2 pk = sorted[p];
        int fine = pk.x >> 17;
        int src  = pk.x & 0x1FFFF;
        int r = atomicAdd(&fcur[fine], 1);
        atomicAdd(&fdeg[fine], __int_as_float(pk.y));
        edge[start + fexc[fine] + r] = make_int2(src, pk.y);
    }
    __syncthreads();
    if (tid < 128) {
        int node = node0 + tid;
        if (node < N_) {
            float s = fdeg[tid];
            dinv[node] = (s > 0.f) ? (1.0f / sqrtf(s)) : 0.f;
        }
    }
    if (b == 0 && tid == 0) row_ptr[N_] = E_;
}

// In CSR order: edge[p].y = w * dinv[src] * dinv[dst].
__global__ __launch_bounds__(256) void scale_csr_kernel(int2* __restrict__ edge,
                                                        const int* __restrict__ row_ptr,
                                                        const float* __restrict__ dinv, int N_) {
    int n = blockIdx.x * blockDim.x + threadIdx.x;
    if (n < N_) {
        float dd = dinv[n];
        int p0 = row_ptr[n], p1 = row_ptr[n + 1];
        for (int p = p0; p < p1; ++p) {
            int2 e = edge[p];
            edge[p].y = __float_as_int(__int_as_float(e.y) * dinv[e.x] * dd);
        }
    }
}

// fp32 hop (layer 1, 64 features). One wave per dst node; quarter q fetches
// source row s_q (16 lanes x float4 = 256B); 4 gathers in flight.
// EPI: 0 = none, 1 = +bias then relu.
template<int EPI>
__global__ __launch_bounds__(256) void hop_kernel(const float* __restrict__ xin,
                                                  float* __restrict__ xout,
                                                  const float* __restrict__ dinv,
                                                  const int* __restrict__ row_ptr,
                                                  const int2* __restrict__ edge,
                                                  const float* __restrict__ bias, int N_) {
    int wave = (blockIdx.x * blockDim.x + threadIdx.x) >> 6;
    int lane = threadIdx.x & 63;
    if (wave >= N_) return;
    const int d  = wave;
    const int q  = lane >> 4;
    const int fl = lane & 15;

    int e0 = row_ptr[d], e1 = row_ptr[d + 1];
    int nE = e1 - e0;
    float di = dinv[d];
    float4 selfv = ((const float4*)(xin + (size_t)d * 64))[fl];
    float4 acc = make_float4(0.f, 0.f, 0.f, 0.f);

    for (int eb = 0; eb < nE; eb += 64) {
        bool ok = (eb + lane) < nE;
        int2 ev = ok ? edge[e0 + eb + lane] : make_int2(d, 0);
        int m = min(64, nE - eb);
        for (int g = 0; g < m; g += 16) {
            int   s0 = __shfl(ev.x, g + q);
            int   s1 = __shfl(ev.x, g + 4 + q);
            int   s2 = __shfl(ev.x, g + 8 + q);
            int   s3 = __shfl(ev.x, g + 12 + q);
            float v0 = __shfl(__int_as_float(ev.y), g + q);
            float v1 = __shfl(__int_as_float(ev.y), g + 4 + q);
            float v2 = __shfl(__int_as_float(ev.y), g + 8 + q);
            float v3 = __shfl(__int_as_float(ev.y), g + 12 + q);
            float4 x0 = ((const float4*)(xin + (size_t)s0 * 64))[fl];
            float4 x1 = ((const float4*)(xin + (size_t)s1 * 64))[fl];
            float4 x2 = ((const float4*)(xin + (size_t)s2 * 64))[fl];
            float4 x3 = ((const float4*)(xin + (size_t)s3 * 64))[fl];
            acc.x = fmaf(v0, x0.x, acc.x); acc.y = fmaf(v0, x0.y, acc.y);
            acc.z = fmaf(v0, x0.z, acc.z); acc.w = fmaf(v0, x0.w, acc.w);
            acc.x = fmaf(v1, x1.x, acc.x); acc.y = fmaf(v1, x1.y, acc.y);
            acc.z = fmaf(v1, x1.z, acc.z); acc.w = fmaf(v1, x1.w, acc.w);
            acc.x = fmaf(v2, x2.x, acc.x); acc.y = fmaf(v2, x2.y, acc.y);
            acc.z = fmaf(v2, x2.z, acc.z); acc.w = fmaf(v2, x2.w, acc.w);
            acc.x = fmaf(v3, x3.x, acc.x); acc.y = fmaf(v3, x3.y, acc.y);
            acc.z = fmaf(v3, x3.z, acc.z); acc.w = fmaf(v3, x3.w, acc.w);
        }
    }
    acc.x += __shfl_xor(acc.x, 16); acc.y += __shfl_xor(acc.y, 16);
    acc.z += __shfl_xor(acc.z, 16); acc.w += __shfl_xor(acc.w, 16);
    acc.x += __shfl_xor(acc.x, 32); acc.y += __shfl_xor(acc.y, 32);
    acc.z += __shfl_xor(acc.z, 32); acc.w += __shfl_xor(acc.w, 32);
    float dii = di * di;
    acc.x = fmaf(dii, selfv.x, acc.x); acc.y = fmaf(dii, selfv.y, acc.y);
    acc.z = fmaf(dii, selfv.z, acc.z); acc.w = fmaf(dii, selfv.w, acc.w);
    if (lane < 16) {
        if constexpr (EPI == 1) {
            float4 bv = ((const float4*)bias)[fl];
            acc.x = fmaxf(acc.x + bv.x, 0.f); acc.y = fmaxf(acc.y + bv.y, 0.f);
            acc.z = fmaxf(acc.z + bv.z, 0.f); acc.w = fmaxf(acc.w + bv.w, 0.f);
        }
        ((float4*)(xout + (size_t)d * 64))[fl] = acc;
    }
}

// fp16 hop (layer 2, 40 features as 5x8-half slots, pitch 64 halves = 128B:
// ONE cache line per row gather). Octet groups: 8 lanes/row, 8 rows per gather
// instruction. EPI: 0 = fp16 out (pitch 64h), 2 = +bias, fp32 out (pitch 40f).
template<int EPI>
__global__ __launch_bounds__(256) void hop40h_kernel(const __half* __restrict__ xin,
                                                     void* __restrict__ xout,
                                                     const float* __restrict__ dinv,
                                                     const int* __restrict__ row_ptr,
                                                     const int2* __restrict__ edge,
                                                     const float* __restrict__ bias, int N_) {
    int wave = (blockIdx.x * blockDim.x + threadIdx.x) >> 6;
    int lane = threadIdx.x & 63;
    if (wave >= N_) return;
    const int d    = wave;
    const int q8   = lane >> 3;               // octet 0..7
    const int sl   = lane & 7;
    const int slot = min(sl, 4);              // 5 real slots; 5..7 clamp (same line)

    int e0 = row_ptr[d], e1 = row_ptr[d + 1];
    int nE = e1 - e0;
    float di = dinv[d];

    float sf[8];
    {
        float4 sv = ((const float4*)(xin + (size_t)d * 64))[slot];
        const __half2* h2 = (const __half2*)&sv;
        #pragma unroll
        for (int u = 0; u < 4; ++u) {
            float2 f = __half22float2(h2[u]);
            sf[2 * u] = f.x; sf[2 * u + 1] = f.y;
        }
    }
    float acc[8];
    #pragma unroll
    for (int u = 0; u < 8; ++u) acc[u] = 0.f;

    for (int eb = 0; eb < nE; eb += 64) {
        bool ok = (eb + lane) < nE;
        int2 ev = ok ? edge[e0 + eb + lane] : make_int2(d, 0);
        int m = min(64, nE - eb);
        for (int g = 0; g < m; g += 32) {
            int   s0 = __shfl(ev.x, g + q8);
            int   s1 = __shfl(ev.x, g + 8 + q8);
            int   s2 = __shfl(ev.x, g + 16 + q8);
            int   s3 = __shfl(ev.x, g + 24 + q8);
            float v0 = __shfl(__int_as_float(ev.y), g + q8);
            float v1 = __shfl(__int_as_float(ev.y), g + 8 + q8);
            float v2 = __shfl(__int_as_float(ev.y), g + 16 + q8);
            float v3 = __shfl(__int_as_float(ev.y), g + 24 + q8);
            float4 x0 = ((const float4*)(xin + (size_t)s0 * 64))[slot];
            float4 x1 = ((const float4*)(xin + (size_t)s1 * 64))[slot];
            float4 x2 = ((const float4*)(xin + (size_t)s2 * 64))[slot];
            float4 x3 = ((const float4*)(xin + (size_t)s3 * 64))[slot];
            const __half2* h0 = (const __half2*)&x0;
            const __half2* h1 = (const __half2*)&x1;
            const __half2* h2 = (const __half2*)&x2;
            const __half2* h3 = (const __half2*)&x3;
            #pragma unroll
            for (int u = 0; u < 4; ++u) {
                float2 f0 = __half22float2(h0[u]);
                float2 f1 = __half22float2(h1[u]);
                float2 f2 = __half22float2(h2[u]);
                float2 f3 = __half22float2(h3[u]);
                acc[2*u]   = fmaf(v0, f0.x, acc[2*u]);   acc[2*u+1] = fmaf(v0, f0.y, acc[2*u+1]);
                acc[2*u]   = fmaf(v1, f1.x, acc[2*u]);   acc[2*u+1] = fmaf(v1, f1.y, acc[2*u+1]);
                acc[2*u]   = fmaf(v2, f2.x, acc[2*u]);   acc[2*u+1] = fmaf(v2, f2.y, acc[2*u+1]);
                acc[2*u]   = fmaf(v3, f3.x, acc[2*u]);   acc[2*u+1] = fmaf(v3, f3.y, acc[2*u+1]);
            }
        }
    }
    // reduce the 8 octet partials (lanes differing in bits 3..5)
    #pragma unroll
    for (int u = 0; u < 8; ++u) {
        acc[u] += __shfl_xor(acc[u], 8);
        acc[u] += __shfl_xor(acc[u], 16);
        acc[u] += __shfl_xor(acc[u], 32);
    }
    float dii = di * di;
    #pragma unroll
    for (int u = 0; u < 8; ++u) acc[u] = fmaf(dii, sf[u], acc[u]);

    if (lane < 5) {   // lane == slot, octet 0
        if constexpr (EPI == 0) {
            union { __half2 h2[4]; float4 f4; } pk;
            #pragma unroll
            for (int u = 0; u < 4; ++u)
                pk.h2[u] = __floats2half2_rn(acc[2*u], acc[2*u+1]);
            ((float4*)((__half*)xout + (size_t)d * 64))[lane] = pk.f4;
        } else {
            float* o = (float*)xout + (size_t)d * 40 + lane * 8;
            float4 r0, r1;
            r0.x = acc[0] + bias[lane*8+0]; r0.y = acc[1] + bias[lane*8+1];
            r0.z = acc[2] + bias[lane*8+2]; r0.w = acc[3] + bias[lane*8+3];
            r1.x = acc[4] + bias[lane*8+4]; r1.y = acc[5] + bias[lane*8+5];
            r1.z = acc[6] + bias[lane*8+6]; r1.w = acc[7] + bias[lane*8+7];
            *(float4*)o = r0;
            *(float4*)(o + 4) = r1;
        }
    }
}

// LDS-tiled GEMM (no bias/activation): out[n][f] = sum_k h[n][k]*W[f][k].
// OUTH: write fp16 rows at 64-half pitch (layer-2 z); else fp32 at F-float pitch.
template<int F, bool OUTH>
__global__ __launch_bounds__(256, 4) void linear_tiled_kernel(const float* __restrict__ hin,
                                                              void* __restrict__ outp,
                                                              const float* __restrict__ W,
                                                              int N_) {
    constexpr int BM = 64;
    __shared__ float hs[BM * 64];
    __shared__ float ws[64 * 64];
    const int tid  = threadIdx.x;
    const int base = blockIdx.x * BM;

    for (int u = tid; u < 64 * 16; u += 256) {
        int f = u >> 4, kc = u & 15;
        float4 v = (f < F) ? ((const float4*)W)[f * 16 + kc]
                           : make_float4(0.f, 0.f, 0.f, 0.f);
        *(float4*)&ws[f * 64 + ((kc ^ ((f >> 2) & 7)) << 2)] = v;
    }
    const int lim = min(BM, N_ - base);
    for (int u = tid; u < BM * 16; u += 256) {
        int n = u >> 4, kc = u & 15;
        float4 v = (n < lim) ? ((const float4*)(hin + (size_t)(base + n) * 64))[kc]
                             : make_float4(0.f, 0.f, 0.f, 0.f);
        *(float4*)&hs[n * 64 + ((kc ^ ((n >> 2) & 7)) << 2)] = v;
    }
    __syncthreads();

    const int f0 = (tid & 15) << 2;
    const int n0 = (tid >> 4) << 2;
    float4 acc[4];
    #pragma unroll
    for (int i = 0; i < 4; ++i) acc[i] = make_float4(0.f, 0.f, 0.f, 0.f);

    #pragma unroll 2
    for (int kc = 0; kc < 16; ++kc) {
        float4 hv[4], wv[4];
        #pragma unroll
        for (int i = 0; i < 4; ++i) {
            int n = n0 + i;
            hv[i] = *(const float4*)&hs[n * 64 + ((kc ^ ((n >> 2) & 7)) << 2)];
        }
        #pragma unroll
        for (int j = 0; j < 4; ++j) {
            int f = f0 + j;
            wv[j] = *(const float4*)&ws[f * 64 + ((kc ^ ((f >> 2) & 7)) << 2)];
        }
        #pragma unroll
        for (int i = 0; i < 4; ++i) {
            acc[i].x = fmaf(hv[i].x, wv[0].x, acc[i].x);
            acc[i].x = fmaf(hv[i].y, wv[0].y, acc[i].x);
            acc[i].x = fmaf(hv[i].z, wv[0].z, acc[i].x);
            acc[i].x = fmaf(hv[i].w, wv[0].w, acc[i].x);
            acc[i].y = fmaf(hv[i].x, wv[1].x, acc[i].y);
            acc[i].y = fmaf(hv[i].y, wv[1].y, acc[i].y);
            acc[i].y = fmaf(hv[i].z, wv[1].z, acc[i].y);
            acc[i].y = fmaf(hv[i].w, wv[1].w, acc[i].y);
            acc[i].z = fmaf(hv[i].x, wv[2].x, acc[i].z);
            acc[i].z = fmaf(hv[i].y, wv[2].y, acc[i].z);
            acc[i].z = fmaf(hv[i].z, wv[2].z, acc[i].z);
            acc[i].z = fmaf(hv[i].w, wv[2].w, acc[i].z);
            acc[i].w = fmaf(hv[i].x, wv[3].x, acc[i].w);
            acc[i].w = fmaf(hv[i].y, wv[3].y, acc[i].w);
            acc[i].w = fmaf(hv[i].z, wv[3].z, acc[i].w);
            acc[i].w = fmaf(hv[i].w, wv[3].w, acc[i].w);
        }
    }

    if (f0 < F) {
        #pragma unroll
        for (int i = 0; i < 4; ++i) {
            int n = base + n0 + i;
            if (n < N_) {
                if constexpr (OUTH) {
                    __half* o = (__half*)outp + (size_t)n * 64 + f0;
                    ((__half2*)o)[0] = __floats2half2_rn(acc[i].x, acc[i].y);
                    ((__half2*)o)[1] = __floats2half2_rn(acc[i].z, acc[i].w);
                } else {
                    *(float4*)&((float*)outp)[(size_t)n * F + f0] = acc[i];
                }
            }
        }
    }
}

extern "C" void kernel_launch(void* const* d_in, const int* in_sizes, int n_in,
                              void* d_out, int out_size, void* d_ws, size_t ws_size,
                              hipStream_t stream) {
    const float* x   = (const float*)d_in[0];
    const int*   ei  = (const int*)d_in[1];
    const float* w   = (const float*)d_in[2];
    const float* W1  = (const float*)d_in[3];
    const float* b1  = (const float*)d_in[4];
    const float* W2  = (const float*)d_in[5];
    const float* b2  = (const float*)d_in[6];
    float* out = (float*)d_out;

    const int N_ = in_sizes[0] / 64;        // 100000
    const int E_ = in_sizes[2];             // 1200000
    const int PB = (E_ + P1_EDGES - 1) / P1_EDGES;
    const int NB = (N_ + 127) >> 7;
    const int M  = NB * PB;

    char* ws = (char*)d_ws;
    size_t off = 0;
    auto alloc = [&](size_t bytes) { size_t o = off; off += (bytes + 255) & ~(size_t)255; return o; };
    float* dinv      = (float*)(ws + alloc((size_t)N_ * 4));
    int*   row_ptr   = (int*)  (ws + alloc(((size_t)N_ + 1) * 4));
    int*   bsums     = (int*)  (ws + alloc(1024 * 4));
    int*   coarseCnt = (int*)  (ws + alloc((size_t)M * 4));
    int*   coarseOff = (int*)  (ws + alloc(((size_t)M + 1) * 4));
    int2*  edge      = (int2*) (ws + alloc((size_t)E_ * 8));
    float* bufA      = (float*)(ws + alloc((size_t)N_ * 64 * 4));
    float* bufB      = (float*)(ws + alloc((size_t)N_ * 64 * 4));
    int2*   sorted = (int2*)bufA;                                   // dead before linear1
    __half* zH     = (__half*)bufB;                                 // dead after hop2
    __half* z2H    = (__half*)((char*)bufB + (size_t)N_ * 64 * 2);  // second half of bufB
    (void)ws_size; (void)n_in; (void)out_size;

    const int bn = (N_ + 255) / 256;
    const int bh = (N_ + 3) / 4;
    const int nbs = (M + SCAN_CHUNK - 1) / SCAN_CHUNK;
    const int bl_ = (N_ + 63) / 64;

    // CSR build (atomic-free LDS counting sort) + dinv
    p1_count_kernel<<<PB, 256, 0, stream>>>(ei, coarseCnt, E_, PB, NB);
    scan_partial_kernel<<<nbs, SCAN_TPB, 0, stream>>>(coarseCnt, bsums, M);
    scan_bsums_kernel<<<1, 1024, 0, stream>>>(bsums, nbs, coarseOff, M);
    scan_final_kernel<<<nbs, SCAN_TPB, 0, stream>>>(coarseCnt, bsums, coarseOff, M);
    p1_scatter_kernel<<<PB, 256, 0, stream>>>(ei, w, coarseOff, sorted, E_, PB, NB);
    p2_fine_kernel<<<NB, 256, 0, stream>>>(sorted, coarseOff, edge, row_ptr, dinv, N_, E_, PB, NB);
    scale_csr_kernel<<<bn, 256, 0, stream>>>(edge, row_ptr, dinv, N_);

    // Layer 1 (fp32, 64f): y = X W1^T; h = relu(A^2 y + b1)
    linear_tiled_kernel<64, false><<<bl_, 256, 0, stream>>>(x, bufA, W1, N_);
    hop_kernel<0><<<bh, 256, 0, stream>>>(bufA, bufB, dinv, row_ptr, edge, nullptr, N_);
    hop_kernel<1><<<bh, 256, 0, stream>>>(bufB, bufA, dinv, row_ptr, edge, b1, N_);
    // Layer 2 (fp16 rows, 40f in 128B lines): z = h W2^T; out = A^2 z + b2
    linear_tiled_kernel<40, true><<<bl_, 256, 0, stream>>>(bufA, zH, W2, N_);
    hop40h_kernel<0><<<bh, 256, 0, stream>>>(zH, z2H, dinv, row_ptr, edge, nullptr, N_);
    hop40h_kernel<2><<<bh, 256, 0, stream>>>(z2H, out, dinv, row_ptr, edge, b2, N_);
}

// Round 10
// 270.952 us; speedup vs baseline: 2.5131x; 1.0778x over previous
//
#include <hip/hip_runtime.h>
#include <hip/hip_fp16.h>

// SGConv (K=2, two layers) on MI355X.
// R6: atomic-free CSR build (2-phase LDS counting sort).
// R7: hop-after-weight associativity rewrite (layer-2 on 40f).
// R8: fp16 layer-2 rows at 64-half pitch -> one 128B line/gather; absmax
//     unchanged (4.88e-4), hop3/4 fetch halved.
// R9: same scheme for layer 1: y=X W1^T stored fp16 (64f x 2B = 128B = one
//     line). All 4 hops now fp16-row octet-gather; h returned to fp32 for the
//     layer-2 GEMM. Generic hop_h<SLOTS,EPI> replaces both hop variants.

#define SCAN_TPB 256
#define SCAN_ITEMS 8
#define SCAN_CHUNK (SCAN_TPB * SCAN_ITEMS)   // 2048 elements per block
#define P1_EDGES 8192                        // edges per phase-1 block
#define MAX_NB 784                           // coarse buckets (ceil(100000/128)=782)

// --- 3-phase hierarchical exclusive scan (generic: cnt[] -> out[], out[M]=total) ---

__global__ __launch_bounds__(SCAN_TPB) void scan_partial_kernel(const int* __restrict__ cnt,
                                                                int* __restrict__ bsums, int N_) {
    int t = threadIdx.x;
    int base = blockIdx.x * SCAN_CHUNK + t * SCAN_ITEMS;
    int s = 0;
    #pragma unroll
    for (int j = 0; j < SCAN_ITEMS; ++j) { int i = base + j; if (i < N_) s += cnt[i]; }
    __shared__ int sm[SCAN_TPB];
    sm[t] = s; __syncthreads();
    for (int o = SCAN_TPB / 2; o > 0; o >>= 1) {
        if (t < o) sm[t] += sm[t + o];
        __syncthreads();
    }
    if (t == 0) bsums[blockIdx.x] = sm[0];
}

__global__ __launch_bounds__(1024) void scan_bsums_kernel(int* bsums, int nb,
                                                          int* out, int N_) {
    __shared__ int sm[1024];
    int t = threadIdx.x;
    int v = (t < nb) ? bsums[t] : 0;
    sm[t] = v; __syncthreads();
    for (int o = 1; o < 1024; o <<= 1) {
        int u = (t >= o) ? sm[t - o] : 0;
        __syncthreads();
        sm[t] += u;
        __syncthreads();
    }
    if (t < nb) bsums[t] = sm[t] - v;          // exclusive block offset
    if (t == 1023) out[N_] = sm[1023];         // grand total
}

__global__ __launch_bounds__(SCAN_TPB) void scan_final_kernel(const int* __restrict__ cnt,
                                                              const int* __restrict__ bsums,
                                                              int* __restrict__ out, int N_) {
    int t = threadIdx.x;
    int base = blockIdx.x * SCAN_CHUNK + t * SCAN_ITEMS;
    int loc[SCAN_ITEMS];
    int s = 0;
    #pragma unroll
    for (int j = 0; j < SCAN_ITEMS; ++j) {
        int i = base + j;
        int c = (i < N_) ? cnt[i] : 0;
        loc[j] = s; s += c;
    }
    __shared__ int sm[SCAN_TPB];
    sm[t] = s; __syncthreads();
    for (int o = 1; o < SCAN_TPB; o <<= 1) {
        int u = (t >= o) ? sm[t - o] : 0;
        __syncthreads();
        sm[t] += u;
        __syncthreads();
    }
    int excl = bsums[blockIdx.x] + sm[t] - s;
    #pragma unroll
    for (int j = 0; j < SCAN_ITEMS; ++j) {
        int i = base + j;
        if (i < N_) out[i] = excl + loc[j];
    }
}

// --- Phase 1: coarse bucket (dst>>7) LDS histogram per 8192-edge block ---
__global__ __launch_bounds__(256) void p1_count_kernel(const int* __restrict__ ei,
                                                       int* __restrict__ coarseCnt,
                                                       int E_, int PB, int NB) {
    __shared__ int hist[MAX_NB];
    int tid = threadIdx.x;
    for (int u = tid; u < NB; u += 256) hist[u] = 0;
    __syncthreads();
    int base = blockIdx.x * P1_EDGES;
    #pragma unroll 4
    for (int j = 0; j < P1_EDGES / 256; ++j) {
        int e = base + j * 256 + tid;
        if (e < E_) atomicAdd(&hist[ei[E_ + e] >> 7], 1);
    }
    __syncthreads();
    for (int u = tid; u < NB; u += 256) coarseCnt[u * PB + blockIdx.x] = hist[u];
}

// Scatter edges into coarse-bucket-sorted order. LDS cursor = coarseOff column.
__global__ __launch_bounds__(256) void p1_scatter_kernel(const int* __restrict__ ei,
                                                         const float* __restrict__ w,
                                                         const int* __restrict__ coarseOff,
                                                         int2* __restrict__ sorted,
                                                         int E_, int PB, int NB) {
    __shared__ int lcur[MAX_NB];
    int tid = threadIdx.x;
    for (int u = tid; u < NB; u += 256) lcur[u] = coarseOff[u * PB + blockIdx.x];
    __syncthreads();
    int base = blockIdx.x * P1_EDGES;
    #pragma unroll 4
    for (int j = 0; j < P1_EDGES / 256; ++j) {
        int e = base + j * 256 + tid;
        if (e < E_) {
            int dst = ei[E_ + e];
            int b = dst >> 7;
            int pos = atomicAdd(&lcur[b], 1);
            sorted[pos] = make_int2(ei[e] | ((dst & 127) << 17), __float_as_int(w[e]));
        }
    }
}

// --- Phase 2: per coarse bucket: fine histogram + scan, CSR emit + dinv. ---
__global__ __launch_bounds__(256) void p2_fine_kernel(const int2* __restrict__ sorted,
                                                      const int* __restrict__ coarseOff,
                                                      int2* __restrict__ edge,
                                                      int* __restrict__ row_ptr,
                                                      float* __restrict__ dinv,
                                                      int N_, int E_, int PB, int NB) {
    __shared__ int fcnt[128], fexc[128], fcur[128];
    __shared__ float fdeg[128];
    const int b = blockIdx.x;
    const int tid = threadIdx.x;
    const int start = coarseOff[b * PB];
    const int end = (b + 1 < NB) ? coarseOff[(b + 1) * PB] : E_;
    if (tid < 128) { fcnt[tid] = 0; fdeg[tid] = 1.0f; }   // self-loop weight pre-added
    __syncthreads();
    for (int p = start + tid; p < end; p += 256)
        atomicAdd(&fcnt[sorted[p].x >> 17], 1);
    __syncthreads();
    if (tid < 128) fexc[tid] = fcnt[tid];
    __syncthreads();
    for (int o = 1; o < 128; o <<= 1) {
        int v = (tid < 128 && tid >= o) ? fexc[tid - o] : 0;
        __syncthreads();
        if (tid < 128) fexc[tid] += v;
        __syncthreads();
    }
    const int node0 = b << 7;
    if (tid < 128) {
        fexc[tid] -= fcnt[tid];          // inclusive -> exclusive
        fcur[tid] = 0;
        int node = node0 + tid;
        if (node < N_) row_ptr[node] = start + fexc[tid];
    }
    __syncthreads();
    for (int p = start + tid; p < end; p += 256) {
        int2 pk = sorted[p];
        int fine = pk.x >> 17;
        int src  = pk.x & 0x1FFFF;
        int r = atomicAdd(&fcur[fine], 1);
        atomicAdd(&fdeg[fine], __int_as_float(pk.y));
        edge[start + fexc[fine] + r] = make_int2(src, pk.y);
    }
    __syncthreads();
    if (tid < 128) {
        int node = node0 + tid;
        if (node < N_) {
            float s = fdeg[tid];
            dinv[node] = (s > 0.f) ? (1.0f / sqrtf(s)) : 0.f;
        }
    }
    if (b == 0 && tid == 0) row_ptr[N_] = E_;
}

// In CSR order: edge[p].y = w * dinv[src] * dinv[dst].
__global__ __launch_bounds__(256) void scale_csr_kernel(int2* __restrict__ edge,
                                                        const int* __restrict__ row_ptr,
                                                        const float* __restrict__ dinv, int N_) {
    int n = blockIdx.x * blockDim.x + threadIdx.x;
    if (n < N_) {
        float dd = dinv[n];
        int p0 = row_ptr[n], p1 = row_ptr[n + 1];
        for (int p = p0; p < p1; ++p) {
            int2 e = edge[p];
            edge[p].y = __float_as_int(__int_as_float(e.y) * dinv[e.x] * dd);
        }
    }
}

// fp16-row hop. Rows at 64-half pitch (128B = ONE cache line). SLOTS real
// float4 slots (8 -> 64f, 5 -> 40f); octet groups: 8 lanes/row, 8 rows in
// flight per gather instruction. EPI: 0 = fp16 out (pitch 64h),
// 1 = +bias+relu fp32 out (pitch 64f), 2 = +bias fp32 out (pitch 40f).
template<int SLOTS, int EPI>
__global__ __launch_bounds__(256) void hop_h_kernel(const __half* __restrict__ xin,
                                                    void* __restrict__ xout,
                                                    const float* __restrict__ dinv,
                                                    const int* __restrict__ row_ptr,
                                                    const int2* __restrict__ edge,
                                                    const float* __restrict__ bias, int N_) {
    int wave = (blockIdx.x * blockDim.x + threadIdx.x) >> 6;
    int lane = threadIdx.x & 63;
    if (wave >= N_) return;
    const int d    = wave;
    const int q8   = lane >> 3;               // octet 0..7
    const int sl   = lane & 7;
    const int slot = (SLOTS == 8) ? sl : min(sl, SLOTS - 1);  // clamped lanes stay in-line

    int e0 = row_ptr[d], e1 = row_ptr[d + 1];
    int nE = e1 - e0;
    float di = dinv[d];

    float sf[8];
    {
        float4 sv = ((const float4*)(xin + (size_t)d * 64))[slot];
        const __half2* h2 = (const __half2*)&sv;
        #pragma unroll
        for (int u = 0; u < 4; ++u) {
            float2 f = __half22float2(h2[u]);
            sf[2 * u] = f.x; sf[2 * u + 1] = f.y;
        }
    }
    float acc[8];
    #pragma unroll
    for (int u = 0; u < 8; ++u) acc[u] = 0.f;

    for (int eb = 0; eb < nE; eb += 64) {
        bool ok = (eb + lane) < nE;
        int2 ev = ok ? edge[e0 + eb + lane] : make_int2(d, 0);
        int m = min(64, nE - eb);
        for (int g = 0; g < m; g += 32) {
            int   s0 = __shfl(ev.x, g + q8);
            int   s1 = __shfl(ev.x, g + 8 + q8);
            int   s2 = __shfl(ev.x, g + 16 + q8);
            int   s3 = __shfl(ev.x, g + 24 + q8);
            float v0 = __shfl(__int_as_float(ev.y), g + q8);
            float v1 = __shfl(__int_as_float(ev.y), g + 8 + q8);
            float v2 = __shfl(__int_as_float(ev.y), g + 16 + q8);
            float v3 = __shfl(__int_as_float(ev.y), g + 24 + q8);
            float4 x0 = ((const float4*)(xin + (size_t)s0 * 64))[slot];
            float4 x1 = ((const float4*)(xin + (size_t)s1 * 64))[slot];
            float4 x2 = ((const float4*)(xin + (size_t)s2 * 64))[slot];
            float4 x3 = ((const float4*)(xin + (size_t)s3 * 64))[slot];
            const __half2* h0 = (const __half2*)&x0;
            const __half2* h1 = (const __half2*)&x1;
            const __half2* h2 = (const __half2*)&x2;
            const __half2* h3 = (const __half2*)&x3;
            #pragma unroll
            for (int u = 0; u < 4; ++u) {
                float2 f0 = __half22float2(h0[u]);
                float2 f1 = __half22float2(h1[u]);
                float2 f2 = __half22float2(h2[u]);
                float2 f3 = __half22float2(h3[u]);
                acc[2*u]   = fmaf(v0, f0.x, acc[2*u]);   acc[2*u+1] = fmaf(v0, f0.y, acc[2*u+1]);
                acc[2*u]   = fmaf(v1, f1.x, acc[2*u]);   acc[2*u+1] = fmaf(v1, f1.y, acc[2*u+1]);
                acc[2*u]   = fmaf(v2, f2.x, acc[2*u]);   acc[2*u+1] = fmaf(v2, f2.y, acc[2*u+1]);
                acc[2*u]   = fmaf(v3, f3.x, acc[2*u]);   acc[2*u+1] = fmaf(v3, f3.y, acc[2*u+1]);
            }
        }
    }
    // reduce the 8 octet partials (lanes differing in bits 3..5)
    #pragma unroll
    for (int u = 0; u < 8; ++u) {
        acc[u] += __shfl_xor(acc[u], 8);
        acc[u] += __shfl_xor(acc[u], 16);
        acc[u] += __shfl_xor(acc[u], 32);
    }
    float dii = di * di;
    #pragma unroll
    for (int u = 0; u < 8; ++u) acc[u] = fmaf(dii, sf[u], acc[u]);

    if (lane < SLOTS) {   // octet 0, lane == slot
        if constexpr (EPI == 0) {
            union { __half2 h2[4]; float4 f4; } pk;
            #pragma unroll
            for (int u = 0; u < 4; ++u)
                pk.h2[u] = __floats2half2_rn(acc[2*u], acc[2*u+1]);
            ((float4*)((__half*)xout + (size_t)d * 64))[lane] = pk.f4;
        } else if constexpr (EPI == 1) {
            float* o = (float*)xout + (size_t)d * 64 + lane * 8;
            float4 r0, r1;
            r0.x = fmaxf(acc[0] + bias[lane*8+0], 0.f); r0.y = fmaxf(acc[1] + bias[lane*8+1], 0.f);
            r0.z = fmaxf(acc[2] + bias[lane*8+2], 0.f); r0.w = fmaxf(acc[3] + bias[lane*8+3], 0.f);
            r1.x = fmaxf(acc[4] + bias[lane*8+4], 0.f); r1.y = fmaxf(acc[5] + bias[lane*8+5], 0.f);
            r1.z = fmaxf(acc[6] + bias[lane*8+6], 0.f); r1.w = fmaxf(acc[7] + bias[lane*8+7], 0.f);
            *(float4*)o = r0;
            *(float4*)(o + 4) = r1;
        } else {
            float* o = (float*)xout + (size_t)d * 40 + lane * 8;
            float4 r0, r1;
            r0.x = acc[0] + bias[lane*8+0]; r0.y = acc[1] + bias[lane*8+1];
            r0.z = acc[2] + bias[lane*8+2]; r0.w = acc[3] + bias[lane*8+3];
            r1.x = acc[4] + bias[lane*8+4]; r1.y = acc[5] + bias[lane*8+5];
            r1.z = acc[6] + bias[lane*8+6]; r1.w = acc[7] + bias[lane*8+7];
            *(float4*)o = r0;
            *(float4*)(o + 4) = r1;
        }
    }
}

// LDS-tiled GEMM (no bias/activation): out[n][f] = sum_k h[n][k]*W[f][k].
// Output fp16 rows at 64-half pitch (feeds the fp16 hop).
template<int F>
__global__ __launch_bounds__(256, 4) void linear_tiled_kernel(const float* __restrict__ hin,
                                                              __half* __restrict__ outp,
                                                              const float* __restrict__ W,
                                                              int N_) {
    constexpr int BM = 64;
    __shared__ float hs[BM * 64];
    __shared__ float ws[64 * 64];
    const int tid  = threadIdx.x;
    const int base = blockIdx.x * BM;

    for (int u = tid; u < 64 * 16; u += 256) {
        int f = u >> 4, kc = u & 15;
        float4 v = (f < F) ? ((const float4*)W)[f * 16 + kc]
                           : make_float4(0.f, 0.f, 0.f, 0.f);
        *(float4*)&ws[f * 64 + ((kc ^ ((f >> 2) & 7)) << 2)] = v;
    }
    const int lim = min(BM, N_ - base);
    for (int u = tid; u < BM * 16; u += 256) {
        int n = u >> 4, kc = u & 15;
        float4 v = (n < lim) ? ((const float4*)(hin + (size_t)(base + n) * 64))[kc]
                             : make_float4(0.f, 0.f, 0.f, 0.f);
        *(float4*)&hs[n * 64 + ((kc ^ ((n >> 2) & 7)) << 2)] = v;
    }
    __syncthreads();

    const int f0 = (tid & 15) << 2;
    const int n0 = (tid >> 4) << 2;
    float4 acc[4];
    #pragma unroll
    for (int i = 0; i < 4; ++i) acc[i] = make_float4(0.f, 0.f, 0.f, 0.f);

    #pragma unroll 2
    for (int kc = 0; kc < 16; ++kc) {
        float4 hv[4], wv[4];
        #pragma unroll
        for (int i = 0; i < 4; ++i) {
            int n = n0 + i;
            hv[i] = *(const float4*)&hs[n * 64 + ((kc ^ ((n >> 2) & 7)) << 2)];
        }
        #pragma unroll
        for (int j = 0; j < 4; ++j) {
            int f = f0 + j;
            wv[j] = *(const float4*)&ws[f * 64 + ((kc ^ ((f >> 2) & 7)) << 2)];
        }
        #pragma unroll
        for (int i = 0; i < 4; ++i) {
            acc[i].x = fmaf(hv[i].x, wv[0].x, acc[i].x);
            acc[i].x = fmaf(hv[i].y, wv[0].y, acc[i].x);
            acc[i].x = fmaf(hv[i].z, wv[0].z, acc[i].x);
            acc[i].x = fmaf(hv[i].w, wv[0].w, acc[i].x);
            acc[i].y = fmaf(hv[i].x, wv[1].x, acc[i].y);
            acc[i].y = fmaf(hv[i].y, wv[1].y, acc[i].y);
            acc[i].y = fmaf(hv[i].z, wv[1].z, acc[i].y);
            acc[i].y = fmaf(hv[i].w, wv[1].w, acc[i].y);
            acc[i].z = fmaf(hv[i].x, wv[2].x, acc[i].z);
            acc[i].z = fmaf(hv[i].y, wv[2].y, acc[i].z);
            acc[i].z = fmaf(hv[i].z, wv[2].z, acc[i].z);
            acc[i].z = fmaf(hv[i].w, wv[2].w, acc[i].z);
            acc[i].w = fmaf(hv[i].x, wv[3].x, acc[i].w);
            acc[i].w = fmaf(hv[i].y, wv[3].y, acc[i].w);
            acc[i].w = fmaf(hv[i].z, wv[3].z, acc[i].w);
            acc[i].w = fmaf(hv[i].w, wv[3].w, acc[i].w);
        }
    }

    if (f0 < F) {
        #pragma unroll
        for (int i = 0; i < 4; ++i) {
            int n = base + n0 + i;
            if (n < N_) {
                __half* o = outp + (size_t)n * 64 + f0;
                ((__half2*)o)[0] = __floats2half2_rn(acc[i].x, acc[i].y);
                ((__half2*)o)[1] = __floats2half2_rn(acc[i].z, acc[i].w);
            }
        }
    }
}

extern "C" void kernel_launch(void* const* d_in, const int* in_sizes, int n_in,
                              void* d_out, int out_size, void* d_ws, size_t ws_size,
                              hipStream_t stream) {
    const float* x   = (const float*)d_in[0];
    const int*   ei  = (const int*)d_in[1];
    const float* w   = (const float*)d_in[2];
    const float* W1  = (const float*)d_in[3];
    const float* b1  = (const float*)d_in[4];
    const float* W2  = (const float*)d_in[5];
    const float* b2  = (const float*)d_in[6];
    float* out = (float*)d_out;

    const int N_ = in_sizes[0] / 64;        // 100000
    const int E_ = in_sizes[2];             // 1200000
    const int PB = (E_ + P1_EDGES - 1) / P1_EDGES;
    const int NB = (N_ + 127) >> 7;
    const int M  = NB * PB;

    char* ws = (char*)d_ws;
    size_t off = 0;
    auto alloc = [&](size_t bytes) { size_t o = off; off += (bytes + 255) & ~(size_t)255; return o; };
    float* dinv      = (float*)(ws + alloc((size_t)N_ * 4));
    int*   row_ptr   = (int*)  (ws + alloc(((size_t)N_ + 1) * 4));
    int*   bsums     = (int*)  (ws + alloc(1024 * 4));
    int*   coarseCnt = (int*)  (ws + alloc((size_t)M * 4));
    int*   coarseOff = (int*)  (ws + alloc(((size_t)M + 1) * 4));
    int2*  edge      = (int2*) (ws + alloc((size_t)E_ * 8));
    float* bufA      = (float*)(ws + alloc((size_t)N_ * 64 * 4));   // h (fp32) / sorted
    float* bufB      = (float*)(ws + alloc((size_t)N_ * 64 * 4));   // fp16 ping-pong
    int2*   sorted = (int2*)bufA;                                   // dead before hop2 writes h
    __half* hLo    = (__half*)bufB;                                 // y / z
    __half* hHi    = (__half*)((char*)bufB + (size_t)N_ * 64 * 2);  // Ay / Az
    (void)ws_size; (void)n_in; (void)out_size;

    const int bn = (N_ + 255) / 256;
    const int bh = (N_ + 3) / 4;
    const int nbs = (M + SCAN_CHUNK - 1) / SCAN_CHUNK;
    const int bl_ = (N_ + 63) / 64;

    // CSR build (atomic-free LDS counting sort) + dinv
    p1_count_kernel<<<PB, 256, 0, stream>>>(ei, coarseCnt, E_, PB, NB);
    scan_partial_kernel<<<nbs, SCAN_TPB, 0, stream>>>(coarseCnt, bsums, M);
    scan_bsums_kernel<<<1, 1024, 0, stream>>>(bsums, nbs, coarseOff, M);
    scan_final_kernel<<<nbs, SCAN_TPB, 0, stream>>>(coarseCnt, bsums, coarseOff, M);
    p1_scatter_kernel<<<PB, 256, 0, stream>>>(ei, w, coarseOff, sorted, E_, PB, NB);
    p2_fine_kernel<<<NB, 256, 0, stream>>>(sorted, coarseOff, edge, row_ptr, dinv, N_, E_, PB, NB);
    scale_csr_kernel<<<bn, 256, 0, stream>>>(edge, row_ptr, dinv, N_);

    // Layer 1: y = X W1^T (fp16 rows); h = relu(A^2 y + b1) (fp32)
    linear_tiled_kernel<64><<<bl_, 256, 0, stream>>>(x, hLo, W1, N_);
    hop_h_kernel<8, 0><<<bh, 256, 0, stream>>>(hLo, hHi, dinv, row_ptr, edge, nullptr, N_);
    hop_h_kernel<8, 1><<<bh, 256, 0, stream>>>(hHi, bufA, dinv, row_ptr, edge, b1, N_);
    // Layer 2: z = h W2^T (fp16 rows); out = A^2 z + b2 (fp32)
    linear_tiled_kernel<40><<<bl_, 256, 0, stream>>>(bufA, hLo, W2, N_);
    hop_h_kernel<5, 0><<<bh, 256, 0, stream>>>(hLo, hHi, dinv, row_ptr, edge, nullptr, N_);
    hop_h_kernel<5, 2><<<bh, 256, 0, stream>>>(hHi, out, dinv, row_ptr, edge, b2, N_);
}

// Round 11
// 267.747 us; speedup vs baseline: 2.5432x; 1.0120x over previous
//
#include <hip/hip_runtime.h>
#include <hip/hip_fp16.h>

// SGConv (K=2, two layers) on MI355X.
// R6: atomic-free CSR build (2-phase LDS counting sort).
// R7: hop-after-weight associativity rewrite (layer-2 on 40f).
// R8/R9: fp16 rows at 64-half pitch -> one 128B line per gather (fetch halved:
//     150->71MB/hop). R9 post-mortem: hop flipped to VALU-bound (55% busy) --
//     compiler emits 8 v_cvt_f32_f16 + 8 fma per lane/edge.
// R10: v_fma_mix_f32 inline asm: fp16 operand consumed directly by an fp32
//     FMA (op_sel picks hi/lo half). Halves hop VALU work; numerically
//     identical to cvt+fma.

#define SCAN_TPB 256
#define SCAN_ITEMS 8
#define SCAN_CHUNK (SCAN_TPB * SCAN_ITEMS)   // 2048 elements per block
#define P1_EDGES 8192                        // edges per phase-1 block
#define MAX_NB 784                           // coarse buckets (ceil(100000/128)=782)

// --- 3-phase hierarchical exclusive scan (generic: cnt[] -> out[], out[M]=total) ---

__global__ __launch_bounds__(SCAN_TPB) void scan_partial_kernel(const int* __restrict__ cnt,
                                                                int* __restrict__ bsums, int N_) {
    int t = threadIdx.x;
    int base = blockIdx.x * SCAN_CHUNK + t * SCAN_ITEMS;
    int s = 0;
    #pragma unroll
    for (int j = 0; j < SCAN_ITEMS; ++j) { int i = base + j; if (i < N_) s += cnt[i]; }
    __shared__ int sm[SCAN_TPB];
    sm[t] = s; __syncthreads();
    for (int o = SCAN_TPB / 2; o > 0; o >>= 1) {
        if (t < o) sm[t] += sm[t + o];
        __syncthreads();
    }
    if (t == 0) bsums[blockIdx.x] = sm[0];
}

__global__ __launch_bounds__(1024) void scan_bsums_kernel(int* bsums, int nb,
                                                          int* out, int N_) {
    __shared__ int sm[1024];
    int t = threadIdx.x;
    int v = (t < nb) ? bsums[t] : 0;
    sm[t] = v; __syncthreads();
    for (int o = 1; o < 1024; o <<= 1) {
        int u = (t >= o) ? sm[t - o] : 0;
        __syncthreads();
        sm[t] += u;
        __syncthreads();
    }
    if (t < nb) bsums[t] = sm[t] - v;          // exclusive block offset
    if (t == 1023) out[N_] = sm[1023];         // grand total
}

__global__ __launch_bounds__(SCAN_TPB) void scan_final_kernel(const int* __restrict__ cnt,
                                                              const int* __restrict__ bsums,
                                                              int* __restrict__ out, int N_) {
    int t = threadIdx.x;
    int base = blockIdx.x * SCAN_CHUNK + t * SCAN_ITEMS;
    int loc[SCAN_ITEMS];
    int s = 0;
    #pragma unroll
    for (int j = 0; j < SCAN_ITEMS; ++j) {
        int i = base + j;
        int c = (i < N_) ? cnt[i] : 0;
        loc[j] = s; s += c;
    }
    __shared__ int sm[SCAN_TPB];
    sm[t] = s; __syncthreads();
    for (int o = 1; o < SCAN_TPB; o <<= 1) {
        int u = (t >= o) ? sm[t - o] : 0;
        __syncthreads();
        sm[t] += u;
        __syncthreads();
    }
    int excl = bsums[blockIdx.x] + sm[t] - s;
    #pragma unroll
    for (int j = 0; j < SCAN_ITEMS; ++j) {
        int i = base + j;
        if (i < N_) out[i] = excl + loc[j];
    }
}

// --- Phase 1: coarse bucket (dst>>7) LDS histogram per 8192-edge block ---
__global__ __launch_bounds__(256) void p1_count_kernel(const int* __restrict__ ei,
                                                       int* __restrict__ coarseCnt,
                                                       int E_, int PB, int NB) {
    __shared__ int hist[MAX_NB];
    int tid = threadIdx.x;
    for (int u = tid; u < NB; u += 256) hist[u] = 0;
    __syncthreads();
    int base = blockIdx.x * P1_EDGES;
    #pragma unroll 4
    for (int j = 0; j < P1_EDGES / 256; ++j) {
        int e = base + j * 256 + tid;
        if (e < E_) atomicAdd(&hist[ei[E_ + e] >> 7], 1);
    }
    __syncthreads();
    for (int u = tid; u < NB; u += 256) coarseCnt[u * PB + blockIdx.x] = hist[u];
}

// Scatter edges into coarse-bucket-sorted order. LDS cursor = coarseOff column.
__global__ __launch_bounds__(256) void p1_scatter_kernel(const int* __restrict__ ei,
                                                         const float* __restrict__ w,
                                                         const int* __restrict__ coarseOff,
                                                         int2* __restrict__ sorted,
                                                         int E_, int PB, int NB) {
    __shared__ int lcur[MAX_NB];
    int tid = threadIdx.x;
    for (int u = tid; u < NB; u += 256) lcur[u] = coarseOff[u * PB + blockIdx.x];
    __syncthreads();
    int base = blockIdx.x * P1_EDGES;
    #pragma unroll 4
    for (int j = 0; j < P1_EDGES / 256; ++j) {
        int e = base + j * 256 + tid;
        if (e < E_) {
            int dst = ei[E_ + e];
            int b = dst >> 7;
            int pos = atomicAdd(&lcur[b], 1);
            sorted[pos] = make_int2(ei[e] | ((dst & 127) << 17), __float_as_int(w[e]));
        }
    }
}

// --- Phase 2: per coarse bucket: fine histogram + scan, CSR emit + dinv. ---
__global__ __launch_bounds__(256) void p2_fine_kernel(const int2* __restrict__ sorted,
                                                      const int* __restrict__ coarseOff,
                                                      int2* __restrict__ edge,
                                                      int* __restrict__ row_ptr,
                                                      float* __restrict__ dinv,
                                                      int N_, int E_, int PB, int NB) {
    __shared__ int fcnt[128], fexc[128], fcur[128];
    __shared__ float fdeg[128];
    const int b = blockIdx.x;
    const int tid = threadIdx.x;
    const int start = coarseOff[b * PB];
    const int end = (b + 1 < NB) ? coarseOff[(b + 1) * PB] : E_;
    if (tid < 128) { fcnt[tid] = 0; fdeg[tid] = 1.0f; }   // self-loop weight pre-added
    __syncthreads();
    for (int p = start + tid; p < end; p += 256)
        atomicAdd(&fcnt[sorted[p].x >> 17], 1);
    __syncthreads();
    if (tid < 128) fexc[tid] = fcnt[tid];
    __syncthreads();
    for (int o = 1; o < 128; o <<= 1) {
        int v = (tid < 128 && tid >= o) ? fexc[tid - o] : 0;
        __syncthreads();
        if (tid < 128) fexc[tid] += v;
        __syncthreads();
    }
    const int node0 = b << 7;
    if (tid < 128) {
        fexc[tid] -= fcnt[tid];          // inclusive -> exclusive
        fcur[tid] = 0;
        int node = node0 + tid;
        if (node < N_) row_ptr[node] = start + fexc[tid];
    }
    __syncthreads();
    for (int p = start + tid; p < end; p += 256) {
        int2 pk = sorted[p];
        int fine = pk.x >> 17;
        int src  = pk.x & 0x1FFFF;
        int r = atomicAdd(&fcur[fine], 1);
        atomicAdd(&fdeg[fine], __int_as_float(pk.y));
        edge[start + fexc[fine] + r] = make_int2(src, pk.y);
    }
    __syncthreads();
    if (tid < 128) {
        int node = node0 + tid;
        if (node < N_) {
            float s = fdeg[tid];
            dinv[node] = (s > 0.f) ? (1.0f / sqrtf(s)) : 0.f;
        }
    }
    if (b == 0 && tid == 0) row_ptr[N_] = E_;
}

// In CSR order: edge[p].y = w * dinv[src] * dinv[dst].
__global__ __launch_bounds__(256) void scale_csr_kernel(int2* __restrict__ edge,
                                                        const int* __restrict__ row_ptr,
                                                        const float* __restrict__ dinv, int N_) {
    int n = blockIdx.x * blockDim.x + threadIdx.x;
    if (n < N_) {
        float dd = dinv[n];
        int p0 = row_ptr[n], p1 = row_ptr[n + 1];
        for (int p = p0; p < p1; ++p) {
            int2 e = edge[p];
            edge[p].y = __float_as_int(__int_as_float(e.y) * dinv[e.x] * dd);
        }
    }
}

// fp32-FMA with fp16 src0, no conversion instruction (VOP3P v_fma_mix_f32).
// LO: acc += lo_half(h) * v ; HI: acc += hi_half(h) * v. Bit-identical to
// cvt_f32_f16 + fma.
#define FMA_MIX_LO(accv, hbits, vw) \
    asm("v_fma_mix_f32 %0, %1, %2, %0 op_sel_hi:[1,0,0]" : "+v"(accv) : "v"(hbits), "v"(vw))
#define FMA_MIX_HI(accv, hbits, vw) \
    asm("v_fma_mix_f32 %0, %1, %2, %0 op_sel:[1,0,0] op_sel_hi:[1,0,0]" : "+v"(accv) : "v"(hbits), "v"(vw))

// fp16-row hop. Rows at 64-half pitch (128B = ONE cache line). SLOTS real
// float4 slots (8 -> 64f, 5 -> 40f); octet groups: 8 lanes/row, 8 rows in
// flight per gather instruction. EPI: 0 = fp16 out (pitch 64h),
// 1 = +bias+relu fp32 out (pitch 64f), 2 = +bias fp32 out (pitch 40f).
template<int SLOTS, int EPI>
__global__ __launch_bounds__(256) void hop_h_kernel(const __half* __restrict__ xin,
                                                    void* __restrict__ xout,
                                                    const float* __restrict__ dinv,
                                                    const int* __restrict__ row_ptr,
                                                    const int2* __restrict__ edge,
                                                    const float* __restrict__ bias, int N_) {
    int wave = (blockIdx.x * blockDim.x + threadIdx.x) >> 6;
    int lane = threadIdx.x & 63;
    if (wave >= N_) return;
    const int d    = wave;
    const int q8   = lane >> 3;               // octet 0..7
    const int sl   = lane & 7;
    const int slot = (SLOTS == 8) ? sl : min(sl, SLOTS - 1);  // clamped lanes stay in-line

    int e0 = row_ptr[d], e1 = row_ptr[d + 1];
    int nE = e1 - e0;
    float di = dinv[d];

    float sf[8];
    {
        float4 sv = ((const float4*)(xin + (size_t)d * 64))[slot];
        const __half2* h2 = (const __half2*)&sv;
        #pragma unroll
        for (int u = 0; u < 4; ++u) {
            float2 f = __half22float2(h2[u]);
            sf[2 * u] = f.x; sf[2 * u + 1] = f.y;
        }
    }
    float acc[8];
    #pragma unroll
    for (int u = 0; u < 8; ++u) acc[u] = 0.f;

    for (int eb = 0; eb < nE; eb += 64) {
        bool ok = (eb + lane) < nE;
        int2 ev = ok ? edge[e0 + eb + lane] : make_int2(d, 0);
        int m = min(64, nE - eb);
        for (int g = 0; g < m; g += 32) {
            int   s0 = __shfl(ev.x, g + q8);
            int   s1 = __shfl(ev.x, g + 8 + q8);
            int   s2 = __shfl(ev.x, g + 16 + q8);
            int   s3 = __shfl(ev.x, g + 24 + q8);
            float v0 = __shfl(__int_as_float(ev.y), g + q8);
            float v1 = __shfl(__int_as_float(ev.y), g + 8 + q8);
            float v2 = __shfl(__int_as_float(ev.y), g + 16 + q8);
            float v3 = __shfl(__int_as_float(ev.y), g + 24 + q8);
            float4 x0 = ((const float4*)(xin + (size_t)s0 * 64))[slot];
            float4 x1 = ((const float4*)(xin + (size_t)s1 * 64))[slot];
            float4 x2 = ((const float4*)(xin + (size_t)s2 * 64))[slot];
            float4 x3 = ((const float4*)(xin + (size_t)s3 * 64))[slot];
            #pragma unroll
            for (int u = 0; u < 4; ++u) {
                float h0 = ((const float*)&x0)[u];
                float h1 = ((const float*)&x1)[u];
                float h2v = ((const float*)&x2)[u];
                float h3v = ((const float*)&x3)[u];
                FMA_MIX_LO(acc[2*u],   h0,  v0);
                FMA_MIX_HI(acc[2*u+1], h0,  v0);
                FMA_MIX_LO(acc[2*u],   h1,  v1);
                FMA_MIX_HI(acc[2*u+1], h1,  v1);
                FMA_MIX_LO(acc[2*u],   h2v, v2);
                FMA_MIX_HI(acc[2*u+1], h2v, v2);
                FMA_MIX_LO(acc[2*u],   h3v, v3);
                FMA_MIX_HI(acc[2*u+1], h3v, v3);
            }
        }
    }
    // reduce the 8 octet partials (lanes differing in bits 3..5)
    #pragma unroll
    for (int u = 0; u < 8; ++u) {
        acc[u] += __shfl_xor(acc[u], 8);
        acc[u] += __shfl_xor(acc[u], 16);
        acc[u] += __shfl_xor(acc[u], 32);
    }
    float dii = di * di;
    #pragma unroll
    for (int u = 0; u < 8; ++u) acc[u] = fmaf(dii, sf[u], acc[u]);

    if (lane < SLOTS) {   // octet 0, lane == slot
        if constexpr (EPI == 0) {
            union { __half2 h2[4]; float4 f4; } pk;
            #pragma unroll
            for (int u = 0; u < 4; ++u)
                pk.h2[u] = __floats2half2_rn(acc[2*u], acc[2*u+1]);
            ((float4*)((__half*)xout + (size_t)d * 64))[lane] = pk.f4;
        } else if constexpr (EPI == 1) {
            float* o = (float*)xout + (size_t)d * 64 + lane * 8;
            float4 r0, r1;
            r0.x = fmaxf(acc[0] + bias[lane*8+0], 0.f); r0.y = fmaxf(acc[1] + bias[lane*8+1], 0.f);
            r0.z = fmaxf(acc[2] + bias[lane*8+2], 0.f); r0.w = fmaxf(acc[3] + bias[lane*8+3], 0.f);
            r1.x = fmaxf(acc[4] + bias[lane*8+4], 0.f); r1.y = fmaxf(acc[5] + bias[lane*8+5], 0.f);
            r1.z = fmaxf(acc[6] + bias[lane*8+6], 0.f); r1.w = fmaxf(acc[7] + bias[lane*8+7], 0.f);
            *(float4*)o = r0;
            *(float4*)(o + 4) = r1;
        } else {
            float* o = (float*)xout + (size_t)d * 40 + lane * 8;
            float4 r0, r1;
            r0.x = acc[0] + bias[lane*8+0]; r0.y = acc[1] + bias[lane*8+1];
            r0.z = acc[2] + bias[lane*8+2]; r0.w = acc[3] + bias[lane*8+3];
            r1.x = acc[4] + bias[lane*8+4]; r1.y = acc[5] + bias[lane*8+5];
            r1.z = acc[6] + bias[lane*8+6]; r1.w = acc[7] + bias[lane*8+7];
            *(float4*)o = r0;
            *(float4*)(o + 4) = r1;
        }
    }
}

// LDS-tiled GEMM (no bias/activation): out[n][f] = sum_k h[n][k]*W[f][k].
// Output fp16 rows at 64-half pitch (feeds the fp16 hop).
template<int F>
__global__ __launch_bounds__(256, 4) void linear_tiled_kernel(const float* __restrict__ hin,
                                                              __half* __restrict__ outp,
                                                              const float* __restrict__ W,
                                                              int N_) {
    constexpr int BM = 64;
    __shared__ float hs[BM * 64];
    __shared__ float ws[64 * 64];
    const int tid  = threadIdx.x;
    const int base = blockIdx.x * BM;

    for (int u = tid; u < 64 * 16; u += 256) {
        int f = u >> 4, kc = u & 15;
        float4 v = (f < F) ? ((const float4*)W)[f * 16 + kc]
                           : make_float4(0.f, 0.f, 0.f, 0.f);
        *(float4*)&ws[f * 64 + ((kc ^ ((f >> 2) & 7)) << 2)] = v;
    }
    const int lim = min(BM, N_ - base);
    for (int u = tid; u < BM * 16; u += 256) {
        int n = u >> 4, kc = u & 15;
        float4 v = (n < lim) ? ((const float4*)(hin + (size_t)(base + n) * 64))[kc]
                             : make_float4(0.f, 0.f, 0.f, 0.f);
        *(float4*)&hs[n * 64 + ((kc ^ ((n >> 2) & 7)) << 2)] = v;
    }
    __syncthreads();

    const int f0 = (tid & 15) << 2;
    const int n0 = (tid >> 4) << 2;
    float4 acc[4];
    #pragma unroll
    for (int i = 0; i < 4; ++i) acc[i] = make_float4(0.f, 0.f, 0.f, 0.f);

    #pragma unroll 2
    for (int kc = 0; kc < 16; ++kc) {
        float4 hv[4], wv[4];
        #pragma unroll
        for (int i = 0; i < 4; ++i) {
            int n = n0 + i;
            hv[i] = *(const float4*)&hs[n * 64 + ((kc ^ ((n >> 2) & 7)) << 2)];
        }
        #pragma unroll
        for (int j = 0; j < 4; ++j) {
            int f = f0 + j;
            wv[j] = *(const float4*)&ws[f * 64 + ((kc ^ ((f >> 2) & 7)) << 2)];
        }
        #pragma unroll
        for (int i = 0; i < 4; ++i) {
            acc[i].x = fmaf(hv[i].x, wv[0].x, acc[i].x);
            acc[i].x = fmaf(hv[i].y, wv[0].y, acc[i].x);
            acc[i].x = fmaf(hv[i].z, wv[0].z, acc[i].x);
            acc[i].x = fmaf(hv[i].w, wv[0].w, acc[i].x);
            acc[i].y = fmaf(hv[i].x, wv[1].x, acc[i].y);
            acc[i].y = fmaf(hv[i].y, wv[1].y, acc[i].y);
            acc[i].y = fmaf(hv[i].z, wv[1].z, acc[i].y);
            acc[i].y = fmaf(hv[i].w, wv[1].w, acc[i].y);
            acc[i].z = fmaf(hv[i].x, wv[2].x, acc[i].z);
            acc[i].z = fmaf(hv[i].y, wv[2].y, acc[i].z);
            acc[i].z = fmaf(hv[i].z, wv[2].z, acc[i].z);
            acc[i].z = fmaf(hv[i].w, wv[2].w, acc[i].z);
            acc[i].w = fmaf(hv[i].x, wv[3].x, acc[i].w);
            acc[i].w = fmaf(hv[i].y, wv[3].y, acc[i].w);
            acc[i].w = fmaf(hv[i].z, wv[3].z, acc[i].w);
            acc[i].w = fmaf(hv[i].w, wv[3].w, acc[i].w);
        }
    }

    if (f0 < F) {
        #pragma unroll
        for (int i = 0; i < 4; ++i) {
            int n = base + n0 + i;
            if (n < N_) {
                __half* o = outp + (size_t)n * 64 + f0;
                ((__half2*)o)[0] = __floats2half2_rn(acc[i].x, acc[i].y);
                ((__half2*)o)[1] = __floats2half2_rn(acc[i].z, acc[i].w);
            }
        }
    }
}

extern "C" void kernel_launch(void* const* d_in, const int* in_sizes, int n_in,
                              void* d_out, int out_size, void* d_ws, size_t ws_size,
                              hipStream_t stream) {
    const float* x   = (const float*)d_in[0];
    const int*   ei  = (const int*)d_in[1];
    const float* w   = (const float*)d_in[2];
    const float* W1  = (const float*)d_in[3];
    const float* b1  = (const float*)d_in[4];
    const float* W2  = (const float*)d_in[5];
    const float* b2  = (const float*)d_in[6];
    float* out = (float*)d_out;

    const int N_ = in_sizes[0] / 64;        // 100000
    const int E_ = in_sizes[2];             // 1200000
    const int PB = (E_ + P1_EDGES - 1) / P1_EDGES;
    const int NB = (N_ + 127) >> 7;
    const int M  = NB * PB;

    char* ws = (char*)d_ws;
    size_t off = 0;
    auto alloc = [&](size_t bytes) { size_t o = off; off += (bytes + 255) & ~(size_t)255; return o; };
    float* dinv      = (float*)(ws + alloc((size_t)N_ * 4));
    int*   row_ptr   = (int*)  (ws + alloc(((size_t)N_ + 1) * 4));
    int*   bsums     = (int*)  (ws + alloc(1024 * 4));
    int*   coarseCnt = (int*)  (ws + alloc((size_t)M * 4));
    int*   coarseOff = (int*)  (ws + alloc(((size_t)M + 1) * 4));
    int2*  edge      = (int2*) (ws + alloc((size_t)E_ * 8));
    float* bufA      = (float*)(ws + alloc((size_t)N_ * 64 * 4));   // h (fp32) / sorted
    float* bufB      = (float*)(ws + alloc((size_t)N_ * 64 * 4));   // fp16 ping-pong
    int2*   sorted = (int2*)bufA;                                   // dead before hop2 writes h
    __half* hLo    = (__half*)bufB;                                 // y / z
    __half* hHi    = (__half*)((char*)bufB + (size_t)N_ * 64 * 2);  // Ay / Az
    (void)ws_size; (void)n_in; (void)out_size;

    const int bn = (N_ + 255) / 256;
    const int bh = (N_ + 3) / 4;
    const int nbs = (M + SCAN_CHUNK - 1) / SCAN_CHUNK;
    const int bl_ = (N_ + 63) / 64;

    // CSR build (atomic-free LDS counting sort) + dinv
    p1_count_kernel<<<PB, 256, 0, stream>>>(ei, coarseCnt, E_, PB, NB);
    scan_partial_kernel<<<nbs, SCAN_TPB, 0, stream>>>(coarseCnt, bsums, M);
    scan_bsums_kernel<<<1, 1024, 0, stream>>>(bsums, nbs, coarseOff, M);
    scan_final_kernel<<<nbs, SCAN_TPB, 0, stream>>>(coarseCnt, bsums, coarseOff, M);
    p1_scatter_kernel<<<PB, 256, 0, stream>>>(ei, w, coarseOff, sorted, E_, PB, NB);
    p2_fine_kernel<<<NB, 256, 0, stream>>>(sorted, coarseOff, edge, row_ptr, dinv, N_, E_, PB, NB);
    scale_csr_kernel<<<bn, 256, 0, stream>>>(edge, row_ptr, dinv, N_);

    // Layer 1: y = X W1^T (fp16 rows); h = relu(A^2 y + b1) (fp32)
    linear_tiled_kernel<64><<<bl_, 256, 0, stream>>>(x, hLo, W1, N_);
    hop_h_kernel<8, 0><<<bh, 256, 0, stream>>>(hLo, hHi, dinv, row_ptr, edge, nullptr, N_);
    hop_h_kernel<8, 1><<<bh, 256, 0, stream>>>(hHi, bufA, dinv, row_ptr, edge, b1, N_);
    // Layer 2: z = h W2^T (fp16 rows); out = A^2 z + b2 (fp32)
    linear_tiled_kernel<40><<<bl_, 256, 0, stream>>>(bufA, hLo, W2, N_);
    hop_h_kernel<5, 0><<<bh, 256, 0, stream>>>(hLo, hHi, dinv, row_ptr, edge, nullptr, N_);
    hop_h_kernel<5, 2><<<bh, 256, 0, stream>>>(hHi, out, dinv, row_ptr, edge, b2, N_);
}

// Round 12
// 257.651 us; speedup vs baseline: 2.6429x; 1.0392x over previous
//
#include <hip/hip_runtime.h>
#include <hip/hip_fp16.h>

// SGConv (K=2, two layers) on MI355X.
// R6: atomic-free CSR build (2-phase LDS counting sort).
// R7: hop-after-weight associativity rewrite (layer-2 on 40f).
// R8/R9: fp16 rows at 64-half pitch -> one 128B line per gather.
// R10: v_fma_mix_f32 (no cvt). Null result: hop is per-NODE-overhead bound
//     (deg~12 vs 32-edge groups + 24-swizzle reduce + prologue).
// R11: 16-lane row groups (4 rows in flight), 8-edge step granularity,
//     4 accumulators -> 2-level reduce (8 swizzles). Fixed+padded work ~halved.

#define SCAN_TPB 256
#define SCAN_ITEMS 8
#define SCAN_CHUNK (SCAN_TPB * SCAN_ITEMS)   // 2048 elements per block
#define P1_EDGES 8192                        // edges per phase-1 block
#define MAX_NB 784                           // coarse buckets (ceil(100000/128)=782)

// --- 3-phase hierarchical exclusive scan (generic: cnt[] -> out[], out[M]=total) ---

__global__ __launch_bounds__(SCAN_TPB) void scan_partial_kernel(const int* __restrict__ cnt,
                                                                int* __restrict__ bsums, int N_) {
    int t = threadIdx.x;
    int base = blockIdx.x * SCAN_CHUNK + t * SCAN_ITEMS;
    int s = 0;
    #pragma unroll
    for (int j = 0; j < SCAN_ITEMS; ++j) { int i = base + j; if (i < N_) s += cnt[i]; }
    __shared__ int sm[SCAN_TPB];
    sm[t] = s; __syncthreads();
    for (int o = SCAN_TPB / 2; o > 0; o >>= 1) {
        if (t < o) sm[t] += sm[t + o];
        __syncthreads();
    }
    if (t == 0) bsums[blockIdx.x] = sm[0];
}

__global__ __launch_bounds__(1024) void scan_bsums_kernel(int* bsums, int nb,
                                                          int* out, int N_) {
    __shared__ int sm[1024];
    int t = threadIdx.x;
    int v = (t < nb) ? bsums[t] : 0;
    sm[t] = v; __syncthreads();
    for (int o = 1; o < 1024; o <<= 1) {
        int u = (t >= o) ? sm[t - o] : 0;
        __syncthreads();
        sm[t] += u;
        __syncthreads();
    }
    if (t < nb) bsums[t] = sm[t] - v;          // exclusive block offset
    if (t == 1023) out[N_] = sm[1023];         // grand total
}

__global__ __launch_bounds__(SCAN_TPB) void scan_final_kernel(const int* __restrict__ cnt,
                                                              const int* __restrict__ bsums,
                                                              int* __restrict__ out, int N_) {
    int t = threadIdx.x;
    int base = blockIdx.x * SCAN_CHUNK + t * SCAN_ITEMS;
    int loc[SCAN_ITEMS];
    int s = 0;
    #pragma unroll
    for (int j = 0; j < SCAN_ITEMS; ++j) {
        int i = base + j;
        int c = (i < N_) ? cnt[i] : 0;
        loc[j] = s; s += c;
    }
    __shared__ int sm[SCAN_TPB];
    sm[t] = s; __syncthreads();
    for (int o = 1; o < SCAN_TPB; o <<= 1) {
        int u = (t >= o) ? sm[t - o] : 0;
        __syncthreads();
        sm[t] += u;
        __syncthreads();
    }
    int excl = bsums[blockIdx.x] + sm[t] - s;
    #pragma unroll
    for (int j = 0; j < SCAN_ITEMS; ++j) {
        int i = base + j;
        if (i < N_) out[i] = excl + loc[j];
    }
}

// --- Phase 1: coarse bucket (dst>>7) LDS histogram per 8192-edge block ---
__global__ __launch_bounds__(256) void p1_count_kernel(const int* __restrict__ ei,
                                                       int* __restrict__ coarseCnt,
                                                       int E_, int PB, int NB) {
    __shared__ int hist[MAX_NB];
    int tid = threadIdx.x;
    for (int u = tid; u < NB; u += 256) hist[u] = 0;
    __syncthreads();
    int base = blockIdx.x * P1_EDGES;
    #pragma unroll 4
    for (int j = 0; j < P1_EDGES / 256; ++j) {
        int e = base + j * 256 + tid;
        if (e < E_) atomicAdd(&hist[ei[E_ + e] >> 7], 1);
    }
    __syncthreads();
    for (int u = tid; u < NB; u += 256) coarseCnt[u * PB + blockIdx.x] = hist[u];
}

// Scatter edges into coarse-bucket-sorted order. LDS cursor = coarseOff column.
__global__ __launch_bounds__(256) void p1_scatter_kernel(const int* __restrict__ ei,
                                                         const float* __restrict__ w,
                                                         const int* __restrict__ coarseOff,
                                                         int2* __restrict__ sorted,
                                                         int E_, int PB, int NB) {
    __shared__ int lcur[MAX_NB];
    int tid = threadIdx.x;
    for (int u = tid; u < NB; u += 256) lcur[u] = coarseOff[u * PB + blockIdx.x];
    __syncthreads();
    int base = blockIdx.x * P1_EDGES;
    #pragma unroll 4
    for (int j = 0; j < P1_EDGES / 256; ++j) {
        int e = base + j * 256 + tid;
        if (e < E_) {
            int dst = ei[E_ + e];
            int b = dst >> 7;
            int pos = atomicAdd(&lcur[b], 1);
            sorted[pos] = make_int2(ei[e] | ((dst & 127) << 17), __float_as_int(w[e]));
        }
    }
}

// --- Phase 2: per coarse bucket: fine histogram + scan, CSR emit + dinv. ---
__global__ __launch_bounds__(256) void p2_fine_kernel(const int2* __restrict__ sorted,
                                                      const int* __restrict__ coarseOff,
                                                      int2* __restrict__ edge,
                                                      int* __restrict__ row_ptr,
                                                      float* __restrict__ dinv,
                                                      int N_, int E_, int PB, int NB) {
    __shared__ int fcnt[128], fexc[128], fcur[128];
    __shared__ float fdeg[128];
    const int b = blockIdx.x;
    const int tid = threadIdx.x;
    const int start = coarseOff[b * PB];
    const int end = (b + 1 < NB) ? coarseOff[(b + 1) * PB] : E_;
    if (tid < 128) { fcnt[tid] = 0; fdeg[tid] = 1.0f; }   // self-loop weight pre-added
    __syncthreads();
    for (int p = start + tid; p < end; p += 256)
        atomicAdd(&fcnt[sorted[p].x >> 17], 1);
    __syncthreads();
    if (tid < 128) fexc[tid] = fcnt[tid];
    __syncthreads();
    for (int o = 1; o < 128; o <<= 1) {
        int v = (tid < 128 && tid >= o) ? fexc[tid - o] : 0;
        __syncthreads();
        if (tid < 128) fexc[tid] += v;
        __syncthreads();
    }
    const int node0 = b << 7;
    if (tid < 128) {
        fexc[tid] -= fcnt[tid];          // inclusive -> exclusive
        fcur[tid] = 0;
        int node = node0 + tid;
        if (node < N_) row_ptr[node] = start + fexc[tid];
    }
    __syncthreads();
    for (int p = start + tid; p < end; p += 256) {
        int2 pk = sorted[p];
        int fine = pk.x >> 17;
        int src  = pk.x & 0x1FFFF;
        int r = atomicAdd(&fcur[fine], 1);
        atomicAdd(&fdeg[fine], __int_as_float(pk.y));
        edge[start + fexc[fine] + r] = make_int2(src, pk.y);
    }
    __syncthreads();
    if (tid < 128) {
        int node = node0 + tid;
        if (node < N_) {
            float s = fdeg[tid];
            dinv[node] = (s > 0.f) ? (1.0f / sqrtf(s)) : 0.f;
        }
    }
    if (b == 0 && tid == 0) row_ptr[N_] = E_;
}

// In CSR order: edge[p].y = w * dinv[src] * dinv[dst].
__global__ __launch_bounds__(256) void scale_csr_kernel(int2* __restrict__ edge,
                                                        const int* __restrict__ row_ptr,
                                                        const float* __restrict__ dinv, int N_) {
    int n = blockIdx.x * blockDim.x + threadIdx.x;
    if (n < N_) {
        float dd = dinv[n];
        int p0 = row_ptr[n], p1 = row_ptr[n + 1];
        for (int p = p0; p < p1; ++p) {
            int2 e = edge[p];
            edge[p].y = __float_as_int(__int_as_float(e.y) * dinv[e.x] * dd);
        }
    }
}

// fp32-FMA with fp16 src0, no conversion instruction (VOP3P v_fma_mix_f32).
#define FMA_MIX_LO(accv, hbits, vw) \
    asm("v_fma_mix_f32 %0, %1, %2, %0 op_sel_hi:[1,0,0]" : "+v"(accv) : "v"(hbits), "v"(vw))
#define FMA_MIX_HI(accv, hbits, vw) \
    asm("v_fma_mix_f32 %0, %1, %2, %0 op_sel:[1,0,0] op_sel_hi:[1,0,0]" : "+v"(accv) : "v"(hbits), "v"(vw))

// fp16-row hop, 16-lane row groups. Rows at 64-half pitch (128B = one line);
// lane covers 4 halves (float2). 4 groups/wave -> 4 rows in flight per gather,
// edge-step 8 (two 4-edge subgroups). 2-level xor reduce (8 swizzles).
// NL = active lanes/group (16 -> 64f, 10 -> 40f). EPI: 0 = fp16 out (pitch
// 64h), 1 = +bias+relu fp32 out (pitch 64f), 2 = +bias fp32 out (pitch 40f).
template<int NL, int EPI>
__global__ __launch_bounds__(256) void hop_h_kernel(const __half* __restrict__ xin,
                                                    void* __restrict__ xout,
                                                    const float* __restrict__ dinv,
                                                    const int* __restrict__ row_ptr,
                                                    const int2* __restrict__ edge,
                                                    const float* __restrict__ bias, int N_) {
    int wave = (blockIdx.x * blockDim.x + threadIdx.x) >> 6;
    int lane = threadIdx.x & 63;
    if (wave >= N_) return;
    const int d   = wave;
    const int g4  = lane >> 4;                          // row group 0..3
    const int hl  = lane & 15;
    const int hle = (NL == 16) ? hl : min(hl, NL - 1);  // clamped lanes stay in-line

    int e0 = row_ptr[d], e1 = row_ptr[d + 1];
    int nE = e1 - e0;
    float di = dinv[d];
    float2 selfv = ((const float2*)(xin + (size_t)d * 64))[hle];
    float acc[4] = {0.f, 0.f, 0.f, 0.f};

    for (int eb = 0; eb < nE; eb += 64) {
        bool ok = (eb + lane) < nE;
        int2 ev = ok ? edge[e0 + eb + lane] : make_int2(d, 0);   // pad: self row, w=0
        int m = min(64, nE - eb);
        for (int g = 0; g < m; g += 8) {
            // two 4-edge subgroups in flight (indices <= 63 always; pads valid)
            int   s0 = __shfl(ev.x, g + g4);
            int   s1 = __shfl(ev.x, g + 4 + g4);
            float v0 = __shfl(__int_as_float(ev.y), g + g4);
            float v1 = __shfl(__int_as_float(ev.y), g + 4 + g4);
            float2 x0 = ((const float2*)(xin + (size_t)s0 * 64))[hle];
            float2 x1 = ((const float2*)(xin + (size_t)s1 * 64))[hle];
            FMA_MIX_LO(acc[0], x0.x, v0); FMA_MIX_HI(acc[1], x0.x, v0);
            FMA_MIX_LO(acc[2], x0.y, v0); FMA_MIX_HI(acc[3], x0.y, v0);
            FMA_MIX_LO(acc[0], x1.x, v1); FMA_MIX_HI(acc[1], x1.x, v1);
            FMA_MIX_LO(acc[2], x1.y, v1); FMA_MIX_HI(acc[3], x1.y, v1);
        }
    }
    // combine the 4 row-group partials (lanes differing in bits 4..5)
    #pragma unroll
    for (int u = 0; u < 4; ++u) {
        acc[u] += __shfl_xor(acc[u], 16);
        acc[u] += __shfl_xor(acc[u], 32);
    }
    float dii = di * di;
    FMA_MIX_LO(acc[0], selfv.x, dii); FMA_MIX_HI(acc[1], selfv.x, dii);
    FMA_MIX_LO(acc[2], selfv.y, dii); FMA_MIX_HI(acc[3], selfv.y, dii);

    if (lane < NL) {   // group 0, lane == hl; features 4*lane .. 4*lane+3
        if constexpr (EPI == 0) {
            float2 pk;
            ((__half2*)&pk)[0] = __floats2half2_rn(acc[0], acc[1]);
            ((__half2*)&pk)[1] = __floats2half2_rn(acc[2], acc[3]);
            ((float2*)((__half*)xout + (size_t)d * 64))[lane] = pk;
        } else if constexpr (EPI == 1) {
            float4 bv = ((const float4*)bias)[lane];
            float4 r;
            r.x = fmaxf(acc[0] + bv.x, 0.f); r.y = fmaxf(acc[1] + bv.y, 0.f);
            r.z = fmaxf(acc[2] + bv.z, 0.f); r.w = fmaxf(acc[3] + bv.w, 0.f);
            ((float4*)((float*)xout + (size_t)d * 64))[lane] = r;
        } else {
            float4 bv = ((const float4*)bias)[lane];
            float4 r = make_float4(acc[0] + bv.x, acc[1] + bv.y,
                                   acc[2] + bv.z, acc[3] + bv.w);
            *(float4*)((float*)xout + (size_t)d * 40 + lane * 4) = r;
        }
    }
}

// LDS-tiled GEMM (no bias/activation): out[n][f] = sum_k h[n][k]*W[f][k].
// Output fp16 rows at 64-half pitch (feeds the fp16 hop).
template<int F>
__global__ __launch_bounds__(256, 4) void linear_tiled_kernel(const float* __restrict__ hin,
                                                              __half* __restrict__ outp,
                                                              const float* __restrict__ W,
                                                              int N_) {
    constexpr int BM = 64;
    __shared__ float hs[BM * 64];
    __shared__ float ws[64 * 64];
    const int tid  = threadIdx.x;
    const int base = blockIdx.x * BM;

    for (int u = tid; u < 64 * 16; u += 256) {
        int f = u >> 4, kc = u & 15;
        float4 v = (f < F) ? ((const float4*)W)[f * 16 + kc]
                           : make_float4(0.f, 0.f, 0.f, 0.f);
        *(float4*)&ws[f * 64 + ((kc ^ ((f >> 2) & 7)) << 2)] = v;
    }
    const int lim = min(BM, N_ - base);
    for (int u = tid; u < BM * 16; u += 256) {
        int n = u >> 4, kc = u & 15;
        float4 v = (n < lim) ? ((const float4*)(hin + (size_t)(base + n) * 64))[kc]
                             : make_float4(0.f, 0.f, 0.f, 0.f);
        *(float4*)&hs[n * 64 + ((kc ^ ((n >> 2) & 7)) << 2)] = v;
    }
    __syncthreads();

    const int f0 = (tid & 15) << 2;
    const int n0 = (tid >> 4) << 2;
    float4 acc[4];
    #pragma unroll
    for (int i = 0; i < 4; ++i) acc[i] = make_float4(0.f, 0.f, 0.f, 0.f);

    #pragma unroll 2
    for (int kc = 0; kc < 16; ++kc) {
        float4 hv[4], wv[4];
        #pragma unroll
        for (int i = 0; i < 4; ++i) {
            int n = n0 + i;
            hv[i] = *(const float4*)&hs[n * 64 + ((kc ^ ((n >> 2) & 7)) << 2)];
        }
        #pragma unroll
        for (int j = 0; j < 4; ++j) {
            int f = f0 + j;
            wv[j] = *(const float4*)&ws[f * 64 + ((kc ^ ((f >> 2) & 7)) << 2)];
        }
        #pragma unroll
        for (int i = 0; i < 4; ++i) {
            acc[i].x = fmaf(hv[i].x, wv[0].x, acc[i].x);
            acc[i].x = fmaf(hv[i].y, wv[0].y, acc[i].x);
            acc[i].x = fmaf(hv[i].z, wv[0].z, acc[i].x);
            acc[i].x = fmaf(hv[i].w, wv[0].w, acc[i].x);
            acc[i].y = fmaf(hv[i].x, wv[1].x, acc[i].y);
            acc[i].y = fmaf(hv[i].y, wv[1].y, acc[i].y);
            acc[i].y = fmaf(hv[i].z, wv[1].z, acc[i].y);
            acc[i].y = fmaf(hv[i].w, wv[1].w, acc[i].y);
            acc[i].z = fmaf(hv[i].x, wv[2].x, acc[i].z);
            acc[i].z = fmaf(hv[i].y, wv[2].y, acc[i].z);
            acc[i].z = fmaf(hv[i].z, wv[2].z, acc[i].z);
            acc[i].z = fmaf(hv[i].w, wv[2].w, acc[i].z);
            acc[i].w = fmaf(hv[i].x, wv[3].x, acc[i].w);
            acc[i].w = fmaf(hv[i].y, wv[3].y, acc[i].w);
            acc[i].w = fmaf(hv[i].z, wv[3].z, acc[i].w);
            acc[i].w = fmaf(hv[i].w, wv[3].w, acc[i].w);
        }
    }

    if (f0 < F) {
        #pragma unroll
        for (int i = 0; i < 4; ++i) {
            int n = base + n0 + i;
            if (n < N_) {
                __half* o = outp + (size_t)n * 64 + f0;
                ((__half2*)o)[0] = __floats2half2_rn(acc[i].x, acc[i].y);
                ((__half2*)o)[1] = __floats2half2_rn(acc[i].z, acc[i].w);
            }
        }
    }
}

extern "C" void kernel_launch(void* const* d_in, const int* in_sizes, int n_in,
                              void* d_out, int out_size, void* d_ws, size_t ws_size,
                              hipStream_t stream) {
    const float* x   = (const float*)d_in[0];
    const int*   ei  = (const int*)d_in[1];
    const float* w   = (const float*)d_in[2];
    const float* W1  = (const float*)d_in[3];
    const float* b1  = (const float*)d_in[4];
    const float* W2  = (const float*)d_in[5];
    const float* b2  = (const float*)d_in[6];
    float* out = (float*)d_out;

    const int N_ = in_sizes[0] / 64;        // 100000
    const int E_ = in_sizes[2];             // 1200000
    const int PB = (E_ + P1_EDGES - 1) / P1_EDGES;
    const int NB = (N_ + 127) >> 7;
    const int M  = NB * PB;

    char* ws = (char*)d_ws;
    size_t off = 0;
    auto alloc = [&](size_t bytes) { size_t o = off; off += (bytes + 255) & ~(size_t)255; return o; };
    float* dinv      = (float*)(ws + alloc((size_t)N_ * 4));
    int*   row_ptr   = (int*)  (ws + alloc(((size_t)N_ + 1) * 4));
    int*   bsums     = (int*)  (ws + alloc(1024 * 4));
    int*   coarseCnt = (int*)  (ws + alloc((size_t)M * 4));
    int*   coarseOff = (int*)  (ws + alloc(((size_t)M + 1) * 4));
    int2*  edge      = (int2*) (ws + alloc((size_t)E_ * 8));
    float* bufA      = (float*)(ws + alloc((size_t)N_ * 64 * 4));   // h (fp32) / sorted
    float* bufB      = (float*)(ws + alloc((size_t)N_ * 64 * 4));   // fp16 ping-pong
    int2*   sorted = (int2*)bufA;                                   // dead before hop2 writes h
    __half* hLo    = (__half*)bufB;                                 // y / z
    __half* hHi    = (__half*)((char*)bufB + (size_t)N_ * 64 * 2);  // Ay / Az
    (void)ws_size; (void)n_in; (void)out_size;

    const int bn = (N_ + 255) / 256;
    const int bh = (N_ + 3) / 4;
    const int nbs = (M + SCAN_CHUNK - 1) / SCAN_CHUNK;
    const int bl_ = (N_ + 63) / 64;

    // CSR build (atomic-free LDS counting sort) + dinv
    p1_count_kernel<<<PB, 256, 0, stream>>>(ei, coarseCnt, E_, PB, NB);
    scan_partial_kernel<<<nbs, SCAN_TPB, 0, stream>>>(coarseCnt, bsums, M);
    scan_bsums_kernel<<<1, 1024, 0, stream>>>(bsums, nbs, coarseOff, M);
    scan_final_kernel<<<nbs, SCAN_TPB, 0, stream>>>(coarseCnt, bsums, coarseOff, M);
    p1_scatter_kernel<<<PB, 256, 0, stream>>>(ei, w, coarseOff, sorted, E_, PB, NB);
    p2_fine_kernel<<<NB, 256, 0, stream>>>(sorted, coarseOff, edge, row_ptr, dinv, N_, E_, PB, NB);
    scale_csr_kernel<<<bn, 256, 0, stream>>>(edge, row_ptr, dinv, N_);

    // Layer 1: y = X W1^T (fp16 rows); h = relu(A^2 y + b1) (fp32)
    linear_tiled_kernel<64><<<bl_, 256, 0, stream>>>(x, hLo, W1, N_);
    hop_h_kernel<16, 0><<<bh, 256, 0, stream>>>(hLo, hHi, dinv, row_ptr, edge, nullptr, N_);
    hop_h_kernel<16, 1><<<bh, 256, 0, stream>>>(hHi, bufA, dinv, row_ptr, edge, b1, N_);
    // Layer 2: z = h W2^T (fp16 rows); out = A^2 z + b2 (fp32)
    linear_tiled_kernel<40><<<bl_, 256, 0, stream>>>(bufA, hLo, W2, N_);
    hop_h_kernel<10, 0><<<bh, 256, 0, stream>>>(hLo, hHi, dinv, row_ptr, edge, nullptr, N_);
    hop_h_kernel<10, 2><<<bh, 256, 0, stream>>>(hHi, out, dinv, row_ptr, edge, b2, N_);
}

// Round 13
// 249.423 us; speedup vs baseline: 2.7301x; 1.0330x over previous
//
#include <hip/hip_runtime.h>
#include <hip/hip_fp16.h>

// SGConv (K=2, two layers) on MI355X.
// R6: atomic-free CSR build (2-phase LDS counting sort).
// R7: hop-after-weight associativity rewrite (layer-2 on 40f).
// R8/R9: fp16 rows at 64-half pitch -> one 128B line per gather.
// R10: v_fma_mix_f32 (no cvt). R11: 16-lane row groups, 8-edge step,
//     2-level reduce -- per-node overhead halved, hops off the top-5.
// R12: P1_EDGES 8192->2048. p1_scatter was at 4.5% occupancy (147 blocks on
//     256 CUs) -- pure latency. 586 blocks gives ~2.3/CU; scan matrix grows
//     to 458K entries (streaming, negligible).

#define SCAN_TPB 256
#define SCAN_ITEMS 8
#define SCAN_CHUNK (SCAN_TPB * SCAN_ITEMS)   // 2048 elements per block
#define P1_EDGES 2048                        // edges per phase-1 block
#define MAX_NB 784                           // coarse buckets (ceil(100000/128)=782)

// --- 3-phase hierarchical exclusive scan (generic: cnt[] -> out[], out[M]=total) ---

__global__ __launch_bounds__(SCAN_TPB) void scan_partial_kernel(const int* __restrict__ cnt,
                                                                int* __restrict__ bsums, int N_) {
    int t = threadIdx.x;
    int base = blockIdx.x * SCAN_CHUNK + t * SCAN_ITEMS;
    int s = 0;
    #pragma unroll
    for (int j = 0; j < SCAN_ITEMS; ++j) { int i = base + j; if (i < N_) s += cnt[i]; }
    __shared__ int sm[SCAN_TPB];
    sm[t] = s; __syncthreads();
    for (int o = SCAN_TPB / 2; o > 0; o >>= 1) {
        if (t < o) sm[t] += sm[t + o];
        __syncthreads();
    }
    if (t == 0) bsums[blockIdx.x] = sm[0];
}

__global__ __launch_bounds__(1024) void scan_bsums_kernel(int* bsums, int nb,
                                                          int* out, int N_) {
    __shared__ int sm[1024];
    int t = threadIdx.x;
    int v = (t < nb) ? bsums[t] : 0;
    sm[t] = v; __syncthreads();
    for (int o = 1; o < 1024; o <<= 1) {
        int u = (t >= o) ? sm[t - o] : 0;
        __syncthreads();
        sm[t] += u;
        __syncthreads();
    }
    if (t < nb) bsums[t] = sm[t] - v;          // exclusive block offset
    if (t == 1023) out[N_] = sm[1023];         // grand total
}

__global__ __launch_bounds__(SCAN_TPB) void scan_final_kernel(const int* __restrict__ cnt,
                                                              const int* __restrict__ bsums,
                                                              int* __restrict__ out, int N_) {
    int t = threadIdx.x;
    int base = blockIdx.x * SCAN_CHUNK + t * SCAN_ITEMS;
    int loc[SCAN_ITEMS];
    int s = 0;
    #pragma unroll
    for (int j = 0; j < SCAN_ITEMS; ++j) {
        int i = base + j;
        int c = (i < N_) ? cnt[i] : 0;
        loc[j] = s; s += c;
    }
    __shared__ int sm[SCAN_TPB];
    sm[t] = s; __syncthreads();
    for (int o = 1; o < SCAN_TPB; o <<= 1) {
        int u = (t >= o) ? sm[t - o] : 0;
        __syncthreads();
        sm[t] += u;
        __syncthreads();
    }
    int excl = bsums[blockIdx.x] + sm[t] - s;
    #pragma unroll
    for (int j = 0; j < SCAN_ITEMS; ++j) {
        int i = base + j;
        if (i < N_) out[i] = excl + loc[j];
    }
}

// --- Phase 1: coarse bucket (dst>>7) LDS histogram per 2048-edge block ---
__global__ __launch_bounds__(256) void p1_count_kernel(const int* __restrict__ ei,
                                                       int* __restrict__ coarseCnt,
                                                       int E_, int PB, int NB) {
    __shared__ int hist[MAX_NB];
    int tid = threadIdx.x;
    for (int u = tid; u < NB; u += 256) hist[u] = 0;
    __syncthreads();
    int base = blockIdx.x * P1_EDGES;
    #pragma unroll 4
    for (int j = 0; j < P1_EDGES / 256; ++j) {
        int e = base + j * 256 + tid;
        if (e < E_) atomicAdd(&hist[ei[E_ + e] >> 7], 1);
    }
    __syncthreads();
    for (int u = tid; u < NB; u += 256) coarseCnt[u * PB + blockIdx.x] = hist[u];
}

// Scatter edges into coarse-bucket-sorted order. LDS cursor = coarseOff column.
__global__ __launch_bounds__(256) void p1_scatter_kernel(const int* __restrict__ ei,
                                                         const float* __restrict__ w,
                                                         const int* __restrict__ coarseOff,
                                                         int2* __restrict__ sorted,
                                                         int E_, int PB, int NB) {
    __shared__ int lcur[MAX_NB];
    int tid = threadIdx.x;
    for (int u = tid; u < NB; u += 256) lcur[u] = coarseOff[u * PB + blockIdx.x];
    __syncthreads();
    int base = blockIdx.x * P1_EDGES;
    #pragma unroll 4
    for (int j = 0; j < P1_EDGES / 256; ++j) {
        int e = base + j * 256 + tid;
        if (e < E_) {
            int dst = ei[E_ + e];
            int b = dst >> 7;
            int pos = atomicAdd(&lcur[b], 1);
            sorted[pos] = make_int2(ei[e] | ((dst & 127) << 17), __float_as_int(w[e]));
        }
    }
}

// --- Phase 2: per coarse bucket: fine histogram + scan, CSR emit + dinv. ---
__global__ __launch_bounds__(256) void p2_fine_kernel(const int2* __restrict__ sorted,
                                                      const int* __restrict__ coarseOff,
                                                      int2* __restrict__ edge,
                                                      int* __restrict__ row_ptr,
                                                      float* __restrict__ dinv,
                                                      int N_, int E_, int PB, int NB) {
    __shared__ int fcnt[128], fexc[128], fcur[128];
    __shared__ float fdeg[128];
    const int b = blockIdx.x;
    const int tid = threadIdx.x;
    const int start = coarseOff[b * PB];
    const int end = (b + 1 < NB) ? coarseOff[(b + 1) * PB] : E_;
    if (tid < 128) { fcnt[tid] = 0; fdeg[tid] = 1.0f; }   // self-loop weight pre-added
    __syncthreads();
    for (int p = start + tid; p < end; p += 256)
        atomicAdd(&fcnt[sorted[p].x >> 17], 1);
    __syncthreads();
    if (tid < 128) fexc[tid] = fcnt[tid];
    __syncthreads();
    for (int o = 1; o < 128; o <<= 1) {
        int v = (tid < 128 && tid >= o) ? fexc[tid - o] : 0;
        __syncthreads();
        if (tid < 128) fexc[tid] += v;
        __syncthreads();
    }
    const int node0 = b << 7;
    if (tid < 128) {
        fexc[tid] -= fcnt[tid];          // inclusive -> exclusive
        fcur[tid] = 0;
        int node = node0 + tid;
        if (node < N_) row_ptr[node] = start + fexc[tid];
    }
    __syncthreads();
    for (int p = start + tid; p < end; p += 256) {
        int2 pk = sorted[p];
        int fine = pk.x >> 17;
        int src  = pk.x & 0x1FFFF;
        int r = atomicAdd(&fcur[fine], 1);
        atomicAdd(&fdeg[fine], __int_as_float(pk.y));
        edge[start + fexc[fine] + r] = make_int2(src, pk.y);
    }
    __syncthreads();
    if (tid < 128) {
        int node = node0 + tid;
        if (node < N_) {
            float s = fdeg[tid];
            dinv[node] = (s > 0.f) ? (1.0f / sqrtf(s)) : 0.f;
        }
    }
    if (b == 0 && tid == 0) row_ptr[N_] = E_;
}

// In CSR order: edge[p].y = w * dinv[src] * dinv[dst].
__global__ __launch_bounds__(256) void scale_csr_kernel(int2* __restrict__ edge,
                                                        const int* __restrict__ row_ptr,
                                                        const float* __restrict__ dinv, int N_) {
    int n = blockIdx.x * blockDim.x + threadIdx.x;
    if (n < N_) {
        float dd = dinv[n];
        int p0 = row_ptr[n], p1 = row_ptr[n + 1];
        for (int p = p0; p < p1; ++p) {
            int2 e = edge[p];
            edge[p].y = __float_as_int(__int_as_float(e.y) * dinv[e.x] * dd);
        }
    }
}

// fp32-FMA with fp16 src0, no conversion instruction (VOP3P v_fma_mix_f32).
#define FMA_MIX_LO(accv, hbits, vw) \
    asm("v_fma_mix_f32 %0, %1, %2, %0 op_sel_hi:[1,0,0]" : "+v"(accv) : "v"(hbits), "v"(vw))
#define FMA_MIX_HI(accv, hbits, vw) \
    asm("v_fma_mix_f32 %0, %1, %2, %0 op_sel:[1,0,0] op_sel_hi:[1,0,0]" : "+v"(accv) : "v"(hbits), "v"(vw))

// fp16-row hop, 16-lane row groups. Rows at 64-half pitch (128B = one line);
// lane covers 4 halves (float2). 4 groups/wave -> 4 rows in flight per gather,
// edge-step 8 (two 4-edge subgroups). 2-level xor reduce (8 swizzles).
// NL = active lanes/group (16 -> 64f, 10 -> 40f). EPI: 0 = fp16 out (pitch
// 64h), 1 = +bias+relu fp32 out (pitch 64f), 2 = +bias fp32 out (pitch 40f).
template<int NL, int EPI>
__global__ __launch_bounds__(256) void hop_h_kernel(const __half* __restrict__ xin,
                                                    void* __restrict__ xout,
                                                    const float* __restrict__ dinv,
                                                    const int* __restrict__ row_ptr,
                                                    const int2* __restrict__ edge,
                                                    const float* __restrict__ bias, int N_) {
    int wave = (blockIdx.x * blockDim.x + threadIdx.x) >> 6;
    int lane = threadIdx.x & 63;
    if (wave >= N_) return;
    const int d   = wave;
    const int g4  = lane >> 4;                          // row group 0..3
    const int hl  = lane & 15;
    const int hle = (NL == 16) ? hl : min(hl, NL - 1);  // clamped lanes stay in-line

    int e0 = row_ptr[d], e1 = row_ptr[d + 1];
    int nE = e1 - e0;
    float di = dinv[d];
    float2 selfv = ((const float2*)(xin + (size_t)d * 64))[hle];
    float acc[4] = {0.f, 0.f, 0.f, 0.f};

    for (int eb = 0; eb < nE; eb += 64) {
        bool ok = (eb + lane) < nE;
        int2 ev = ok ? edge[e0 + eb + lane] : make_int2(d, 0);   // pad: self row, w=0
        int m = min(64, nE - eb);
        for (int g = 0; g < m; g += 8) {
            int   s0 = __shfl(ev.x, g + g4);
            int   s1 = __shfl(ev.x, g + 4 + g4);
            float v0 = __shfl(__int_as_float(ev.y), g + g4);
            float v1 = __shfl(__int_as_float(ev.y), g + 4 + g4);
            float2 x0 = ((const float2*)(xin + (size_t)s0 * 64))[hle];
            float2 x1 = ((const float2*)(xin + (size_t)s1 * 64))[hle];
            FMA_MIX_LO(acc[0], x0.x, v0); FMA_MIX_HI(acc[1], x0.x, v0);
            FMA_MIX_LO(acc[2], x0.y, v0); FMA_MIX_HI(acc[3], x0.y, v0);
            FMA_MIX_LO(acc[0], x1.x, v1); FMA_MIX_HI(acc[1], x1.x, v1);
            FMA_MIX_LO(acc[2], x1.y, v1); FMA_MIX_HI(acc[3], x1.y, v1);
        }
    }
    // combine the 4 row-group partials (lanes differing in bits 4..5)
    #pragma unroll
    for (int u = 0; u < 4; ++u) {
        acc[u] += __shfl_xor(acc[u], 16);
        acc[u] += __shfl_xor(acc[u], 32);
    }
    float dii = di * di;
    FMA_MIX_LO(acc[0], selfv.x, dii); FMA_MIX_HI(acc[1], selfv.x, dii);
    FMA_MIX_LO(acc[2], selfv.y, dii); FMA_MIX_HI(acc[3], selfv.y, dii);

    if (lane < NL) {   // group 0, lane == hl; features 4*lane .. 4*lane+3
        if constexpr (EPI == 0) {
            float2 pk;
            ((__half2*)&pk)[0] = __floats2half2_rn(acc[0], acc[1]);
            ((__half2*)&pk)[1] = __floats2half2_rn(acc[2], acc[3]);
            ((float2*)((__half*)xout + (size_t)d * 64))[lane] = pk;
        } else if constexpr (EPI == 1) {
            float4 bv = ((const float4*)bias)[lane];
            float4 r;
            r.x = fmaxf(acc[0] + bv.x, 0.f); r.y = fmaxf(acc[1] + bv.y, 0.f);
            r.z = fmaxf(acc[2] + bv.z, 0.f); r.w = fmaxf(acc[3] + bv.w, 0.f);
            ((float4*)((float*)xout + (size_t)d * 64))[lane] = r;
        } else {
            float4 bv = ((const float4*)bias)[lane];
            float4 r = make_float4(acc[0] + bv.x, acc[1] + bv.y,
                                   acc[2] + bv.z, acc[3] + bv.w);
            *(float4*)((float*)xout + (size_t)d * 40 + lane * 4) = r;
        }
    }
}

// LDS-tiled GEMM (no bias/activation): out[n][f] = sum_k h[n][k]*W[f][k].
// Output fp16 rows at 64-half pitch (feeds the fp16 hop).
template<int F>
__global__ __launch_bounds__(256, 4) void linear_tiled_kernel(const float* __restrict__ hin,
                                                              __half* __restrict__ outp,
                                                              const float* __restrict__ W,
                                                              int N_) {
    constexpr int BM = 64;
    __shared__ float hs[BM * 64];
    __shared__ float ws[64 * 64];
    const int tid  = threadIdx.x;
    const int base = blockIdx.x * BM;

    for (int u = tid; u < 64 * 16; u += 256) {
        int f = u >> 4, kc = u & 15;
        float4 v = (f < F) ? ((const float4*)W)[f * 16 + kc]
                           : make_float4(0.f, 0.f, 0.f, 0.f);
        *(float4*)&ws[f * 64 + ((kc ^ ((f >> 2) & 7)) << 2)] = v;
    }
    const int lim = min(BM, N_ - base);
    for (int u = tid; u < BM * 16; u += 256) {
        int n = u >> 4, kc = u & 15;
        float4 v = (n < lim) ? ((const float4*)(hin + (size_t)(base + n) * 64))[kc]
                             : make_float4(0.f, 0.f, 0.f, 0.f);
        *(float4*)&hs[n * 64 + ((kc ^ ((n >> 2) & 7)) << 2)] = v;
    }
    __syncthreads();

    const int f0 = (tid & 15) << 2;
    const int n0 = (tid >> 4) << 2;
    float4 acc[4];
    #pragma unroll
    for (int i = 0; i < 4; ++i) acc[i] = make_float4(0.f, 0.f, 0.f, 0.f);

    #pragma unroll 2
    for (int kc = 0; kc < 16; ++kc) {
        float4 hv[4], wv[4];
        #pragma unroll
        for (int i = 0; i < 4; ++i) {
            int n = n0 + i;
            hv[i] = *(const float4*)&hs[n * 64 + ((kc ^ ((n >> 2) & 7)) << 2)];
        }
        #pragma unroll
        for (int j = 0; j < 4; ++j) {
            int f = f0 + j;
            wv[j] = *(const float4*)&ws[f * 64 + ((kc ^ ((f >> 2) & 7)) << 2)];
        }
        #pragma unroll
        for (int i = 0; i < 4; ++i) {
            acc[i].x = fmaf(hv[i].x, wv[0].x, acc[i].x);
            acc[i].x = fmaf(hv[i].y, wv[0].y, acc[i].x);
            acc[i].x = fmaf(hv[i].z, wv[0].z, acc[i].x);
            acc[i].x = fmaf(hv[i].w, wv[0].w, acc[i].x);
            acc[i].y = fmaf(hv[i].x, wv[1].x, acc[i].y);
            acc[i].y = fmaf(hv[i].y, wv[1].y, acc[i].y);
            acc[i].y = fmaf(hv[i].z, wv[1].z, acc[i].y);
            acc[i].y = fmaf(hv[i].w, wv[1].w, acc[i].y);
            acc[i].z = fmaf(hv[i].x, wv[2].x, acc[i].z);
            acc[i].z = fmaf(hv[i].y, wv[2].y, acc[i].z);
            acc[i].z = fmaf(hv[i].z, wv[2].z, acc[i].z);
            acc[i].z = fmaf(hv[i].w, wv[2].w, acc[i].z);
            acc[i].w = fmaf(hv[i].x, wv[3].x, acc[i].w);
            acc[i].w = fmaf(hv[i].y, wv[3].y, acc[i].w);
            acc[i].w = fmaf(hv[i].z, wv[3].z, acc[i].w);
            acc[i].w = fmaf(hv[i].w, wv[3].w, acc[i].w);
        }
    }

    if (f0 < F) {
        #pragma unroll
        for (int i = 0; i < 4; ++i) {
            int n = base + n0 + i;
            if (n < N_) {
                __half* o = outp + (size_t)n * 64 + f0;
                ((__half2*)o)[0] = __floats2half2_rn(acc[i].x, acc[i].y);
                ((__half2*)o)[1] = __floats2half2_rn(acc[i].z, acc[i].w);
            }
        }
    }
}

extern "C" void kernel_launch(void* const* d_in, const int* in_sizes, int n_in,
                              void* d_out, int out_size, void* d_ws, size_t ws_size,
                              hipStream_t stream) {
    const float* x   = (const float*)d_in[0];
    const int*   ei  = (const int*)d_in[1];
    const float* w   = (const float*)d_in[2];
    const float* W1  = (const float*)d_in[3];
    const float* b1  = (const float*)d_in[4];
    const float* W2  = (const float*)d_in[5];
    const float* b2  = (const float*)d_in[6];
    float* out = (float*)d_out;

    const int N_ = in_sizes[0] / 64;        // 100000
    const int E_ = in_sizes[2];             // 1200000
    const int PB = (E_ + P1_EDGES - 1) / P1_EDGES;   // 586 phase-1 blocks
    const int NB = (N_ + 127) >> 7;                  // 782 coarse buckets
    const int M  = NB * PB;                          // ~458K coarse counters

    char* ws = (char*)d_ws;
    size_t off = 0;
    auto alloc = [&](size_t bytes) { size_t o = off; off += (bytes + 255) & ~(size_t)255; return o; };
    float* dinv      = (float*)(ws + alloc((size_t)N_ * 4));
    int*   row_ptr   = (int*)  (ws + alloc(((size_t)N_ + 1) * 4));
    int*   bsums     = (int*)  (ws + alloc(1024 * 4));
    int*   coarseCnt = (int*)  (ws + alloc((size_t)M * 4));
    int*   coarseOff = (int*)  (ws + alloc(((size_t)M + 1) * 4));
    int2*  edge      = (int2*) (ws + alloc((size_t)E_ * 8));
    float* bufA      = (float*)(ws + alloc((size_t)N_ * 64 * 4));   // h (fp32) / sorted
    float* bufB      = (float*)(ws + alloc((size_t)N_ * 64 * 4));   // fp16 ping-pong
    int2*   sorted = (int2*)bufA;                                   // dead before hop2 writes h
    __half* hLo    = (__half*)bufB;                                 // y / z
    __half* hHi    = (__half*)((char*)bufB + (size_t)N_ * 64 * 2);  // Ay / Az
    (void)ws_size; (void)n_in; (void)out_size;

    const int bn = (N_ + 255) / 256;
    const int bh = (N_ + 3) / 4;
    const int nbs = (M + SCAN_CHUNK - 1) / SCAN_CHUNK;   // 224 scan blocks (<=1024)
    const int bl_ = (N_ + 63) / 64;

    // CSR build (atomic-free LDS counting sort) + dinv
    p1_count_kernel<<<PB, 256, 0, stream>>>(ei, coarseCnt, E_, PB, NB);
    scan_partial_kernel<<<nbs, SCAN_TPB, 0, stream>>>(coarseCnt, bsums, M);
    scan_bsums_kernel<<<1, 1024, 0, stream>>>(bsums, nbs, coarseOff, M);
    scan_final_kernel<<<nbs, SCAN_TPB, 0, stream>>>(coarseCnt, bsums, coarseOff, M);
    p1_scatter_kernel<<<PB, 256, 0, stream>>>(ei, w, coarseOff, sorted, E_, PB, NB);
    p2_fine_kernel<<<NB, 256, 0, stream>>>(sorted, coarseOff, edge, row_ptr, dinv, N_, E_, PB, NB);
    scale_csr_kernel<<<bn, 256, 0, stream>>>(edge, row_ptr, dinv, N_);

    // Layer 1: y = X W1^T (fp16 rows); h = relu(A^2 y + b1) (fp32)
    linear_tiled_kernel<64><<<bl_, 256, 0, stream>>>(x, hLo, W1, N_);
    hop_h_kernel<16, 0><<<bh, 256, 0, stream>>>(hLo, hHi, dinv, row_ptr, edge, nullptr, N_);
    hop_h_kernel<16, 1><<<bh, 256, 0, stream>>>(hHi, bufA, dinv, row_ptr, edge, b1, N_);
    // Layer 2: z = h W2^T (fp16 rows); out = A^2 z + b2 (fp32)
    linear_tiled_kernel<40><<<bl_, 256, 0, stream>>>(bufA, hLo, W2, N_);
    hop_h_kernel<10, 0><<<bh, 256, 0, stream>>>(hLo, hHi, dinv, row_ptr, edge, nullptr, N_);
    hop_h_kernel<10, 2><<<bh, 256, 0, stream>>>(hHi, out, dinv, row_ptr, edge, b2, N_);
}

// Round 14
// 247.080 us; speedup vs baseline: 2.7559x; 1.0095x over previous
//
#include <hip/hip_runtime.h>
#include <hip/hip_fp16.h>

// SGConv (K=2, two layers) on MI355X.
// R6: atomic-free CSR build (2-phase LDS counting sort).
// R7: hop-after-weight associativity rewrite (layer-2 on 40f).
// R8/R9: fp16 rows at 64-half pitch -> one 128B line per gather.
// R10: v_fma_mix_f32. R11: 16-lane row groups, 2-level reduce.
// R12: P1_EDGES 2048 (p1 occupancy 4.5%->~18%).
// R13: fp16 h end-to-end (hop2 emits fp16, lin2 stages fp16 input; kills a
//      25.6MB fp32 roundtrip); p1 kernels read edges 2-wide (int2/float2).

#define SCAN_TPB 256
#define SCAN_ITEMS 8
#define SCAN_CHUNK (SCAN_TPB * SCAN_ITEMS)   // 2048 elements per block
#define P1_EDGES 2048                        // edges per phase-1 block
#define MAX_NB 784                           // coarse buckets (ceil(100000/128)=782)

// --- 3-phase hierarchical exclusive scan (generic: cnt[] -> out[], out[M]=total) ---

__global__ __launch_bounds__(SCAN_TPB) void scan_partial_kernel(const int* __restrict__ cnt,
                                                                int* __restrict__ bsums, int N_) {
    int t = threadIdx.x;
    int base = blockIdx.x * SCAN_CHUNK + t * SCAN_ITEMS;
    int s = 0;
    #pragma unroll
    for (int j = 0; j < SCAN_ITEMS; ++j) { int i = base + j; if (i < N_) s += cnt[i]; }
    __shared__ int sm[SCAN_TPB];
    sm[t] = s; __syncthreads();
    for (int o = SCAN_TPB / 2; o > 0; o >>= 1) {
        if (t < o) sm[t] += sm[t + o];
        __syncthreads();
    }
    if (t == 0) bsums[blockIdx.x] = sm[0];
}

__global__ __launch_bounds__(1024) void scan_bsums_kernel(int* bsums, int nb,
                                                          int* out, int N_) {
    __shared__ int sm[1024];
    int t = threadIdx.x;
    int v = (t < nb) ? bsums[t] : 0;
    sm[t] = v; __syncthreads();
    for (int o = 1; o < 1024; o <<= 1) {
        int u = (t >= o) ? sm[t - o] : 0;
        __syncthreads();
        sm[t] += u;
        __syncthreads();
    }
    if (t < nb) bsums[t] = sm[t] - v;          // exclusive block offset
    if (t == 1023) out[N_] = sm[1023];         // grand total
}

__global__ __launch_bounds__(SCAN_TPB) void scan_final_kernel(const int* __restrict__ cnt,
                                                              const int* __restrict__ bsums,
                                                              int* __restrict__ out, int N_) {
    int t = threadIdx.x;
    int base = blockIdx.x * SCAN_CHUNK + t * SCAN_ITEMS;
    int loc[SCAN_ITEMS];
    int s = 0;
    #pragma unroll
    for (int j = 0; j < SCAN_ITEMS; ++j) {
        int i = base + j;
        int c = (i < N_) ? cnt[i] : 0;
        loc[j] = s; s += c;
    }
    __shared__ int sm[SCAN_TPB];
    sm[t] = s; __syncthreads();
    for (int o = 1; o < SCAN_TPB; o <<= 1) {
        int u = (t >= o) ? sm[t - o] : 0;
        __syncthreads();
        sm[t] += u;
        __syncthreads();
    }
    int excl = bsums[blockIdx.x] + sm[t] - s;
    #pragma unroll
    for (int j = 0; j < SCAN_ITEMS; ++j) {
        int i = base + j;
        if (i < N_) out[i] = excl + loc[j];
    }
}

// --- Phase 1: coarse bucket (dst>>7) LDS histogram, 2 edges/thread (int2) ---
__global__ __launch_bounds__(256) void p1_count_kernel(const int* __restrict__ ei,
                                                       int* __restrict__ coarseCnt,
                                                       int E_, int PB, int NB) {
    __shared__ int hist[MAX_NB];
    int tid = threadIdx.x;
    for (int u = tid; u < NB; u += 256) hist[u] = 0;
    __syncthreads();
    int base = blockIdx.x * P1_EDGES;
    #pragma unroll
    for (int j = 0; j < P1_EDGES / 512; ++j) {
        int e = base + j * 512 + tid * 2;
        if (e + 1 < E_) {
            int2 d2 = *(const int2*)&ei[E_ + e];
            atomicAdd(&hist[d2.x >> 7], 1);
            atomicAdd(&hist[d2.y >> 7], 1);
        } else if (e < E_) {
            atomicAdd(&hist[ei[E_ + e] >> 7], 1);
        }
    }
    __syncthreads();
    for (int u = tid; u < NB; u += 256) coarseCnt[u * PB + blockIdx.x] = hist[u];
}

// Scatter edges into coarse-bucket-sorted order, 2 edges/thread.
__global__ __launch_bounds__(256) void p1_scatter_kernel(const int* __restrict__ ei,
                                                         const float* __restrict__ w,
                                                         const int* __restrict__ coarseOff,
                                                         int2* __restrict__ sorted,
                                                         int E_, int PB, int NB) {
    __shared__ int lcur[MAX_NB];
    int tid = threadIdx.x;
    for (int u = tid; u < NB; u += 256) lcur[u] = coarseOff[u * PB + blockIdx.x];
    __syncthreads();
    int base = blockIdx.x * P1_EDGES;
    #pragma unroll
    for (int j = 0; j < P1_EDGES / 512; ++j) {
        int e = base + j * 512 + tid * 2;
        if (e + 1 < E_) {
            int2   s2 = *(const int2*)&ei[e];
            int2   d2 = *(const int2*)&ei[E_ + e];
            float2 w2 = *(const float2*)&w[e];
            int p0 = atomicAdd(&lcur[d2.x >> 7], 1);
            sorted[p0] = make_int2(s2.x | ((d2.x & 127) << 17), __float_as_int(w2.x));
            int p1 = atomicAdd(&lcur[d2.y >> 7], 1);
            sorted[p1] = make_int2(s2.y | ((d2.y & 127) << 17), __float_as_int(w2.y));
        } else if (e < E_) {
            int dst = ei[E_ + e];
            int pos = atomicAdd(&lcur[dst >> 7], 1);
            sorted[pos] = make_int2(ei[e] | ((dst & 127) << 17), __float_as_int(w[e]));
        }
    }
}

// --- Phase 2: per coarse bucket: fine histogram + scan, CSR emit + dinv. ---
__global__ __launch_bounds__(256) void p2_fine_kernel(const int2* __restrict__ sorted,
                                                      const int* __restrict__ coarseOff,
                                                      int2* __restrict__ edge,
                                                      int* __restrict__ row_ptr,
                                                      float* __restrict__ dinv,
                                                      int N_, int E_, int PB, int NB) {
    __shared__ int fcnt[128], fexc[128], fcur[128];
    __shared__ float fdeg[128];
    const int b = blockIdx.x;
    const int tid = threadIdx.x;
    const int start = coarseOff[b * PB];
    const int end = (b + 1 < NB) ? coarseOff[(b + 1) * PB] : E_;
    if (tid < 128) { fcnt[tid] = 0; fdeg[tid] = 1.0f; }   // self-loop weight pre-added
    __syncthreads();
    for (int p = start + tid; p < end; p += 256)
        atomicAdd(&fcnt[sorted[p].x >> 17], 1);
    __syncthreads();
    if (tid < 128) fexc[tid] = fcnt[tid];
    __syncthreads();
    for (int o = 1; o < 128; o <<= 1) {
        int v = (tid < 128 && tid >= o) ? fexc[tid - o] : 0;
        __syncthreads();
        if (tid < 128) fexc[tid] += v;
        __syncthreads();
    }
    const int node0 = b << 7;
    if (tid < 128) {
        fexc[tid] -= fcnt[tid];          // inclusive -> exclusive
        fcur[tid] = 0;
        int node = node0 + tid;
        if (node < N_) row_ptr[node] = start + fexc[tid];
    }
    __syncthreads();
    for (int p = start + tid; p < end; p += 256) {
        int2 pk = sorted[p];
        int fine = pk.x >> 17;
        int src  = pk.x & 0x1FFFF;
        int r = atomicAdd(&fcur[fine], 1);
        atomicAdd(&fdeg[fine], __int_as_float(pk.y));
        edge[start + fexc[fine] + r] = make_int2(src, pk.y);
    }
    __syncthreads();
    if (tid < 128) {
        int node = node0 + tid;
        if (node < N_) {
            float s = fdeg[tid];
            dinv[node] = (s > 0.f) ? (1.0f / sqrtf(s)) : 0.f;
        }
    }
    if (b == 0 && tid == 0) row_ptr[N_] = E_;
}

// In CSR order: edge[p].y = w * dinv[src] * dinv[dst].
__global__ __launch_bounds__(256) void scale_csr_kernel(int2* __restrict__ edge,
                                                        const int* __restrict__ row_ptr,
                                                        const float* __restrict__ dinv, int N_) {
    int n = blockIdx.x * blockDim.x + threadIdx.x;
    if (n < N_) {
        float dd = dinv[n];
        int p0 = row_ptr[n], p1 = row_ptr[n + 1];
        for (int p = p0; p < p1; ++p) {
            int2 e = edge[p];
            edge[p].y = __float_as_int(__int_as_float(e.y) * dinv[e.x] * dd);
        }
    }
}

// fp32-FMA with fp16 src0, no conversion instruction (VOP3P v_fma_mix_f32).
#define FMA_MIX_LO(accv, hbits, vw) \
    asm("v_fma_mix_f32 %0, %1, %2, %0 op_sel_hi:[1,0,0]" : "+v"(accv) : "v"(hbits), "v"(vw))
#define FMA_MIX_HI(accv, hbits, vw) \
    asm("v_fma_mix_f32 %0, %1, %2, %0 op_sel:[1,0,0] op_sel_hi:[1,0,0]" : "+v"(accv) : "v"(hbits), "v"(vw))

// fp16-row hop, 16-lane row groups. Rows at 64-half pitch (128B = one line);
// lane covers 4 halves (float2). 4 groups/wave -> 4 rows in flight per gather,
// edge-step 8. NL = active lanes/group (16 -> 64f, 10 -> 40f).
// EPI: 0 = fp16 out, 1 = +bias+relu fp16 out, 2 = +bias fp32 out (pitch 40f).
template<int NL, int EPI>
__global__ __launch_bounds__(256) void hop_h_kernel(const __half* __restrict__ xin,
                                                    void* __restrict__ xout,
                                                    const float* __restrict__ dinv,
                                                    const int* __restrict__ row_ptr,
                                                    const int2* __restrict__ edge,
                                                    const float* __restrict__ bias, int N_) {
    int wave = (blockIdx.x * blockDim.x + threadIdx.x) >> 6;
    int lane = threadIdx.x & 63;
    if (wave >= N_) return;
    const int d   = wave;
    const int g4  = lane >> 4;                          // row group 0..3
    const int hl  = lane & 15;
    const int hle = (NL == 16) ? hl : min(hl, NL - 1);  // clamped lanes stay in-line

    int e0 = row_ptr[d], e1 = row_ptr[d + 1];
    int nE = e1 - e0;
    float di = dinv[d];
    float2 selfv = ((const float2*)(xin + (size_t)d * 64))[hle];
    float acc[4] = {0.f, 0.f, 0.f, 0.f};

    for (int eb = 0; eb < nE; eb += 64) {
        bool ok = (eb + lane) < nE;
        int2 ev = ok ? edge[e0 + eb + lane] : make_int2(d, 0);   // pad: self row, w=0
        int m = min(64, nE - eb);
        for (int g = 0; g < m; g += 8) {
            int   s0 = __shfl(ev.x, g + g4);
            int   s1 = __shfl(ev.x, g + 4 + g4);
            float v0 = __shfl(__int_as_float(ev.y), g + g4);
            float v1 = __shfl(__int_as_float(ev.y), g + 4 + g4);
            float2 x0 = ((const float2*)(xin + (size_t)s0 * 64))[hle];
            float2 x1 = ((const float2*)(xin + (size_t)s1 * 64))[hle];
            FMA_MIX_LO(acc[0], x0.x, v0); FMA_MIX_HI(acc[1], x0.x, v0);
            FMA_MIX_LO(acc[2], x0.y, v0); FMA_MIX_HI(acc[3], x0.y, v0);
            FMA_MIX_LO(acc[0], x1.x, v1); FMA_MIX_HI(acc[1], x1.x, v1);
            FMA_MIX_LO(acc[2], x1.y, v1); FMA_MIX_HI(acc[3], x1.y, v1);
        }
    }
    // combine the 4 row-group partials (lanes differing in bits 4..5)
    #pragma unroll
    for (int u = 0; u < 4; ++u) {
        acc[u] += __shfl_xor(acc[u], 16);
        acc[u] += __shfl_xor(acc[u], 32);
    }
    float dii = di * di;
    FMA_MIX_LO(acc[0], selfv.x, dii); FMA_MIX_HI(acc[1], selfv.x, dii);
    FMA_MIX_LO(acc[2], selfv.y, dii); FMA_MIX_HI(acc[3], selfv.y, dii);

    if (lane < NL) {   // group 0, lane == hl; features 4*lane .. 4*lane+3
        if constexpr (EPI == 0) {
            float2 pk;
            ((__half2*)&pk)[0] = __floats2half2_rn(acc[0], acc[1]);
            ((__half2*)&pk)[1] = __floats2half2_rn(acc[2], acc[3]);
            ((float2*)((__half*)xout + (size_t)d * 64))[lane] = pk;
        } else if constexpr (EPI == 1) {
            float4 bv = ((const float4*)bias)[lane];
            float2 pk;
            ((__half2*)&pk)[0] = __floats2half2_rn(fmaxf(acc[0] + bv.x, 0.f),
                                                   fmaxf(acc[1] + bv.y, 0.f));
            ((__half2*)&pk)[1] = __floats2half2_rn(fmaxf(acc[2] + bv.z, 0.f),
                                                   fmaxf(acc[3] + bv.w, 0.f));
            ((float2*)((__half*)xout + (size_t)d * 64))[lane] = pk;
        } else {
            float4 bv = ((const float4*)bias)[lane];
            float4 r = make_float4(acc[0] + bv.x, acc[1] + bv.y,
                                   acc[2] + bv.z, acc[3] + bv.w);
            *(float4*)((float*)xout + (size_t)d * 40 + lane * 4) = r;
        }
    }
}

// LDS-tiled GEMM (no bias/activation): out[n][f] = sum_k in[n][k]*W[f][k].
// INH: input rows are fp16 at 64-half pitch; else fp32 at 64-float pitch.
// Output fp16 rows at 64-half pitch (feeds the fp16 hop).
template<int F, bool INH>
__global__ __launch_bounds__(256, 4) void linear_tiled_kernel(const void* __restrict__ hin,
                                                              __half* __restrict__ outp,
                                                              const float* __restrict__ W,
                                                              int N_) {
    constexpr int BM = 64;
    __shared__ float hs[BM * 64];
    __shared__ float ws[64 * 64];
    const int tid  = threadIdx.x;
    const int base = blockIdx.x * BM;

    for (int u = tid; u < 64 * 16; u += 256) {
        int f = u >> 4, kc = u & 15;
        float4 v = (f < F) ? ((const float4*)W)[f * 16 + kc]
                           : make_float4(0.f, 0.f, 0.f, 0.f);
        *(float4*)&ws[f * 64 + ((kc ^ ((f >> 2) & 7)) << 2)] = v;
    }
    const int lim = min(BM, N_ - base);
    for (int u = tid; u < BM * 16; u += 256) {
        int n = u >> 4, kc = u & 15;
        float4 v;
        if (n < lim) {
            if constexpr (INH) {
                float2 hv = ((const float2*)((const __half*)hin + (size_t)(base + n) * 64))[kc];
                const __half2* hh = (const __half2*)&hv;
                float2 a = __half22float2(hh[0]);
                float2 b = __half22float2(hh[1]);
                v = make_float4(a.x, a.y, b.x, b.y);
            } else {
                v = ((const float4*)((const float*)hin + (size_t)(base + n) * 64))[kc];
            }
        } else v = make_float4(0.f, 0.f, 0.f, 0.f);
        *(float4*)&hs[n * 64 + ((kc ^ ((n >> 2) & 7)) << 2)] = v;
    }
    __syncthreads();

    const int f0 = (tid & 15) << 2;
    const int n0 = (tid >> 4) << 2;
    float4 acc[4];
    #pragma unroll
    for (int i = 0; i < 4; ++i) acc[i] = make_float4(0.f, 0.f, 0.f, 0.f);

    #pragma unroll 2
    for (int kc = 0; kc < 16; ++kc) {
        float4 hv[4], wv[4];
        #pragma unroll
        for (int i = 0; i < 4; ++i) {
            int n = n0 + i;
            hv[i] = *(const float4*)&hs[n * 64 + ((kc ^ ((n >> 2) & 7)) << 2)];
        }
        #pragma unroll
        for (int j = 0; j < 4; ++j) {
            int f = f0 + j;
            wv[j] = *(const float4*)&ws[f * 64 + ((kc ^ ((f >> 2) & 7)) << 2)];
        }
        #pragma unroll
        for (int i = 0; i < 4; ++i) {
            acc[i].x = fmaf(hv[i].x, wv[0].x, acc[i].x);
            acc[i].x = fmaf(hv[i].y, wv[0].y, acc[i].x);
            acc[i].x = fmaf(hv[i].z, wv[0].z, acc[i].x);
            acc[i].x = fmaf(hv[i].w, wv[0].w, acc[i].x);
            acc[i].y = fmaf(hv[i].x, wv[1].x, acc[i].y);
            acc[i].y = fmaf(hv[i].y, wv[1].y, acc[i].y);
            acc[i].y = fmaf(hv[i].z, wv[1].z, acc[i].y);
            acc[i].y = fmaf(hv[i].w, wv[1].w, acc[i].y);
            acc[i].z = fmaf(hv[i].x, wv[2].x, acc[i].z);
            acc[i].z = fmaf(hv[i].y, wv[2].y, acc[i].z);
            acc[i].z = fmaf(hv[i].z, wv[2].z, acc[i].z);
            acc[i].z = fmaf(hv[i].w, wv[2].w, acc[i].z);
            acc[i].w = fmaf(hv[i].x, wv[3].x, acc[i].w);
            acc[i].w = fmaf(hv[i].y, wv[3].y, acc[i].w);
            acc[i].w = fmaf(hv[i].z, wv[3].z, acc[i].w);
            acc[i].w = fmaf(hv[i].w, wv[3].w, acc[i].w);
        }
    }

    if (f0 < F) {
        #pragma unroll
        for (int i = 0; i < 4; ++i) {
            int n = base + n0 + i;
            if (n < N_) {
                __half* o = outp + (size_t)n * 64 + f0;
                ((__half2*)o)[0] = __floats2half2_rn(acc[i].x, acc[i].y);
                ((__half2*)o)[1] = __floats2half2_rn(acc[i].z, acc[i].w);
            }
        }
    }
}

extern "C" void kernel_launch(void* const* d_in, const int* in_sizes, int n_in,
                              void* d_out, int out_size, void* d_ws, size_t ws_size,
                              hipStream_t stream) {
    const float* x   = (const float*)d_in[0];
    const int*   ei  = (const int*)d_in[1];
    const float* w   = (const float*)d_in[2];
    const float* W1  = (const float*)d_in[3];
    const float* b1  = (const float*)d_in[4];
    const float* W2  = (const float*)d_in[5];
    const float* b2  = (const float*)d_in[6];
    float* out = (float*)d_out;

    const int N_ = in_sizes[0] / 64;        // 100000
    const int E_ = in_sizes[2];             // 1200000
    const int PB = (E_ + P1_EDGES - 1) / P1_EDGES;   // 586 phase-1 blocks
    const int NB = (N_ + 127) >> 7;                  // 782 coarse buckets
    const int M  = NB * PB;                          // ~458K coarse counters

    char* ws = (char*)d_ws;
    size_t off = 0;
    auto alloc = [&](size_t bytes) { size_t o = off; off += (bytes + 255) & ~(size_t)255; return o; };
    float* dinv      = (float*)(ws + alloc((size_t)N_ * 4));
    int*   row_ptr   = (int*)  (ws + alloc(((size_t)N_ + 1) * 4));
    int*   bsums     = (int*)  (ws + alloc(1024 * 4));
    int*   coarseCnt = (int*)  (ws + alloc((size_t)M * 4));
    int*   coarseOff = (int*)  (ws + alloc(((size_t)M + 1) * 4));
    int2*  edge      = (int2*) (ws + alloc((size_t)E_ * 8));
    float* bufA      = (float*)(ws + alloc((size_t)N_ * 64 * 4));   // sorted / h(fp16)
    float* bufB      = (float*)(ws + alloc((size_t)N_ * 64 * 4));   // fp16 ping-pong
    int2*   sorted = (int2*)bufA;                                   // dead after p2_fine
    __half* hA0    = (__half*)bufA;                                 // h (fp16), after sorted dead
    __half* hLo    = (__half*)bufB;                                 // y / z
    __half* hHi    = (__half*)((char*)bufB + (size_t)N_ * 64 * 2);  // Ay / Az
    (void)ws_size; (void)n_in; (void)out_size;

    const int bn = (N_ + 255) / 256;
    const int bh = (N_ + 3) / 4;
    const int nbs = (M + SCAN_CHUNK - 1) / SCAN_CHUNK;   // 224 scan blocks (<=1024)
    const int bl_ = (N_ + 63) / 64;

    // CSR build (atomic-free LDS counting sort) + dinv
    p1_count_kernel<<<PB, 256, 0, stream>>>(ei, coarseCnt, E_, PB, NB);
    scan_partial_kernel<<<nbs, SCAN_TPB, 0, stream>>>(coarseCnt, bsums, M);
    scan_bsums_kernel<<<1, 1024, 0, stream>>>(bsums, nbs, coarseOff, M);
    scan_final_kernel<<<nbs, SCAN_TPB, 0, stream>>>(coarseCnt, bsums, coarseOff, M);
    p1_scatter_kernel<<<PB, 256, 0, stream>>>(ei, w, coarseOff, sorted, E_, PB, NB);
    p2_fine_kernel<<<NB, 256, 0, stream>>>(sorted, coarseOff, edge, row_ptr, dinv, N_, E_, PB, NB);
    scale_csr_kernel<<<bn, 256, 0, stream>>>(edge, row_ptr, dinv, N_);

    // Layer 1: y = X W1^T (fp16 rows); h = relu(A^2 y + b1) (fp16)
    linear_tiled_kernel<64, false><<<bl_, 256, 0, stream>>>(x, hLo, W1, N_);
    hop_h_kernel<16, 0><<<bh, 256, 0, stream>>>(hLo, hHi, dinv, row_ptr, edge, nullptr, N_);
    hop_h_kernel<16, 1><<<bh, 256, 0, stream>>>(hHi, hA0, dinv, row_ptr, edge, b1, N_);
    // Layer 2: z = h W2^T (fp16 rows); out = A^2 z + b2 (fp32)
    linear_tiled_kernel<40, true><<<bl_, 256, 0, stream>>>(hA0, hLo, W2, N_);
    hop_h_kernel<10, 0><<<bh, 256, 0, stream>>>(hLo, hHi, dinv, row_ptr, edge, nullptr, N_);
    hop_h_kernel<10, 2><<<bh, 256, 0, stream>>>(hHi, out, dinv, row_ptr, edge, b2, N_);
}

// Round 15
// 221.870 us; speedup vs baseline: 3.0691x; 1.1136x over previous
//
#include <hip/hip_runtime.h>
#include <hip/hip_fp16.h>

// SGConv (K=2, two layers) on MI355X.
// R6: atomic-free CSR build (2-phase LDS counting sort).
// R7: hop-after-weight associativity rewrite (layer-2 on 40f).
// R8/R9: fp16 rows at 64-half pitch -> one 128B line per gather.
// R10: v_fma_mix_f32. R11: 16-lane row groups. R12: P1_EDGES 2048.
// R13: fp16 h end-to-end, 2-wide p1 reads.
// R14: hop re-tiled to ONE 16-lane group PER NODE (4 nodes/wave): group's 16
//      lanes cover the whole 64-half row -> cross-group reduce (8 swz + 8 add)
//      eliminated, prologue amortized 4x, 8 gathers in flight per wave.

#define SCAN_TPB 256
#define SCAN_ITEMS 8
#define SCAN_CHUNK (SCAN_TPB * SCAN_ITEMS)   // 2048 elements per block
#define P1_EDGES 2048                        // edges per phase-1 block
#define MAX_NB 784                           // coarse buckets (ceil(100000/128)=782)

// --- 3-phase hierarchical exclusive scan (generic: cnt[] -> out[], out[M]=total) ---

__global__ __launch_bounds__(SCAN_TPB) void scan_partial_kernel(const int* __restrict__ cnt,
                                                                int* __restrict__ bsums, int N_) {
    int t = threadIdx.x;
    int base = blockIdx.x * SCAN_CHUNK + t * SCAN_ITEMS;
    int s = 0;
    #pragma unroll
    for (int j = 0; j < SCAN_ITEMS; ++j) { int i = base + j; if (i < N_) s += cnt[i]; }
    __shared__ int sm[SCAN_TPB];
    sm[t] = s; __syncthreads();
    for (int o = SCAN_TPB / 2; o > 0; o >>= 1) {
        if (t < o) sm[t] += sm[t + o];
        __syncthreads();
    }
    if (t == 0) bsums[blockIdx.x] = sm[0];
}

__global__ __launch_bounds__(1024) void scan_bsums_kernel(int* bsums, int nb,
                                                          int* out, int N_) {
    __shared__ int sm[1024];
    int t = threadIdx.x;
    int v = (t < nb) ? bsums[t] : 0;
    sm[t] = v; __syncthreads();
    for (int o = 1; o < 1024; o <<= 1) {
        int u = (t >= o) ? sm[t - o] : 0;
        __syncthreads();
        sm[t] += u;
        __syncthreads();
    }
    if (t < nb) bsums[t] = sm[t] - v;          // exclusive block offset
    if (t == 1023) out[N_] = sm[1023];         // grand total
}

__global__ __launch_bounds__(SCAN_TPB) void scan_final_kernel(const int* __restrict__ cnt,
                                                              const int* __restrict__ bsums,
                                                              int* __restrict__ out, int N_) {
    int t = threadIdx.x;
    int base = blockIdx.x * SCAN_CHUNK + t * SCAN_ITEMS;
    int loc[SCAN_ITEMS];
    int s = 0;
    #pragma unroll
    for (int j = 0; j < SCAN_ITEMS; ++j) {
        int i = base + j;
        int c = (i < N_) ? cnt[i] : 0;
        loc[j] = s; s += c;
    }
    __shared__ int sm[SCAN_TPB];
    sm[t] = s; __syncthreads();
    for (int o = 1; o < SCAN_TPB; o <<= 1) {
        int u = (t >= o) ? sm[t - o] : 0;
        __syncthreads();
        sm[t] += u;
        __syncthreads();
    }
    int excl = bsums[blockIdx.x] + sm[t] - s;
    #pragma unroll
    for (int j = 0; j < SCAN_ITEMS; ++j) {
        int i = base + j;
        if (i < N_) out[i] = excl + loc[j];
    }
}

// --- Phase 1: coarse bucket (dst>>7) LDS histogram, 2 edges/thread (int2) ---
__global__ __launch_bounds__(256) void p1_count_kernel(const int* __restrict__ ei,
                                                       int* __restrict__ coarseCnt,
                                                       int E_, int PB, int NB) {
    __shared__ int hist[MAX_NB];
    int tid = threadIdx.x;
    for (int u = tid; u < NB; u += 256) hist[u] = 0;
    __syncthreads();
    int base = blockIdx.x * P1_EDGES;
    #pragma unroll
    for (int j = 0; j < P1_EDGES / 512; ++j) {
        int e = base + j * 512 + tid * 2;
        if (e + 1 < E_) {
            int2 d2 = *(const int2*)&ei[E_ + e];
            atomicAdd(&hist[d2.x >> 7], 1);
            atomicAdd(&hist[d2.y >> 7], 1);
        } else if (e < E_) {
            atomicAdd(&hist[ei[E_ + e] >> 7], 1);
        }
    }
    __syncthreads();
    for (int u = tid; u < NB; u += 256) coarseCnt[u * PB + blockIdx.x] = hist[u];
}

// Scatter edges into coarse-bucket-sorted order, 2 edges/thread.
__global__ __launch_bounds__(256) void p1_scatter_kernel(const int* __restrict__ ei,
                                                         const float* __restrict__ w,
                                                         const int* __restrict__ coarseOff,
                                                         int2* __restrict__ sorted,
                                                         int E_, int PB, int NB) {
    __shared__ int lcur[MAX_NB];
    int tid = threadIdx.x;
    for (int u = tid; u < NB; u += 256) lcur[u] = coarseOff[u * PB + blockIdx.x];
    __syncthreads();
    int base = blockIdx.x * P1_EDGES;
    #pragma unroll
    for (int j = 0; j < P1_EDGES / 512; ++j) {
        int e = base + j * 512 + tid * 2;
        if (e + 1 < E_) {
            int2   s2 = *(const int2*)&ei[e];
            int2   d2 = *(const int2*)&ei[E_ + e];
            float2 w2 = *(const float2*)&w[e];
            int p0 = atomicAdd(&lcur[d2.x >> 7], 1);
            sorted[p0] = make_int2(s2.x | ((d2.x & 127) << 17), __float_as_int(w2.x));
            int p1 = atomicAdd(&lcur[d2.y >> 7], 1);
            sorted[p1] = make_int2(s2.y | ((d2.y & 127) << 17), __float_as_int(w2.y));
        } else if (e < E_) {
            int dst = ei[E_ + e];
            int pos = atomicAdd(&lcur[dst >> 7], 1);
            sorted[pos] = make_int2(ei[e] | ((dst & 127) << 17), __float_as_int(w[e]));
        }
    }
}

// --- Phase 2: per coarse bucket: fine histogram + scan, CSR emit + dinv. ---
__global__ __launch_bounds__(256) void p2_fine_kernel(const int2* __restrict__ sorted,
                                                      const int* __restrict__ coarseOff,
                                                      int2* __restrict__ edge,
                                                      int* __restrict__ row_ptr,
                                                      float* __restrict__ dinv,
                                                      int N_, int E_, int PB, int NB) {
    __shared__ int fcnt[128], fexc[128], fcur[128];
    __shared__ float fdeg[128];
    const int b = blockIdx.x;
    const int tid = threadIdx.x;
    const int start = coarseOff[b * PB];
    const int end = (b + 1 < NB) ? coarseOff[(b + 1) * PB] : E_;
    if (tid < 128) { fcnt[tid] = 0; fdeg[tid] = 1.0f; }   // self-loop weight pre-added
    __syncthreads();
    for (int p = start + tid; p < end; p += 256)
        atomicAdd(&fcnt[sorted[p].x >> 17], 1);
    __syncthreads();
    if (tid < 128) fexc[tid] = fcnt[tid];
    __syncthreads();
    for (int o = 1; o < 128; o <<= 1) {
        int v = (tid < 128 && tid >= o) ? fexc[tid - o] : 0;
        __syncthreads();
        if (tid < 128) fexc[tid] += v;
        __syncthreads();
    }
    const int node0 = b << 7;
    if (tid < 128) {
        fexc[tid] -= fcnt[tid];          // inclusive -> exclusive
        fcur[tid] = 0;
        int node = node0 + tid;
        if (node < N_) row_ptr[node] = start + fexc[tid];
    }
    __syncthreads();
    for (int p = start + tid; p < end; p += 256) {
        int2 pk = sorted[p];
        int fine = pk.x >> 17;
        int src  = pk.x & 0x1FFFF;
        int r = atomicAdd(&fcur[fine], 1);
        atomicAdd(&fdeg[fine], __int_as_float(pk.y));
        edge[start + fexc[fine] + r] = make_int2(src, pk.y);
    }
    __syncthreads();
    if (tid < 128) {
        int node = node0 + tid;
        if (node < N_) {
            float s = fdeg[tid];
            dinv[node] = (s > 0.f) ? (1.0f / sqrtf(s)) : 0.f;
        }
    }
    if (b == 0 && tid == 0) row_ptr[N_] = E_;
}

// In CSR order: edge[p].y = w * dinv[src] * dinv[dst].
__global__ __launch_bounds__(256) void scale_csr_kernel(int2* __restrict__ edge,
                                                        const int* __restrict__ row_ptr,
                                                        const float* __restrict__ dinv, int N_) {
    int n = blockIdx.x * blockDim.x + threadIdx.x;
    if (n < N_) {
        float dd = dinv[n];
        int p0 = row_ptr[n], p1 = row_ptr[n + 1];
        for (int p = p0; p < p1; ++p) {
            int2 e = edge[p];
            edge[p].y = __float_as_int(__int_as_float(e.y) * dinv[e.x] * dd);
        }
    }
}

// fp32-FMA with fp16 src0, no conversion instruction (VOP3P v_fma_mix_f32).
#define FMA_MIX_LO(accv, hbits, vw) \
    asm("v_fma_mix_f32 %0, %1, %2, %0 op_sel_hi:[1,0,0]" : "+v"(accv) : "v"(hbits), "v"(vw))
#define FMA_MIX_HI(accv, hbits, vw) \
    asm("v_fma_mix_f32 %0, %1, %2, %0 op_sel:[1,0,0] op_sel_hi:[1,0,0]" : "+v"(accv) : "v"(hbits), "v"(vw))

// fp16-row hop, ONE 16-lane group per node (4 nodes/wave). Group's 16 lanes
// cover the whole 64-half row (float2 = 4 halves per lane) -> NO cross-group
// reduction. Edges chunked 16/group; wave-max chunk loop, w=0 pads for
// finished groups. j unrolled x2 -> 2 gathers in flight/group (8/wave).
// NL = active store lanes (16 -> 64f, 10 -> 40f). EPI: 0 = fp16 out,
// 1 = +bias+relu fp16 out, 2 = +bias fp32 out (pitch 40f).
template<int NL, int EPI>
__global__ __launch_bounds__(256) void hop_h_kernel(const __half* __restrict__ xin,
                                                    void* __restrict__ xout,
                                                    const float* __restrict__ dinv,
                                                    const int* __restrict__ row_ptr,
                                                    const int2* __restrict__ edge,
                                                    const float* __restrict__ bias, int N_) {
    int wave = (blockIdx.x * blockDim.x + threadIdx.x) >> 6;
    int lane = threadIdx.x & 63;
    const int g   = lane >> 4;            // group 0..3 -> node wave*4+g
    const int hl  = lane & 15;
    const int hle = (NL == 16) ? hl : min(hl, NL - 1);   // clamped lanes stay in-line

    int nd = wave * 4 + g;
    bool real = nd < N_;
    int d = real ? nd : (N_ - 1);         // safe address for inactive groups

    int e0 = row_ptr[d];
    int nE = real ? (row_ptr[d + 1] - e0) : 0;
    float di = dinv[d];
    float2 selfv = ((const float2*)(xin + (size_t)d * 64))[hle];
    float acc[4] = {0.f, 0.f, 0.f, 0.f};

    // wave-max edge count across the 4 groups
    int maxNE = nE;
    maxNE = max(maxNE, __shfl_xor(maxNE, 16));
    maxNE = max(maxNE, __shfl_xor(maxNE, 32));

    for (int eb = 0; eb < maxNE; eb += 16) {
        int rem = nE - eb;
        int2 ev = (hl < rem) ? edge[e0 + eb + hl] : make_int2(d, 0);  // pad: self, w=0
        int mm = min(16, maxNE - eb);
        for (int j = 0; j < mm; j += 2) {
            int   s0 = __shfl(ev.x, (g << 4) | j);
            int   s1 = __shfl(ev.x, (g << 4) | (j + 1));   // slot <=15; pads are w=0
            float v0 = __shfl(__int_as_float(ev.y), (g << 4) | j);
            float v1 = __shfl(__int_as_float(ev.y), (g << 4) | (j + 1));
            float2 x0 = ((const float2*)(xin + (size_t)s0 * 64))[hle];
            float2 x1 = ((const float2*)(xin + (size_t)s1 * 64))[hle];
            FMA_MIX_LO(acc[0], x0.x, v0); FMA_MIX_HI(acc[1], x0.x, v0);
            FMA_MIX_LO(acc[2], x0.y, v0); FMA_MIX_HI(acc[3], x0.y, v0);
            FMA_MIX_LO(acc[0], x1.x, v1); FMA_MIX_HI(acc[1], x1.x, v1);
            FMA_MIX_LO(acc[2], x1.y, v1); FMA_MIX_HI(acc[3], x1.y, v1);
        }
    }
    float dii = di * di;
    FMA_MIX_LO(acc[0], selfv.x, dii); FMA_MIX_HI(acc[1], selfv.x, dii);
    FMA_MIX_LO(acc[2], selfv.y, dii); FMA_MIX_HI(acc[3], selfv.y, dii);

    if (real && hl < NL) {   // features 4*hl .. 4*hl+3
        if constexpr (EPI == 0) {
            float2 pk;
            ((__half2*)&pk)[0] = __floats2half2_rn(acc[0], acc[1]);
            ((__half2*)&pk)[1] = __floats2half2_rn(acc[2], acc[3]);
            ((float2*)((__half*)xout + (size_t)d * 64))[hl] = pk;
        } else if constexpr (EPI == 1) {
            float4 bv = ((const float4*)bias)[hl];
            float2 pk;
            ((__half2*)&pk)[0] = __floats2half2_rn(fmaxf(acc[0] + bv.x, 0.f),
                                                   fmaxf(acc[1] + bv.y, 0.f));
            ((__half2*)&pk)[1] = __floats2half2_rn(fmaxf(acc[2] + bv.z, 0.f),
                                                   fmaxf(acc[3] + bv.w, 0.f));
            ((float2*)((__half*)xout + (size_t)d * 64))[hl] = pk;
        } else {
            float4 bv = ((const float4*)bias)[hl];
            float4 r = make_float4(acc[0] + bv.x, acc[1] + bv.y,
                                   acc[2] + bv.z, acc[3] + bv.w);
            *(float4*)((float*)xout + (size_t)d * 40 + hl * 4) = r;
        }
    }
}

// LDS-tiled GEMM (no bias/activation): out[n][f] = sum_k in[n][k]*W[f][k].
// INH: input rows are fp16 at 64-half pitch; else fp32 at 64-float pitch.
// Output fp16 rows at 64-half pitch (feeds the fp16 hop).
template<int F, bool INH>
__global__ __launch_bounds__(256, 4) void linear_tiled_kernel(const void* __restrict__ hin,
                                                              __half* __restrict__ outp,
                                                              const float* __restrict__ W,
                                                              int N_) {
    constexpr int BM = 64;
    __shared__ float hs[BM * 64];
    __shared__ float ws[64 * 64];
    const int tid  = threadIdx.x;
    const int base = blockIdx.x * BM;

    for (int u = tid; u < 64 * 16; u += 256) {
        int f = u >> 4, kc = u & 15;
        float4 v = (f < F) ? ((const float4*)W)[f * 16 + kc]
                           : make_float4(0.f, 0.f, 0.f, 0.f);
        *(float4*)&ws[f * 64 + ((kc ^ ((f >> 2) & 7)) << 2)] = v;
    }
    const int lim = min(BM, N_ - base);
    for (int u = tid; u < BM * 16; u += 256) {
        int n = u >> 4, kc = u & 15;
        float4 v;
        if (n < lim) {
            if constexpr (INH) {
                float2 hv = ((const float2*)((const __half*)hin + (size_t)(base + n) * 64))[kc];
                const __half2* hh = (const __half2*)&hv;
                float2 a = __half22float2(hh[0]);
                float2 b = __half22float2(hh[1]);
                v = make_float4(a.x, a.y, b.x, b.y);
            } else {
                v = ((const float4*)((const float*)hin + (size_t)(base + n) * 64))[kc];
            }
        } else v = make_float4(0.f, 0.f, 0.f, 0.f);
        *(float4*)&hs[n * 64 + ((kc ^ ((n >> 2) & 7)) << 2)] = v;
    }
    __syncthreads();

    const int f0 = (tid & 15) << 2;
    const int n0 = (tid >> 4) << 2;
    float4 acc[4];
    #pragma unroll
    for (int i = 0; i < 4; ++i) acc[i] = make_float4(0.f, 0.f, 0.f, 0.f);

    #pragma unroll 2
    for (int kc = 0; kc < 16; ++kc) {
        float4 hv[4], wv[4];
        #pragma unroll
        for (int i = 0; i < 4; ++i) {
            int n = n0 + i;
            hv[i] = *(const float4*)&hs[n * 64 + ((kc ^ ((n >> 2) & 7)) << 2)];
        }
        #pragma unroll
        for (int j = 0; j < 4; ++j) {
            int f = f0 + j;
            wv[j] = *(const float4*)&ws[f * 64 + ((kc ^ ((f >> 2) & 7)) << 2)];
        }
        #pragma unroll
        for (int i = 0; i < 4; ++i) {
            acc[i].x = fmaf(hv[i].x, wv[0].x, acc[i].x);
            acc[i].x = fmaf(hv[i].y, wv[0].y, acc[i].x);
            acc[i].x = fmaf(hv[i].z, wv[0].z, acc[i].x);
            acc[i].x = fmaf(hv[i].w, wv[0].w, acc[i].x);
            acc[i].y = fmaf(hv[i].x, wv[1].x, acc[i].y);
            acc[i].y = fmaf(hv[i].y, wv[1].y, acc[i].y);
            acc[i].y = fmaf(hv[i].z, wv[1].z, acc[i].y);
            acc[i].y = fmaf(hv[i].w, wv[1].w, acc[i].y);
            acc[i].z = fmaf(hv[i].x, wv[2].x, acc[i].z);
            acc[i].z = fmaf(hv[i].y, wv[2].y, acc[i].z);
            acc[i].z = fmaf(hv[i].z, wv[2].z, acc[i].z);
            acc[i].z = fmaf(hv[i].w, wv[2].w, acc[i].z);
            acc[i].w = fmaf(hv[i].x, wv[3].x, acc[i].w);
            acc[i].w = fmaf(hv[i].y, wv[3].y, acc[i].w);
            acc[i].w = fmaf(hv[i].z, wv[3].z, acc[i].w);
            acc[i].w = fmaf(hv[i].w, wv[3].w, acc[i].w);
        }
    }

    if (f0 < F) {
        #pragma unroll
        for (int i = 0; i < 4; ++i) {
            int n = base + n0 + i;
            if (n < N_) {
                __half* o = outp + (size_t)n * 64 + f0;
                ((__half2*)o)[0] = __floats2half2_rn(acc[i].x, acc[i].y);
                ((__half2*)o)[1] = __floats2half2_rn(acc[i].z, acc[i].w);
            }
        }
    }
}

extern "C" void kernel_launch(void* const* d_in, const int* in_sizes, int n_in,
                              void* d_out, int out_size, void* d_ws, size_t ws_size,
                              hipStream_t stream) {
    const float* x   = (const float*)d_in[0];
    const int*   ei  = (const int*)d_in[1];
    const float* w   = (const float*)d_in[2];
    const float* W1  = (const float*)d_in[3];
    const float* b1  = (const float*)d_in[4];
    const float* W2  = (const float*)d_in[5];
    const float* b2  = (const float*)d_in[6];
    float* out = (float*)d_out;

    const int N_ = in_sizes[0] / 64;        // 100000
    const int E_ = in_sizes[2];             // 1200000
    const int PB = (E_ + P1_EDGES - 1) / P1_EDGES;   // 586 phase-1 blocks
    const int NB = (N_ + 127) >> 7;                  // 782 coarse buckets
    const int M  = NB * PB;                          // ~458K coarse counters

    char* ws = (char*)d_ws;
    size_t off = 0;
    auto alloc = [&](size_t bytes) { size_t o = off; off += (bytes + 255) & ~(size_t)255; return o; };
    float* dinv      = (float*)(ws + alloc((size_t)N_ * 4));
    int*   row_ptr   = (int*)  (ws + alloc(((size_t)N_ + 1) * 4));
    int*   bsums     = (int*)  (ws + alloc(1024 * 4));
    int*   coarseCnt = (int*)  (ws + alloc((size_t)M * 4));
    int*   coarseOff = (int*)  (ws + alloc(((size_t)M + 1) * 4));
    int2*  edge      = (int2*) (ws + alloc((size_t)E_ * 8));
    float* bufA      = (float*)(ws + alloc((size_t)N_ * 64 * 4));   // sorted / h(fp16)
    float* bufB      = (float*)(ws + alloc((size_t)N_ * 64 * 4));   // fp16 ping-pong
    int2*   sorted = (int2*)bufA;                                   // dead after p2_fine
    __half* hA0    = (__half*)bufA;                                 // h (fp16), after sorted dead
    __half* hLo    = (__half*)bufB;                                 // y / z
    __half* hHi    = (__half*)((char*)bufB + (size_t)N_ * 64 * 2);  // Ay / Az
    (void)ws_size; (void)n_in; (void)out_size;

    const int bn = (N_ + 255) / 256;
    const int bh4 = (N_ + 15) / 16;                      // hop: 16 nodes per 256-thr block
    const int nbs = (M + SCAN_CHUNK - 1) / SCAN_CHUNK;   // 224 scan blocks (<=1024)
    const int bl_ = (N_ + 63) / 64;

    // CSR build (atomic-free LDS counting sort) + dinv
    p1_count_kernel<<<PB, 256, 0, stream>>>(ei, coarseCnt, E_, PB, NB);
    scan_partial_kernel<<<nbs, SCAN_TPB, 0, stream>>>(coarseCnt, bsums, M);
    scan_bsums_kernel<<<1, 1024, 0, stream>>>(bsums, nbs, coarseOff, M);
    scan_final_kernel<<<nbs, SCAN_TPB, 0, stream>>>(coarseCnt, bsums, coarseOff, M);
    p1_scatter_kernel<<<PB, 256, 0, stream>>>(ei, w, coarseOff, sorted, E_, PB, NB);
    p2_fine_kernel<<<NB, 256, 0, stream>>>(sorted, coarseOff, edge, row_ptr, dinv, N_, E_, PB, NB);
    scale_csr_kernel<<<bn, 256, 0, stream>>>(edge, row_ptr, dinv, N_);

    // Layer 1: y = X W1^T (fp16 rows); h = relu(A^2 y + b1) (fp16)
    linear_tiled_kernel<64, false><<<bl_, 256, 0, stream>>>(x, hLo, W1, N_);
    hop_h_kernel<16, 0><<<bh4, 256, 0, stream>>>(hLo, hHi, dinv, row_ptr, edge, nullptr, N_);
    hop_h_kernel<16, 1><<<bh4, 256, 0, stream>>>(hHi, hA0, dinv, row_ptr, edge, b1, N_);
    // Layer 2: z = h W2^T (fp16 rows); out = A^2 z + b2 (fp32)
    linear_tiled_kernel<40, true><<<bl_, 256, 0, stream>>>(hA0, hLo, W2, N_);
    hop_h_kernel<10, 0><<<bh4, 256, 0, stream>>>(hLo, hHi, dinv, row_ptr, edge, nullptr, N_);
    hop_h_kernel<10, 2><<<bh4, 256, 0, stream>>>(hHi, out, dinv, row_ptr, edge, b2, N_);
}

// Round 16
// 207.855 us; speedup vs baseline: 3.2760x; 1.0674x over previous
//
#include <hip/hip_runtime.h>
#include <hip/hip_fp16.h>

// SGConv (K=2, two layers) on MI355X.
// R6: atomic-free CSR build (2-phase LDS counting sort).
// R7: hop-after-weight associativity rewrite (layer-2 on 40f).
// R8/R9: fp16 rows at 64-half pitch -> one 128B line per gather.
// R10: v_fma_mix_f32. R11/R14: one 16-lane group per node (4 nodes/wave),
//      no cross-group reduce. R12: P1_EDGES 2048. R13: fp16 end-to-end.
// R15: normalization folded into epilogues. Buffers hold dinv-scaled rows
//      (y_hat = dinv.*y); hops use RAW weights (edge.y = w, self weight 1)
//      and scale output by dinv^2 (feeding another hop) or dinv (actual).
//      Linears pre-scale their fp16 rows by dinv[n]. scale_csr pass DELETED.

#define SCAN_TPB 256
#define SCAN_ITEMS 8
#define SCAN_CHUNK (SCAN_TPB * SCAN_ITEMS)   // 2048 elements per block
#define P1_EDGES 2048                        // edges per phase-1 block
#define MAX_NB 784                           // coarse buckets (ceil(100000/128)=782)

// --- 3-phase hierarchical exclusive scan (generic: cnt[] -> out[], out[M]=total) ---

__global__ __launch_bounds__(SCAN_TPB) void scan_partial_kernel(const int* __restrict__ cnt,
                                                                int* __restrict__ bsums, int N_) {
    int t = threadIdx.x;
    int base = blockIdx.x * SCAN_CHUNK + t * SCAN_ITEMS;
    int s = 0;
    #pragma unroll
    for (int j = 0; j < SCAN_ITEMS; ++j) { int i = base + j; if (i < N_) s += cnt[i]; }
    __shared__ int sm[SCAN_TPB];
    sm[t] = s; __syncthreads();
    for (int o = SCAN_TPB / 2; o > 0; o >>= 1) {
        if (t < o) sm[t] += sm[t + o];
        __syncthreads();
    }
    if (t == 0) bsums[blockIdx.x] = sm[0];
}

__global__ __launch_bounds__(1024) void scan_bsums_kernel(int* bsums, int nb,
                                                          int* out, int N_) {
    __shared__ int sm[1024];
    int t = threadIdx.x;
    int v = (t < nb) ? bsums[t] : 0;
    sm[t] = v; __syncthreads();
    for (int o = 1; o < 1024; o <<= 1) {
        int u = (t >= o) ? sm[t - o] : 0;
        __syncthreads();
        sm[t] += u;
        __syncthreads();
    }
    if (t < nb) bsums[t] = sm[t] - v;          // exclusive block offset
    if (t == 1023) out[N_] = sm[1023];         // grand total
}

__global__ __launch_bounds__(SCAN_TPB) void scan_final_kernel(const int* __restrict__ cnt,
                                                              const int* __restrict__ bsums,
                                                              int* __restrict__ out, int N_) {
    int t = threadIdx.x;
    int base = blockIdx.x * SCAN_CHUNK + t * SCAN_ITEMS;
    int loc[SCAN_ITEMS];
    int s = 0;
    #pragma unroll
    for (int j = 0; j < SCAN_ITEMS; ++j) {
        int i = base + j;
        int c = (i < N_) ? cnt[i] : 0;
        loc[j] = s; s += c;
    }
    __shared__ int sm[SCAN_TPB];
    sm[t] = s; __syncthreads();
    for (int o = 1; o < SCAN_TPB; o <<= 1) {
        int u = (t >= o) ? sm[t - o] : 0;
        __syncthreads();
        sm[t] += u;
        __syncthreads();
    }
    int excl = bsums[blockIdx.x] + sm[t] - s;
    #pragma unroll
    for (int j = 0; j < SCAN_ITEMS; ++j) {
        int i = base + j;
        if (i < N_) out[i] = excl + loc[j];
    }
}

// --- Phase 1: coarse bucket (dst>>7) LDS histogram, 2 edges/thread (int2) ---
__global__ __launch_bounds__(256) void p1_count_kernel(const int* __restrict__ ei,
                                                       int* __restrict__ coarseCnt,
                                                       int E_, int PB, int NB) {
    __shared__ int hist[MAX_NB];
    int tid = threadIdx.x;
    for (int u = tid; u < NB; u += 256) hist[u] = 0;
    __syncthreads();
    int base = blockIdx.x * P1_EDGES;
    #pragma unroll
    for (int j = 0; j < P1_EDGES / 512; ++j) {
        int e = base + j * 512 + tid * 2;
        if (e + 1 < E_) {
            int2 d2 = *(const int2*)&ei[E_ + e];
            atomicAdd(&hist[d2.x >> 7], 1);
            atomicAdd(&hist[d2.y >> 7], 1);
        } else if (e < E_) {
            atomicAdd(&hist[ei[E_ + e] >> 7], 1);
        }
    }
    __syncthreads();
    for (int u = tid; u < NB; u += 256) coarseCnt[u * PB + blockIdx.x] = hist[u];
}

// Scatter edges into coarse-bucket-sorted order, 2 edges/thread.
__global__ __launch_bounds__(256) void p1_scatter_kernel(const int* __restrict__ ei,
                                                         const float* __restrict__ w,
                                                         const int* __restrict__ coarseOff,
                                                         int2* __restrict__ sorted,
                                                         int E_, int PB, int NB) {
    __shared__ int lcur[MAX_NB];
    int tid = threadIdx.x;
    for (int u = tid; u < NB; u += 256) lcur[u] = coarseOff[u * PB + blockIdx.x];
    __syncthreads();
    int base = blockIdx.x * P1_EDGES;
    #pragma unroll
    for (int j = 0; j < P1_EDGES / 512; ++j) {
        int e = base + j * 512 + tid * 2;
        if (e + 1 < E_) {
            int2   s2 = *(const int2*)&ei[e];
            int2   d2 = *(const int2*)&ei[E_ + e];
            float2 w2 = *(const float2*)&w[e];
            int p0 = atomicAdd(&lcur[d2.x >> 7], 1);
            sorted[p0] = make_int2(s2.x | ((d2.x & 127) << 17), __float_as_int(w2.x));
            int p1 = atomicAdd(&lcur[d2.y >> 7], 1);
            sorted[p1] = make_int2(s2.y | ((d2.y & 127) << 17), __float_as_int(w2.y));
        } else if (e < E_) {
            int dst = ei[E_ + e];
            int pos = atomicAdd(&lcur[dst >> 7], 1);
            sorted[pos] = make_int2(ei[e] | ((dst & 127) << 17), __float_as_int(w[e]));
        }
    }
}

// --- Phase 2: per coarse bucket: fine histogram + scan, CSR emit + dinv.
// edge.y stays RAW weight w (normalization folded into compute epilogues). ---
__global__ __launch_bounds__(256) void p2_fine_kernel(const int2* __restrict__ sorted,
                                                      const int* __restrict__ coarseOff,
                                                      int2* __restrict__ edge,
                                                      int* __restrict__ row_ptr,
                                                      float* __restrict__ dinv,
                                                      int N_, int E_, int PB, int NB) {
    __shared__ int fcnt[128], fexc[128], fcur[128];
    __shared__ float fdeg[128];
    const int b = blockIdx.x;
    const int tid = threadIdx.x;
    const int start = coarseOff[b * PB];
    const int end = (b + 1 < NB) ? coarseOff[(b + 1) * PB] : E_;
    if (tid < 128) { fcnt[tid] = 0; fdeg[tid] = 1.0f; }   // self-loop weight pre-added
    __syncthreads();
    for (int p = start + tid; p < end; p += 256)
        atomicAdd(&fcnt[sorted[p].x >> 17], 1);
    __syncthreads();
    if (tid < 128) fexc[tid] = fcnt[tid];
    __syncthreads();
    for (int o = 1; o < 128; o <<= 1) {
        int v = (tid < 128 && tid >= o) ? fexc[tid - o] : 0;
        __syncthreads();
        if (tid < 128) fexc[tid] += v;
        __syncthreads();
    }
    const int node0 = b << 7;
    if (tid < 128) {
        fexc[tid] -= fcnt[tid];          // inclusive -> exclusive
        fcur[tid] = 0;
        int node = node0 + tid;
        if (node < N_) row_ptr[node] = start + fexc[tid];
    }
    __syncthreads();
    for (int p = start + tid; p < end; p += 256) {
        int2 pk = sorted[p];
        int fine = pk.x >> 17;
        int src  = pk.x & 0x1FFFF;
        int r = atomicAdd(&fcur[fine], 1);
        atomicAdd(&fdeg[fine], __int_as_float(pk.y));
        edge[start + fexc[fine] + r] = make_int2(src, pk.y);
    }
    __syncthreads();
    if (tid < 128) {
        int node = node0 + tid;
        if (node < N_) {
            float s = fdeg[tid];
            dinv[node] = (s > 0.f) ? (1.0f / sqrtf(s)) : 0.f;
        }
    }
    if (b == 0 && tid == 0) row_ptr[N_] = E_;
}

// fp32-FMA with fp16 src0, no conversion instruction (VOP3P v_fma_mix_f32).
#define FMA_MIX_LO(accv, hbits, vw) \
    asm("v_fma_mix_f32 %0, %1, %2, %0 op_sel_hi:[1,0,0]" : "+v"(accv) : "v"(hbits), "v"(vw))
#define FMA_MIX_HI(accv, hbits, vw) \
    asm("v_fma_mix_f32 %0, %1, %2, %0 op_sel:[1,0,0] op_sel_hi:[1,0,0]" : "+v"(accv) : "v"(hbits), "v"(vw))

// fp16-row hop, ONE 16-lane group per node (4 nodes/wave). Input rows are
// dinv-scaled (y_hat); weights raw; self weight 1. Output scaled by dinv^2
// (EPI=0: stays in scaled domain) or dinv (EPI=1/2: actual values).
// NL = active store lanes (16 -> 64f, 10 -> 40f). EPI: 0 = fp16 out (scaled),
// 1 = +bias+relu fp16 out (actual h), 2 = +bias fp32 out (pitch 40f, final).
template<int NL, int EPI>
__global__ __launch_bounds__(256) void hop_h_kernel(const __half* __restrict__ xin,
                                                    void* __restrict__ xout,
                                                    const float* __restrict__ dinv,
                                                    const int* __restrict__ row_ptr,
                                                    const int2* __restrict__ edge,
                                                    const float* __restrict__ bias, int N_) {
    int wave = (blockIdx.x * blockDim.x + threadIdx.x) >> 6;
    int lane = threadIdx.x & 63;
    const int g   = lane >> 4;            // group 0..3 -> node wave*4+g
    const int hl  = lane & 15;
    const int hle = (NL == 16) ? hl : min(hl, NL - 1);   // clamped lanes stay in-line

    int nd = wave * 4 + g;
    bool real = nd < N_;
    int d = real ? nd : (N_ - 1);         // safe address for inactive groups

    int e0 = row_ptr[d];
    int nE = real ? (row_ptr[d + 1] - e0) : 0;
    float di = dinv[d];
    float2 selfv = ((const float2*)(xin + (size_t)d * 64))[hle];
    float acc[4] = {0.f, 0.f, 0.f, 0.f};

    // wave-max edge count across the 4 groups
    int maxNE = nE;
    maxNE = max(maxNE, __shfl_xor(maxNE, 16));
    maxNE = max(maxNE, __shfl_xor(maxNE, 32));

    for (int eb = 0; eb < maxNE; eb += 16) {
        int rem = nE - eb;
        int2 ev = (hl < rem) ? edge[e0 + eb + hl] : make_int2(d, 0);  // pad: self, w=0
        int mm = min(16, maxNE - eb);
        for (int j = 0; j < mm; j += 2) {
            int   s0 = __shfl(ev.x, (g << 4) | j);
            int   s1 = __shfl(ev.x, (g << 4) | (j + 1));   // slot <=15; pads are w=0
            float v0 = __shfl(__int_as_float(ev.y), (g << 4) | j);
            float v1 = __shfl(__int_as_float(ev.y), (g << 4) | (j + 1));
            float2 x0 = ((const float2*)(xin + (size_t)s0 * 64))[hle];
            float2 x1 = ((const float2*)(xin + (size_t)s1 * 64))[hle];
            FMA_MIX_LO(acc[0], x0.x, v0); FMA_MIX_HI(acc[1], x0.x, v0);
            FMA_MIX_LO(acc[2], x0.y, v0); FMA_MIX_HI(acc[3], x0.y, v0);
            FMA_MIX_LO(acc[0], x1.x, v1); FMA_MIX_HI(acc[1], x1.x, v1);
            FMA_MIX_LO(acc[2], x1.y, v1); FMA_MIX_HI(acc[3], x1.y, v1);
        }
    }
    // self loop: weight 1 (input already dinv-scaled)
    const float one = 1.0f;
    FMA_MIX_LO(acc[0], selfv.x, one); FMA_MIX_HI(acc[1], selfv.x, one);
    FMA_MIX_LO(acc[2], selfv.y, one); FMA_MIX_HI(acc[3], selfv.y, one);

    // output scale: dinv^2 (stay scaled) or dinv (actual)
    float sc = (EPI == 0) ? di * di : di;
    #pragma unroll
    for (int u = 0; u < 4; ++u) acc[u] *= sc;

    if (real && hl < NL) {   // features 4*hl .. 4*hl+3
        if constexpr (EPI == 0) {
            float2 pk;
            ((__half2*)&pk)[0] = __floats2half2_rn(acc[0], acc[1]);
            ((__half2*)&pk)[1] = __floats2half2_rn(acc[2], acc[3]);
            ((float2*)((__half*)xout + (size_t)d * 64))[hl] = pk;
        } else if constexpr (EPI == 1) {
            float4 bv = ((const float4*)bias)[hl];
            float2 pk;
            ((__half2*)&pk)[0] = __floats2half2_rn(fmaxf(acc[0] + bv.x, 0.f),
                                                   fmaxf(acc[1] + bv.y, 0.f));
            ((__half2*)&pk)[1] = __floats2half2_rn(fmaxf(acc[2] + bv.z, 0.f),
                                                   fmaxf(acc[3] + bv.w, 0.f));
            ((float2*)((__half*)xout + (size_t)d * 64))[hl] = pk;
        } else {
            float4 bv = ((const float4*)bias)[hl];
            float4 r = make_float4(acc[0] + bv.x, acc[1] + bv.y,
                                   acc[2] + bv.z, acc[3] + bv.w);
            *(float4*)((float*)xout + (size_t)d * 40 + hl * 4) = r;
        }
    }
}

// LDS-tiled GEMM: out[n][f] = dinv[n] * sum_k in[n][k]*W[f][k] (fp16 rows,
// dinv-scaled for the hop's scaled domain). INH: fp16 input at 64-half pitch.
template<int F, bool INH>
__global__ __launch_bounds__(256, 4) void linear_tiled_kernel(const void* __restrict__ hin,
                                                              __half* __restrict__ outp,
                                                              const float* __restrict__ W,
                                                              const float* __restrict__ dinv,
                                                              int N_) {
    constexpr int BM = 64;
    __shared__ float hs[BM * 64];
    __shared__ float ws[64 * 64];
    const int tid  = threadIdx.x;
    const int base = blockIdx.x * BM;

    for (int u = tid; u < 64 * 16; u += 256) {
        int f = u >> 4, kc = u & 15;
        float4 v = (f < F) ? ((const float4*)W)[f * 16 + kc]
                           : make_float4(0.f, 0.f, 0.f, 0.f);
        *(float4*)&ws[f * 64 + ((kc ^ ((f >> 2) & 7)) << 2)] = v;
    }
    const int lim = min(BM, N_ - base);
    for (int u = tid; u < BM * 16; u += 256) {
        int n = u >> 4, kc = u & 15;
        float4 v;
        if (n < lim) {
            if constexpr (INH) {
                float2 hv = ((const float2*)((const __half*)hin + (size_t)(base + n) * 64))[kc];
                const __half2* hh = (const __half2*)&hv;
                float2 a = __half22float2(hh[0]);
                float2 b = __half22float2(hh[1]);
                v = make_float4(a.x, a.y, b.x, b.y);
            } else {
                v = ((const float4*)((const float*)hin + (size_t)(base + n) * 64))[kc];
            }
        } else v = make_float4(0.f, 0.f, 0.f, 0.f);
        *(float4*)&hs[n * 64 + ((kc ^ ((n >> 2) & 7)) << 2)] = v;
    }
    __syncthreads();

    const int f0 = (tid & 15) << 2;
    const int n0 = (tid >> 4) << 2;
    float4 acc[4];
    #pragma unroll
    for (int i = 0; i < 4; ++i) acc[i] = make_float4(0.f, 0.f, 0.f, 0.f);

    #pragma unroll 2
    for (int kc = 0; kc < 16; ++kc) {
        float4 hv[4], wv[4];
        #pragma unroll
        for (int i = 0; i < 4; ++i) {
            int n = n0 + i;
            hv[i] = *(const float4*)&hs[n * 64 + ((kc ^ ((n >> 2) & 7)) << 2)];
        }
        #pragma unroll
        for (int j = 0; j < 4; ++j) {
            int f = f0 + j;
            wv[j] = *(const float4*)&ws[f * 64 + ((kc ^ ((f >> 2) & 7)) << 2)];
        }
        #pragma unroll
        for (int i = 0; i < 4; ++i) {
            acc[i].x = fmaf(hv[i].x, wv[0].x, acc[i].x);
            acc[i].x = fmaf(hv[i].y, wv[0].y, acc[i].x);
            acc[i].x = fmaf(hv[i].z, wv[0].z, acc[i].x);
            acc[i].x = fmaf(hv[i].w, wv[0].w, acc[i].x);
            acc[i].y = fmaf(hv[i].x, wv[1].x, acc[i].y);
            acc[i].y = fmaf(hv[i].y, wv[1].y, acc[i].y);
            acc[i].y = fmaf(hv[i].z, wv[1].z, acc[i].y);
            acc[i].y = fmaf(hv[i].w, wv[1].w, acc[i].y);
            acc[i].z = fmaf(hv[i].x, wv[2].x, acc[i].z);
            acc[i].z = fmaf(hv[i].y, wv[2].y, acc[i].z);
            acc[i].z = fmaf(hv[i].z, wv[2].z, acc[i].z);
            acc[i].z = fmaf(hv[i].w, wv[2].w, acc[i].z);
            acc[i].w = fmaf(hv[i].x, wv[3].x, acc[i].w);
            acc[i].w = fmaf(hv[i].y, wv[3].y, acc[i].w);
            acc[i].w = fmaf(hv[i].z, wv[3].z, acc[i].w);
            acc[i].w = fmaf(hv[i].w, wv[3].w, acc[i].w);
        }
    }

    if (f0 < F) {
        #pragma unroll
        for (int i = 0; i < 4; ++i) {
            int n = base + n0 + i;
            if (n < N_) {
                float dn = dinv[n];
                __half* o = outp + (size_t)n * 64 + f0;
                ((__half2*)o)[0] = __floats2half2_rn(acc[i].x * dn, acc[i].y * dn);
                ((__half2*)o)[1] = __floats2half2_rn(acc[i].z * dn, acc[i].w * dn);
            }
        }
    }
}

extern "C" void kernel_launch(void* const* d_in, const int* in_sizes, int n_in,
                              void* d_out, int out_size, void* d_ws, size_t ws_size,
                              hipStream_t stream) {
    const float* x   = (const float*)d_in[0];
    const int*   ei  = (const int*)d_in[1];
    const float* w   = (const float*)d_in[2];
    const float* W1  = (const float*)d_in[3];
    const float* b1  = (const float*)d_in[4];
    const float* W2  = (const float*)d_in[5];
    const float* b2  = (const float*)d_in[6];
    float* out = (float*)d_out;

    const int N_ = in_sizes[0] / 64;        // 100000
    const int E_ = in_sizes[2];             // 1200000
    const int PB = (E_ + P1_EDGES - 1) / P1_EDGES;   // 586 phase-1 blocks
    const int NB = (N_ + 127) >> 7;                  // 782 coarse buckets
    const int M  = NB * PB;                          // ~458K coarse counters

    char* ws = (char*)d_ws;
    size_t off = 0;
    auto alloc = [&](size_t bytes) { size_t o = off; off += (bytes + 255) & ~(size_t)255; return o; };
    float* dinv      = (float*)(ws + alloc((size_t)N_ * 4));
    int*   row_ptr   = (int*)  (ws + alloc(((size_t)N_ + 1) * 4));
    int*   bsums     = (int*)  (ws + alloc(1024 * 4));
    int*   coarseCnt = (int*)  (ws + alloc((size_t)M * 4));
    int*   coarseOff = (int*)  (ws + alloc(((size_t)M + 1) * 4));
    int2*  edge      = (int2*) (ws + alloc((size_t)E_ * 8));
    float* bufA      = (float*)(ws + alloc((size_t)N_ * 64 * 4));   // sorted / h(fp16)
    float* bufB      = (float*)(ws + alloc((size_t)N_ * 64 * 4));   // fp16 ping-pong
    int2*   sorted = (int2*)bufA;                                   // dead after p2_fine
    __half* hA0    = (__half*)bufA;                                 // h (fp16), after sorted dead
    __half* hLo    = (__half*)bufB;                                 // y / z (dinv-scaled)
    __half* hHi    = (__half*)((char*)bufB + (size_t)N_ * 64 * 2);  // Ay / Az (dinv-scaled)
    (void)ws_size; (void)n_in; (void)out_size;

    const int bh4 = (N_ + 15) / 16;                      // hop: 16 nodes per 256-thr block
    const int nbs = (M + SCAN_CHUNK - 1) / SCAN_CHUNK;   // scan blocks (<=1024)
    const int bl_ = (N_ + 63) / 64;

    // CSR build (atomic-free LDS counting sort) + dinv; edge.y = raw w
    p1_count_kernel<<<PB, 256, 0, stream>>>(ei, coarseCnt, E_, PB, NB);
    scan_partial_kernel<<<nbs, SCAN_TPB, 0, stream>>>(coarseCnt, bsums, M);
    scan_bsums_kernel<<<1, 1024, 0, stream>>>(bsums, nbs, coarseOff, M);
    scan_final_kernel<<<nbs, SCAN_TPB, 0, stream>>>(coarseCnt, bsums, coarseOff, M);
    p1_scatter_kernel<<<PB, 256, 0, stream>>>(ei, w, coarseOff, sorted, E_, PB, NB);
    p2_fine_kernel<<<NB, 256, 0, stream>>>(sorted, coarseOff, edge, row_ptr, dinv, N_, E_, PB, NB);

    // Layer 1: y_hat = dinv.*(X W1^T); hop1 (scaled); hop2 -> h actual (+b1, relu)
    linear_tiled_kernel<64, false><<<bl_, 256, 0, stream>>>(x, hLo, W1, dinv, N_);
    hop_h_kernel<16, 0><<<bh4, 256, 0, stream>>>(hLo, hHi, dinv, row_ptr, edge, nullptr, N_);
    hop_h_kernel<16, 1><<<bh4, 256, 0, stream>>>(hHi, hA0, dinv, row_ptr, edge, b1, N_);
    // Layer 2: z_hat = dinv.*(h W2^T); hop3 (scaled); hop4 -> out (+b2, fp32)
    linear_tiled_kernel<40, true><<<bl_, 256, 0, stream>>>(hA0, hLo, W2, dinv, N_);
    hop_h_kernel<10, 0><<<bh4, 256, 0, stream>>>(hLo, hHi, dinv, row_ptr, edge, nullptr, N_);
    hop_h_kernel<10, 2><<<bh4, 256, 0, stream>>>(hHi, out, dinv, row_ptr, edge, b2, N_);
}

// Round 17
// 198.222 us; speedup vs baseline: 3.4352x; 1.0486x over previous
//
#include <hip/hip_runtime.h>
#include <hip/hip_fp16.h>

// SGConv (K=2, two layers) on MI355X.
// R6: atomic-free CSR build (2-phase LDS counting sort).
// R7: hop-after-weight associativity rewrite (layer-2 on 40f).
// R8/R9: fp16 rows at 64-half pitch -> one 128B line per gather.
// R10: v_fma_mix_f32. R11/R14: one 16-lane group per node (4 nodes/wave).
// R12: P1_EDGES 2048. R13: fp16 end-to-end. R15: norm folded into epilogues
//      (dinv-scaled buffers, raw edge weights), scale_csr pass deleted.
// R16: hop j-unroll x4 + next-chunk edge prefetch (16 gathers in flight/wave);
//      coarse buckets 256 nodes (dst>>8) -> scan matrix + p2 blocks halved.

#define SCAN_TPB 256
#define SCAN_ITEMS 8
#define SCAN_CHUNK (SCAN_TPB * SCAN_ITEMS)   // 2048 elements per block
#define P1_EDGES 2048                        // edges per phase-1 block
#define MAX_NB 392                           // coarse buckets (ceil(100000/256)=391)

// --- 3-phase hierarchical exclusive scan (generic: cnt[] -> out[], out[M]=total) ---

__global__ __launch_bounds__(SCAN_TPB) void scan_partial_kernel(const int* __restrict__ cnt,
                                                                int* __restrict__ bsums, int N_) {
    int t = threadIdx.x;
    int base = blockIdx.x * SCAN_CHUNK + t * SCAN_ITEMS;
    int s = 0;
    #pragma unroll
    for (int j = 0; j < SCAN_ITEMS; ++j) { int i = base + j; if (i < N_) s += cnt[i]; }
    __shared__ int sm[SCAN_TPB];
    sm[t] = s; __syncthreads();
    for (int o = SCAN_TPB / 2; o > 0; o >>= 1) {
        if (t < o) sm[t] += sm[t + o];
        __syncthreads();
    }
    if (t == 0) bsums[blockIdx.x] = sm[0];
}

__global__ __launch_bounds__(1024) void scan_bsums_kernel(int* bsums, int nb,
                                                          int* out, int N_) {
    __shared__ int sm[1024];
    int t = threadIdx.x;
    int v = (t < nb) ? bsums[t] : 0;
    sm[t] = v; __syncthreads();
    for (int o = 1; o < 1024; o <<= 1) {
        int u = (t >= o) ? sm[t - o] : 0;
        __syncthreads();
        sm[t] += u;
        __syncthreads();
    }
    if (t < nb) bsums[t] = sm[t] - v;          // exclusive block offset
    if (t == 1023) out[N_] = sm[1023];         // grand total
}

__global__ __launch_bounds__(SCAN_TPB) void scan_final_kernel(const int* __restrict__ cnt,
                                                              const int* __restrict__ bsums,
                                                              int* __restrict__ out, int N_) {
    int t = threadIdx.x;
    int base = blockIdx.x * SCAN_CHUNK + t * SCAN_ITEMS;
    int loc[SCAN_ITEMS];
    int s = 0;
    #pragma unroll
    for (int j = 0; j < SCAN_ITEMS; ++j) {
        int i = base + j;
        int c = (i < N_) ? cnt[i] : 0;
        loc[j] = s; s += c;
    }
    __shared__ int sm[SCAN_TPB];
    sm[t] = s; __syncthreads();
    for (int o = 1; o < SCAN_TPB; o <<= 1) {
        int u = (t >= o) ? sm[t - o] : 0;
        __syncthreads();
        sm[t] += u;
        __syncthreads();
    }
    int excl = bsums[blockIdx.x] + sm[t] - s;
    #pragma unroll
    for (int j = 0; j < SCAN_ITEMS; ++j) {
        int i = base + j;
        if (i < N_) out[i] = excl + loc[j];
    }
}

// --- Phase 1: coarse bucket (dst>>8) LDS histogram, 2 edges/thread (int2) ---
__global__ __launch_bounds__(256) void p1_count_kernel(const int* __restrict__ ei,
                                                       int* __restrict__ coarseCnt,
                                                       int E_, int PB, int NB) {
    __shared__ int hist[MAX_NB];
    int tid = threadIdx.x;
    for (int u = tid; u < NB; u += 256) hist[u] = 0;
    __syncthreads();
    int base = blockIdx.x * P1_EDGES;
    #pragma unroll
    for (int j = 0; j < P1_EDGES / 512; ++j) {
        int e = base + j * 512 + tid * 2;
        if (e + 1 < E_) {
            int2 d2 = *(const int2*)&ei[E_ + e];
            atomicAdd(&hist[d2.x >> 8], 1);
            atomicAdd(&hist[d2.y >> 8], 1);
        } else if (e < E_) {
            atomicAdd(&hist[ei[E_ + e] >> 8], 1);
        }
    }
    __syncthreads();
    for (int u = tid; u < NB; u += 256) coarseCnt[u * PB + blockIdx.x] = hist[u];
}

// Scatter edges into coarse-bucket-sorted order, 2 edges/thread.
// Payload: src (17 bits) | fine (8 bits: dst & 255) << 17.
__global__ __launch_bounds__(256) void p1_scatter_kernel(const int* __restrict__ ei,
                                                         const float* __restrict__ w,
                                                         const int* __restrict__ coarseOff,
                                                         int2* __restrict__ sorted,
                                                         int E_, int PB, int NB) {
    __shared__ int lcur[MAX_NB];
    int tid = threadIdx.x;
    for (int u = tid; u < NB; u += 256) lcur[u] = coarseOff[u * PB + blockIdx.x];
    __syncthreads();
    int base = blockIdx.x * P1_EDGES;
    #pragma unroll
    for (int j = 0; j < P1_EDGES / 512; ++j) {
        int e = base + j * 512 + tid * 2;
        if (e + 1 < E_) {
            int2   s2 = *(const int2*)&ei[e];
            int2   d2 = *(const int2*)&ei[E_ + e];
            float2 w2 = *(const float2*)&w[e];
            int p0 = atomicAdd(&lcur[d2.x >> 8], 1);
            sorted[p0] = make_int2(s2.x | ((d2.x & 255) << 17), __float_as_int(w2.x));
            int p1 = atomicAdd(&lcur[d2.y >> 8], 1);
            sorted[p1] = make_int2(s2.y | ((d2.y & 255) << 17), __float_as_int(w2.y));
        } else if (e < E_) {
            int dst = ei[E_ + e];
            int pos = atomicAdd(&lcur[dst >> 8], 1);
            sorted[pos] = make_int2(ei[e] | ((dst & 255) << 17), __float_as_int(w[e]));
        }
    }
}

// --- Phase 2: per coarse bucket (256 nodes): fine histogram + scan,
// CSR emit + dinv. edge.y stays RAW weight w. ---
__global__ __launch_bounds__(256) void p2_fine_kernel(const int2* __restrict__ sorted,
                                                      const int* __restrict__ coarseOff,
                                                      int2* __restrict__ edge,
                                                      int* __restrict__ row_ptr,
                                                      float* __restrict__ dinv,
                                                      int N_, int E_, int PB, int NB) {
    __shared__ int fcnt[256], fexc[256], fcur[256];
    __shared__ float fdeg[256];
    const int b = blockIdx.x;
    const int tid = threadIdx.x;
    const int start = coarseOff[b * PB];
    const int end = (b + 1 < NB) ? coarseOff[(b + 1) * PB] : E_;
    fcnt[tid] = 0; fdeg[tid] = 1.0f;            // self-loop weight pre-added
    __syncthreads();
    for (int p = start + tid; p < end; p += 256)
        atomicAdd(&fcnt[(sorted[p].x >> 17) & 255], 1);
    __syncthreads();
    fexc[tid] = fcnt[tid];
    __syncthreads();
    for (int o = 1; o < 256; o <<= 1) {
        int v = (tid >= o) ? fexc[tid - o] : 0;
        __syncthreads();
        fexc[tid] += v;
        __syncthreads();
    }
    const int node0 = b << 8;
    fexc[tid] -= fcnt[tid];                     // inclusive -> exclusive
    fcur[tid] = 0;
    int node = node0 + tid;
    if (node < N_) row_ptr[node] = start + fexc[tid];
    __syncthreads();
    for (int p = start + tid; p < end; p += 256) {
        int2 pk = sorted[p];
        int fine = (pk.x >> 17) & 255;
        int src  = pk.x & 0x1FFFF;
        int r = atomicAdd(&fcur[fine], 1);
        atomicAdd(&fdeg[fine], __int_as_float(pk.y));
        edge[start + fexc[fine] + r] = make_int2(src, pk.y);
    }
    __syncthreads();
    if (node < N_) {
        float s = fdeg[tid];
        dinv[node] = (s > 0.f) ? (1.0f / sqrtf(s)) : 0.f;
    }
    if (b == 0 && tid == 0) row_ptr[N_] = E_;
}

// fp32-FMA with fp16 src0, no conversion instruction (VOP3P v_fma_mix_f32).
#define FMA_MIX_LO(accv, hbits, vw) \
    asm("v_fma_mix_f32 %0, %1, %2, %0 op_sel_hi:[1,0,0]" : "+v"(accv) : "v"(hbits), "v"(vw))
#define FMA_MIX_HI(accv, hbits, vw) \
    asm("v_fma_mix_f32 %0, %1, %2, %0 op_sel:[1,0,0] op_sel_hi:[1,0,0]" : "+v"(accv) : "v"(hbits), "v"(vw))

// fp16-row hop, ONE 16-lane group per node (4 nodes/wave). Input rows are
// dinv-scaled; weights raw; self weight 1. Output scaled by dinv^2 (EPI=0)
// or dinv (EPI=1/2). j unrolled x4 (4 gathers in flight/group, 16/wave) and
// next 16-edge chunk's ev prefetched before the FMA work.
// NL = active store lanes (16 -> 64f, 10 -> 40f). EPI: 0 = fp16 out (scaled),
// 1 = +bias+relu fp16 out (actual h), 2 = +bias fp32 out (pitch 40f, final).
template<int NL, int EPI>
__global__ __launch_bounds__(256) void hop_h_kernel(const __half* __restrict__ xin,
                                                    void* __restrict__ xout,
                                                    const float* __restrict__ dinv,
                                                    const int* __restrict__ row_ptr,
                                                    const int2* __restrict__ edge,
                                                    const float* __restrict__ bias, int N_) {
    int wave = (blockIdx.x * blockDim.x + threadIdx.x) >> 6;
    int lane = threadIdx.x & 63;
    const int g   = lane >> 4;            // group 0..3 -> node wave*4+g
    const int hl  = lane & 15;
    const int hle = (NL == 16) ? hl : min(hl, NL - 1);   // clamped lanes stay in-line

    int nd = wave * 4 + g;
    bool real = nd < N_;
    int d = real ? nd : (N_ - 1);         // safe address for inactive groups

    int e0 = row_ptr[d];
    int nE = real ? (row_ptr[d + 1] - e0) : 0;
    float di = dinv[d];
    float2 selfv = ((const float2*)(xin + (size_t)d * 64))[hle];
    float acc[4] = {0.f, 0.f, 0.f, 0.f};

    // wave-max edge count across the 4 groups
    int maxNE = nE;
    maxNE = max(maxNE, __shfl_xor(maxNE, 16));
    maxNE = max(maxNE, __shfl_xor(maxNE, 32));

    const int2 pad = make_int2(d, 0);     // self row, w=0 (harmless, L1-hot)
    int2 ev = (hl < nE) ? edge[e0 + hl] : pad;
    for (int eb = 0; eb < maxNE; eb += 16) {
        // prefetch next chunk's edge slice before the FMA work
        int nxt = eb + 16;
        int2 evn = (nxt < maxNE && hl < nE - nxt) ? edge[e0 + nxt + hl] : pad;
        int mm = min(16, maxNE - eb);
        for (int j = 0; j < mm; j += 4) {          // slots (g<<4)|j..j+3 <= 63
            int   s0 = __shfl(ev.x, (g << 4) | j);
            int   s1 = __shfl(ev.x, (g << 4) | (j + 1));
            int   s2 = __shfl(ev.x, (g << 4) | (j + 2));
            int   s3 = __shfl(ev.x, (g << 4) | (j + 3));
            float v0 = __shfl(__int_as_float(ev.y), (g << 4) | j);
            float v1 = __shfl(__int_as_float(ev.y), (g << 4) | (j + 1));
            float v2 = __shfl(__int_as_float(ev.y), (g << 4) | (j + 2));
            float v3 = __shfl(__int_as_float(ev.y), (g << 4) | (j + 3));
            float2 x0 = ((const float2*)(xin + (size_t)s0 * 64))[hle];
            float2 x1 = ((const float2*)(xin + (size_t)s1 * 64))[hle];
            float2 x2 = ((const float2*)(xin + (size_t)s2 * 64))[hle];
            float2 x3 = ((const float2*)(xin + (size_t)s3 * 64))[hle];
            FMA_MIX_LO(acc[0], x0.x, v0); FMA_MIX_HI(acc[1], x0.x, v0);
            FMA_MIX_LO(acc[2], x0.y, v0); FMA_MIX_HI(acc[3], x0.y, v0);
            FMA_MIX_LO(acc[0], x1.x, v1); FMA_MIX_HI(acc[1], x1.x, v1);
            FMA_MIX_LO(acc[2], x1.y, v1); FMA_MIX_HI(acc[3], x1.y, v1);
            FMA_MIX_LO(acc[0], x2.x, v2); FMA_MIX_HI(acc[1], x2.x, v2);
            FMA_MIX_LO(acc[2], x2.y, v2); FMA_MIX_HI(acc[3], x2.y, v2);
            FMA_MIX_LO(acc[0], x3.x, v3); FMA_MIX_HI(acc[1], x3.x, v3);
            FMA_MIX_LO(acc[2], x3.y, v3); FMA_MIX_HI(acc[3], x3.y, v3);
        }
        ev = evn;
    }
    // self loop: weight 1 (input already dinv-scaled)
    const float one = 1.0f;
    FMA_MIX_LO(acc[0], selfv.x, one); FMA_MIX_HI(acc[1], selfv.x, one);
    FMA_MIX_LO(acc[2], selfv.y, one); FMA_MIX_HI(acc[3], selfv.y, one);

    // output scale: dinv^2 (stay scaled) or dinv (actual)
    float sc = (EPI == 0) ? di * di : di;
    #pragma unroll
    for (int u = 0; u < 4; ++u) acc[u] *= sc;

    if (real && hl < NL) {   // features 4*hl .. 4*hl+3
        if constexpr (EPI == 0) {
            float2 pk;
            ((__half2*)&pk)[0] = __floats2half2_rn(acc[0], acc[1]);
            ((__half2*)&pk)[1] = __floats2half2_rn(acc[2], acc[3]);
            ((float2*)((__half*)xout + (size_t)d * 64))[hl] = pk;
        } else if constexpr (EPI == 1) {
            float4 bv = ((const float4*)bias)[hl];
            float2 pk;
            ((__half2*)&pk)[0] = __floats2half2_rn(fmaxf(acc[0] + bv.x, 0.f),
                                                   fmaxf(acc[1] + bv.y, 0.f));
            ((__half2*)&pk)[1] = __floats2half2_rn(fmaxf(acc[2] + bv.z, 0.f),
                                                   fmaxf(acc[3] + bv.w, 0.f));
            ((float2*)((__half*)xout + (size_t)d * 64))[hl] = pk;
        } else {
            float4 bv = ((const float4*)bias)[hl];
            float4 r = make_float4(acc[0] + bv.x, acc[1] + bv.y,
                                   acc[2] + bv.z, acc[3] + bv.w);
            *(float4*)((float*)xout + (size_t)d * 40 + hl * 4) = r;
        }
    }
}

// LDS-tiled GEMM: out[n][f] = dinv[n] * sum_k in[n][k]*W[f][k] (fp16 rows,
// dinv-scaled for the hop's scaled domain). INH: fp16 input at 64-half pitch.
template<int F, bool INH>
__global__ __launch_bounds__(256, 4) void linear_tiled_kernel(const void* __restrict__ hin,
                                                              __half* __restrict__ outp,
                                                              const float* __restrict__ W,
                                                              const float* __restrict__ dinv,
                                                              int N_) {
    constexpr int BM = 64;
    __shared__ float hs[BM * 64];
    __shared__ float ws[64 * 64];
    const int tid  = threadIdx.x;
    const int base = blockIdx.x * BM;

    for (int u = tid; u < 64 * 16; u += 256) {
        int f = u >> 4, kc = u & 15;
        float4 v = (f < F) ? ((const float4*)W)[f * 16 + kc]
                           : make_float4(0.f, 0.f, 0.f, 0.f);
        *(float4*)&ws[f * 64 + ((kc ^ ((f >> 2) & 7)) << 2)] = v;
    }
    const int lim = min(BM, N_ - base);
    for (int u = tid; u < BM * 16; u += 256) {
        int n = u >> 4, kc = u & 15;
        float4 v;
        if (n < lim) {
            if constexpr (INH) {
                float2 hv = ((const float2*)((const __half*)hin + (size_t)(base + n) * 64))[kc];
                const __half2* hh = (const __half2*)&hv;
                float2 a = __half22float2(hh[0]);
                float2 b = __half22float2(hh[1]);
                v = make_float4(a.x, a.y, b.x, b.y);
            } else {
                v = ((const float4*)((const float*)hin + (size_t)(base + n) * 64))[kc];
            }
        } else v = make_float4(0.f, 0.f, 0.f, 0.f);
        *(float4*)&hs[n * 64 + ((kc ^ ((n >> 2) & 7)) << 2)] = v;
    }
    __syncthreads();

    const int f0 = (tid & 15) << 2;
    const int n0 = (tid >> 4) << 2;
    float4 acc[4];
    #pragma unroll
    for (int i = 0; i < 4; ++i) acc[i] = make_float4(0.f, 0.f, 0.f, 0.f);

    #pragma unroll 2
    for (int kc = 0; kc < 16; ++kc) {
        float4 hv[4], wv[4];
        #pragma unroll
        for (int i = 0; i < 4; ++i) {
            int n = n0 + i;
            hv[i] = *(const float4*)&hs[n * 64 + ((kc ^ ((n >> 2) & 7)) << 2)];
        }
        #pragma unroll
        for (int j = 0; j < 4; ++j) {
            int f = f0 + j;
            wv[j] = *(const float4*)&ws[f * 64 + ((kc ^ ((f >> 2) & 7)) << 2)];
        }
        #pragma unroll
        for (int i = 0; i < 4; ++i) {
            acc[i].x = fmaf(hv[i].x, wv[0].x, acc[i].x);
            acc[i].x = fmaf(hv[i].y, wv[0].y, acc[i].x);
            acc[i].x = fmaf(hv[i].z, wv[0].z, acc[i].x);
            acc[i].x = fmaf(hv[i].w, wv[0].w, acc[i].x);
            acc[i].y = fmaf(hv[i].x, wv[1].x, acc[i].y);
            acc[i].y = fmaf(hv[i].y, wv[1].y, acc[i].y);
            acc[i].y = fmaf(hv[i].z, wv[1].z, acc[i].y);
            acc[i].y = fmaf(hv[i].w, wv[1].w, acc[i].y);
            acc[i].z = fmaf(hv[i].x, wv[2].x, acc[i].z);
            acc[i].z = fmaf(hv[i].y, wv[2].y, acc[i].z);
            acc[i].z = fmaf(hv[i].z, wv[2].z, acc[i].z);
            acc[i].z = fmaf(hv[i].w, wv[2].w, acc[i].z);
            acc[i].w = fmaf(hv[i].x, wv[3].x, acc[i].w);
            acc[i].w = fmaf(hv[i].y, wv[3].y, acc[i].w);
            acc[i].w = fmaf(hv[i].z, wv[3].z, acc[i].w);
            acc[i].w = fmaf(hv[i].w, wv[3].w, acc[i].w);
        }
    }

    if (f0 < F) {
        #pragma unroll
        for (int i = 0; i < 4; ++i) {
            int n = base + n0 + i;
            if (n < N_) {
                float dn = dinv[n];
                __half* o = outp + (size_t)n * 64 + f0;
                ((__half2*)o)[0] = __floats2half2_rn(acc[i].x * dn, acc[i].y * dn);
                ((__half2*)o)[1] = __floats2half2_rn(acc[i].z * dn, acc[i].w * dn);
            }
        }
    }
}

extern "C" void kernel_launch(void* const* d_in, const int* in_sizes, int n_in,
                              void* d_out, int out_size, void* d_ws, size_t ws_size,
                              hipStream_t stream) {
    const float* x   = (const float*)d_in[0];
    const int*   ei  = (const int*)d_in[1];
    const float* w   = (const float*)d_in[2];
    const float* W1  = (const float*)d_in[3];
    const float* b1  = (const float*)d_in[4];
    const float* W2  = (const float*)d_in[5];
    const float* b2  = (const float*)d_in[6];
    float* out = (float*)d_out;

    const int N_ = in_sizes[0] / 64;        // 100000
    const int E_ = in_sizes[2];             // 1200000
    const int PB = (E_ + P1_EDGES - 1) / P1_EDGES;   // 586 phase-1 blocks
    const int NB = (N_ + 255) >> 8;                  // 391 coarse buckets
    const int M  = NB * PB;                          // ~229K coarse counters

    char* ws = (char*)d_ws;
    size_t off = 0;
    auto alloc = [&](size_t bytes) { size_t o = off; off += (bytes + 255) & ~(size_t)255; return o; };
    float* dinv      = (float*)(ws + alloc((size_t)N_ * 4));
    int*   row_ptr   = (int*)  (ws + alloc(((size_t)N_ + 1) * 4));
    int*   bsums     = (int*)  (ws + alloc(1024 * 4));
    int*   coarseCnt = (int*)  (ws + alloc((size_t)M * 4));
    int*   coarseOff = (int*)  (ws + alloc(((size_t)M + 1) * 4));
    int2*  edge      = (int2*) (ws + alloc((size_t)E_ * 8));
    float* bufA      = (float*)(ws + alloc((size_t)N_ * 64 * 4));   // sorted / h(fp16)
    float* bufB      = (float*)(ws + alloc((size_t)N_ * 64 * 4));   // fp16 ping-pong
    int2*   sorted = (int2*)bufA;                                   // dead after p2_fine
    __half* hA0    = (__half*)bufA;                                 // h (fp16), after sorted dead
    __half* hLo    = (__half*)bufB;                                 // y / z (dinv-scaled)
    __half* hHi    = (__half*)((char*)bufB + (size_t)N_ * 64 * 2);  // Ay / Az (dinv-scaled)
    (void)ws_size; (void)n_in; (void)out_size;

    const int bh4 = (N_ + 15) / 16;                      // hop: 16 nodes per 256-thr block
    const int nbs = (M + SCAN_CHUNK - 1) / SCAN_CHUNK;   // scan blocks (<=1024)
    const int bl_ = (N_ + 63) / 64;

    // CSR build (atomic-free LDS counting sort) + dinv; edge.y = raw w
    p1_count_kernel<<<PB, 256, 0, stream>>>(ei, coarseCnt, E_, PB, NB);
    scan_partial_kernel<<<nbs, SCAN_TPB, 0, stream>>>(coarseCnt, bsums, M);
    scan_bsums_kernel<<<1, 1024, 0, stream>>>(bsums, nbs, coarseOff, M);
    scan_final_kernel<<<nbs, SCAN_TPB, 0, stream>>>(coarseCnt, bsums, coarseOff, M);
    p1_scatter_kernel<<<PB, 256, 0, stream>>>(ei, w, coarseOff, sorted, E_, PB, NB);
    p2_fine_kernel<<<NB, 256, 0, stream>>>(sorted, coarseOff, edge, row_ptr, dinv, N_, E_, PB, NB);

    // Layer 1: y_hat = dinv.*(X W1^T); hop1 (scaled); hop2 -> h actual (+b1, relu)
    linear_tiled_kernel<64, false><<<bl_, 256, 0, stream>>>(x, hLo, W1, dinv, N_);
    hop_h_kernel<16, 0><<<bh4, 256, 0, stream>>>(hLo, hHi, dinv, row_ptr, edge, nullptr, N_);
    hop_h_kernel<16, 1><<<bh4, 256, 0, stream>>>(hHi, hA0, dinv, row_ptr, edge, b1, N_);
    // Layer 2: z_hat = dinv.*(h W2^T); hop3 (scaled); hop4 -> out (+b2, fp32)
    linear_tiled_kernel<40, true><<<bl_, 256, 0, stream>>>(hA0, hLo, W2, dinv, N_);
    hop_h_kernel<10, 0><<<bh4, 256, 0, stream>>>(hLo, hHi, dinv, row_ptr, edge, nullptr, N_);
    hop_h_kernel<10, 2><<<bh4, 256, 0, stream>>>(hHi, out, dinv, row_ptr, edge, b2, N_);
}